// Round 5
// baseline (343.089 us; speedup 1.0000x reference)
//
#include <hip/hip_runtime.h>

#define NPTS 65536

typedef __bf16 bf16_t;
typedef __bf16 bf16x8 __attribute__((ext_vector_type(8)));
typedef float f32x16 __attribute__((ext_vector_type(16)));

#define MFMA32(A, B, C) __builtin_amdgcn_mfma_f32_32x32x16_bf16(A, B, C, 0, 0, 0)

__device__ __forceinline__ float relu(float v) { return v > 0.f ? v : 0.f; }

// ======================================================================
// Layouts (128-pt blocks, 4 mi slots):
// Activation (C ch): octet idx = ((b*(C/16)+kc)*4+mi)*64 + l
//   point = b*128 + mi*32 + (l&31); channel = kc*16 + (l>>5)*8 + j
// Weight (N x K): octet idx = (st*(K/16)+kc)*64 + l; n = st*32+(l&31); k = kc*16+(l>>5)*8+j
// ======================================================================

struct PrepSeg { const float* src; bf16_t* h; bf16_t* l; int SW; int K; int nblk; };
struct PrepAll { PrepSeg seg[6]; };

__global__ __launch_bounds__(256) void kprep(PrepAll pa) {
  int blk = blockIdx.x, i = 0;
  while (blk >= pa.seg[i].nblk) { blk -= pa.seg[i].nblk; ++i; }
  const PrepSeg sg = pa.seg[i];
  int t8 = blk * 256 + threadIdx.x;
  int l = t8 & 63;
  int rest = t8 >> 6;
  int NKC = sg.K >> 4;
  int kc = rest % NKC, st = rest / NKC;
  int n = st * 32 + (l & 31);
  int k0 = kc * 16 + (l >> 5) * 8;
  const float* src = sg.src + (size_t)n * sg.SW + k0;
  bf16x8 hv, lv;
#pragma unroll
  for (int j = 0; j < 8; ++j) {
    float v = src[j];
    bf16_t h = (bf16_t)v;
    hv[j] = h; lv[j] = (bf16_t)(v - (float)h);
  }
  *(bf16x8*)(sg.h + (size_t)t8 * 8) = hv;
  *(bf16x8*)(sg.l + (size_t)t8 * 8) = lv;
}

// ============ k1a: h1 = relu(x@W1.T+b1) in activation order
__global__ __launch_bounds__(256, 2) void k1a(
    const float* __restrict__ x, const float* __restrict__ W1, const float* __restrict__ b1,
    bf16_t* __restrict__ h1h, bf16_t* __restrict__ h1l) {
  int p = blockIdx.x * 256 + threadIdx.x;
  float x0 = x[p * 3 + 0], x1 = x[p * 3 + 1], x2 = x[p * 3 + 2];
  int b = p >> 7, mi = (p >> 5) & 3, p31 = p & 31;
#pragma unroll
  for (int kc = 0; kc < 4; ++kc)
#pragma unroll
    for (int hbw = 0; hbw < 2; ++hbw) {
      bf16x8 hv, lv;
#pragma unroll
      for (int j = 0; j < 8; ++j) {
        int c = kc * 16 + hbw * 8 + j;
        float v = relu(fmaf(W1[c * 3], x0, fmaf(W1[c * 3 + 1], x1, fmaf(W1[c * 3 + 2], x2, b1[c]))));
        bf16_t h = (bf16_t)v;
        hv[j] = h; lv[j] = (bf16_t)(v - (float)h);
      }
      size_t off = (((size_t)(b * 4 + kc) * 4 + mi) * 64 + hbw * 32 + p31) * 8;
      *(bf16x8*)(h1h + off) = hv;
      *(bf16x8*)(h1l + off) = lv;
    }
}

// ============ gemmS: D = W·X^T, 3-term split 32x32x16 bf16 MFMA (L2/L3 only now)
template <int PB, int K, int MODE>
__global__ __launch_bounds__(256, 3) void gemmS(
    const bf16_t* __restrict__ Ah, const bf16_t* __restrict__ Al,
    const bf16_t* __restrict__ Wh, const bf16_t* __restrict__ Wl,
    const float* __restrict__ bias, int nko,
    bf16_t* __restrict__ Oh, bf16_t* __restrict__ Ol,
    float* __restrict__ aux, const float* __restrict__ w8, const float* __restrict__ b8) {
  constexpr int WC = 4 / PB;
  constexpr int NKC = K / 16;
  constexpr int KG = 2;
  constexpr int NG = NKC / KG;
  __shared__ bf16_t smem[2][PB][2][KG * 2048];

  int tid = threadIdx.x;
  int lane = tid & 63;
  int w = __builtin_amdgcn_readfirstlane(tid >> 6);
  int rg = w / WC, cw = w % WC;
  int hb = lane >> 5, p31 = lane & 31;
  int bx = blockIdx.x;
  int st0 = blockIdx.y * WC + cw;
  int bblk = bx * PB + rg;

  f32x16 acc[4];
#pragma unroll
  for (int r = 0; r < 16; ++r) {
    float bv = bias[st0 * 32 + 8 * (r >> 2) + 4 * hb + (r & 3)];
#pragma unroll
    for (int mi = 0; mi < 4; ++mi) acc[mi][r] = bv;
  }

  auto stage = [&](int buf, int g) {
#pragma unroll
    for (int i = 0; i < PB * 4; ++i) {
      int u = i * 256 + tid;
      int rgs = u >> 10, rem = u & 1023;
      int t = rem >> 9, inner = rem & 511;
      const bf16_t* src = (t ? Al : Ah) +
          ((size_t)(bx * PB + rgs) * NKC + g * KG) * 2048 + inner * 8;
      *(bf16x8*)&smem[buf][rgs][t][inner * 8] = *(const bf16x8*)src;
    }
  };

  bf16x8 wch[KG], wcl[KG], wnh[KG], wnl[KG];
  auto wload = [&](int g, bf16x8* h, bf16x8* l) {
#pragma unroll
    for (int kcl = 0; kcl < KG; ++kcl) {
      size_t wo = (((size_t)st0 * NKC + g * KG + kcl) * 64 + lane) * 8;
      h[kcl] = *(const bf16x8*)(Wh + wo);
      l[kcl] = *(const bf16x8*)(Wl + wo);
    }
  };

  auto compute = [&](int buf, bf16x8* h, bf16x8* l) {
#pragma unroll
    for (int kcl = 0; kcl < KG; ++kcl)
#pragma unroll
      for (int mi = 0; mi < 4; ++mi) {
        const bf16_t* xp = &smem[buf][rg][0][((kcl * 4 + mi) * 64 + lane) * 8];
        bf16x8 xh = *(const bf16x8*)xp;
        bf16x8 xl = *(const bf16x8*)(xp + KG * 2048);
        acc[mi] = MFMA32(h[kcl], xh, acc[mi]);
        acc[mi] = MFMA32(l[kcl], xh, acc[mi]);
        acc[mi] = MFMA32(h[kcl], xl, acc[mi]);
      }
  };

  stage(0, 0);
  wload(0, wch, wcl);
  for (int g = 0; g < NG; ++g) {
    __syncthreads();
    if (g + 1 < NG) {
      stage((g + 1) & 1, g + 1);
      wload(g + 1, wnh, wnl);
    }
    compute(g & 1, wch, wcl);
#pragma unroll
    for (int kcl = 0; kcl < KG; ++kcl) { wch[kcl] = wnh[kcl]; wcl[kcl] = wnl[kcl]; }
  }

  if constexpr (MODE == 0) {
#pragma unroll
    for (int mi = 0; mi < 4; ++mi) {
      float a[16], rcv[8];
#pragma unroll
      for (int r = 0; r < 16; ++r) a[r] = relu(acc[mi][r]);
#pragma unroll
      for (int j = 0; j < 8; ++j) rcv[j] = __shfl_xor(hb ? a[j] : a[8 + j], 32);
      float o0[8], o1[8];
#pragma unroll
      for (int j = 0; j < 4; ++j) {
        o0[j]     = hb ? rcv[j]     : a[j];
        o0[4 + j] = hb ? a[8 + j]   : rcv[j];
        o1[j]     = hb ? rcv[4 + j] : a[4 + j];
        o1[4 + j] = hb ? a[12 + j]  : rcv[4 + j];
      }
      bf16x8 h0, l0, h1, l1;
#pragma unroll
      for (int j = 0; j < 8; ++j) {
        bf16_t x0 = (bf16_t)o0[j]; h0[j] = x0; l0[j] = (bf16_t)(o0[j] - (float)x0);
        bf16_t x1 = (bf16_t)o1[j]; h1[j] = x1; l1[j] = (bf16_t)(o1[j] - (float)x1);
      }
      int kco = st0 * 2 + hb;
      size_t ob = ((size_t)(bblk * nko + kco) * 4 + mi) * 64;
      *(bf16x8*)(Oh + (ob + p31) * 8)      = h0;
      *(bf16x8*)(Ol + (ob + p31) * 8)      = l0;
      *(bf16x8*)(Oh + (ob + 32 + p31) * 8) = h1;
      *(bf16x8*)(Ol + (ob + 32 + p31) * 8) = l1;
    }
  } else if constexpr (MODE == 1) {
#pragma unroll
    for (int r = 0; r < 16; ++r) {
      float m = relu(acc[0][r]);
#pragma unroll
      for (int mi = 1; mi < 4; ++mi) m = fmaxf(m, relu(acc[mi][r]));
#pragma unroll
      for (int off = 1; off < 32; off <<= 1) m = fmaxf(m, __shfl_xor(m, off));
      if (p31 == 0)
        aux[(size_t)bx * 1024 + st0 * 32 + 8 * (r >> 2) + 4 * hb + (r & 3)] = m;
    }
  } else {
    __shared__ float sp[4][128];
    float w8v[16];
#pragma unroll
    for (int r = 0; r < 16; ++r) w8v[r] = w8[st0 * 32 + 8 * (r >> 2) + 4 * hb + (r & 3)];
#pragma unroll
    for (int mi = 0; mi < 4; ++mi) {
      float s = 0.f;
#pragma unroll
      for (int r = 0; r < 16; ++r) s = fmaf(relu(acc[mi][r]), w8v[r], s);
      s += __shfl_xor(s, 32);
      if (hb == 0) sp[w][mi * 32 + p31] = s;
    }
    __syncthreads();
    if (tid < 128)
      aux[(size_t)bx * 128 + tid] = sp[0][tid] + sp[1][tid] + sp[2][tid] + sp[3][tid] + b8[0];
  }
}

// ============ kl4max v5: y4 = relu(y3@W4.T+b4), per-block max over 128 pts -> gpart[512][1024]
// v4 post-mortem: NT loads changed nothing -> not L2 capacity. W4 (512 KB) fits L2 but
// misses ~75% because all blocks sweep strips in the SAME order; L2 turns over every
// ~14 us and same-XCD blocks drift past each line's residency (stage-seeded drift,
// self-amplifying). v5: per-block strip-sweep ROTATION (rot = (bx>>3)&7) -> the 8
// rotation groups cover all 8 weight windows at all times, every window continuously
// referenced -> stays L2-resident; also kills same-line request storms. Outputs are
// per-strip independent -> numerics identical.
__global__ __launch_bounds__(256, 2) void kl4max(
    const bf16_t* __restrict__ Ah, const bf16_t* __restrict__ Al,
    const bf16_t* __restrict__ Wh, const bf16_t* __restrict__ Wl,
    const float* __restrict__ bias, float* __restrict__ gpart) {
  __shared__ __align__(16) bf16_t sA[32768];  // hi [0,16384), lo [16384,32768)
  int tid = threadIdx.x, lane = tid & 63;
  int w = __builtin_amdgcn_readfirstlane(tid >> 6);
  int hb = lane >> 5, p31 = lane & 31;
  int bx = blockIdx.x;
  int rot = (bx >> 3) & 7;  // same-XCD blocks get all 8 rotations (round-robin OR chunked map)
  const bf16_t* srcH = Ah + (size_t)bx * 16384;
  const bf16_t* srcL = Al + (size_t)bx * 16384;
#pragma unroll
  for (int i = 0; i < 8; ++i) {
    int u = i * 256 + tid;  // 2048 octets each of hi/lo; NT: once-read stream
    bf16x8 vh = __builtin_nontemporal_load((const bf16x8*)(srcH + (size_t)u * 8));
    bf16x8 vl = __builtin_nontemporal_load((const bf16x8*)(srcL + (size_t)u * 8));
    *(bf16x8*)(sA + (size_t)u * 8)         = vh;
    *(bf16x8*)(sA + 16384 + (size_t)u * 8) = vl;
  }
  __syncthreads();

#pragma unroll 1
  for (int j = 0; j < 8; ++j) {
    int st = ((j + rot) & 7) * 4 + w;  // rotated strip sweep
    bf16x8 cwh, cwl, nwh, nwl;
    {
      size_t wo = ((size_t)(st * 8) * 64 + lane) * 8;
      cwh = *(const bf16x8*)(Wh + wo);
      cwl = *(const bf16x8*)(Wl + wo);
    }
    f32x16 acc[4];
#pragma unroll
    for (int r = 0; r < 16; ++r) {
      float bv = bias[st * 32 + 8 * (r >> 2) + 4 * hb + (r & 3)];
#pragma unroll
      for (int mi = 0; mi < 4; ++mi) acc[mi][r] = bv;
    }
#pragma unroll
    for (int kc = 0; kc < 8; ++kc) {
      if (kc < 7) {
        size_t wo = ((size_t)(st * 8 + kc + 1) * 64 + lane) * 8;
        nwh = *(const bf16x8*)(Wh + wo);
        nwl = *(const bf16x8*)(Wl + wo);
      }
      __builtin_amdgcn_s_setprio(1);
#pragma unroll
      for (int mi = 0; mi < 4; ++mi) {
        const bf16_t* xp = sA + ((kc * 4 + mi) * 64 + lane) * 8;
        bf16x8 xh = *(const bf16x8*)xp;
        bf16x8 xl = *(const bf16x8*)(xp + 16384);
        acc[mi] = MFMA32(cwh, xh, acc[mi]);
        acc[mi] = MFMA32(cwl, xh, acc[mi]);
        acc[mi] = MFMA32(cwh, xl, acc[mi]);
      }
      __builtin_amdgcn_s_setprio(0);
      cwh = nwh; cwl = nwl;
    }
#pragma unroll
    for (int r = 0; r < 16; ++r) {
      float m = fmaxf(fmaxf(acc[0][r], acc[1][r]), fmaxf(acc[2][r], acc[3][r]));
      m = fmaxf(m, 0.f);  // relu folded into the max
#pragma unroll
      for (int off = 1; off < 32; off <<= 1) m = fmaxf(m, __shfl_xor(m, off));
      if (p31 == 0)
        __builtin_nontemporal_store(
            m, gpart + (size_t)bx * 1024 + st * 32 + 8 * (r >> 2) + 4 * hb + (r & 3));
    }
  }
}

// ============ kgmax: g[c] = max over 512 rows of gpart[512][1024]
__global__ __launch_bounds__(256) void kgmax(const float* __restrict__ gpart, float* __restrict__ g) {
  int t = blockIdx.x * 256 + threadIdx.x;  // 8192 threads
  int c = t & 1023, rg = t >> 10;
  const float* gp = gpart + (size_t)rg * 64 * 1024 + c;
  float m = 0.f;
#pragma unroll 8
  for (int r = 0; r < 64; ++r) m = fmaxf(m, gp[(size_t)r * 1024]);
  atomicMax((unsigned int*)(g + c), __float_as_uint(m));  // all values >= 0
}

// ============ kc5: c5[c] = W5[c][64:1088] @ g + b5[c]
__global__ __launch_bounds__(256) void kc5(
    const float* __restrict__ W5, const float* __restrict__ b5,
    const float* __restrict__ g, float* __restrict__ c5) {
  int tid = threadIdx.x;
  int ci = tid >> 3, kg = tid & 7;
  int c = blockIdx.x * 32 + ci;
  const float* wrow = W5 + (size_t)c * 1088 + 64 + kg * 128;
  const float* gp = g + kg * 128;
  float acc = 0.f;
#pragma unroll 8
  for (int k = 0; k < 128; ++k) acc += wrow[k] * gp[k];
#pragma unroll
  for (int off = 1; off <= 4; off <<= 1) acc += __shfl_xor(acc, off);
  if (kg == 0) c5[c] = acc + b5[c];
}

// ======================================================================
// mega2 (R0-measured version, 85.4 us / 88 VGPR / no spill):
// h2 -> z5 -> z6 -> z7 -> out, 64-pt blocks.
// Internal contract (2 mi slots): octet idx = (kc*2+mi)*64+l;
//   point = mi*32+(l&31), channel = kc*16+(l>>5)*8+j.
// ======================================================================

struct Oct { bf16x8 h0, l0, h1, l1; };
__device__ __forceinline__ Oct epi_pack(const f32x16& accv, int hb) {
  float a[16], rcv[8];
#pragma unroll
  for (int r = 0; r < 16; ++r) a[r] = relu(accv[r]);
#pragma unroll
  for (int j = 0; j < 8; ++j) rcv[j] = __shfl_xor(hb ? a[j] : a[8 + j], 32);
  float o0[8], o1[8];
#pragma unroll
  for (int j = 0; j < 4; ++j) {
    o0[j]     = hb ? rcv[j]     : a[j];
    o0[4 + j] = hb ? a[8 + j]   : rcv[j];
    o1[j]     = hb ? rcv[4 + j] : a[4 + j];
    o1[4 + j] = hb ? a[12 + j]  : rcv[4 + j];
  }
  Oct o;
#pragma unroll
  for (int j = 0; j < 8; ++j) {
    bf16_t x0 = (bf16_t)o0[j]; o.h0[j] = x0; o.l0[j] = (bf16_t)(o0[j] - (float)x0);
    bf16_t x1 = (bf16_t)o1[j]; o.h1[j] = x1; o.l1[j] = (bf16_t)(o1[j] - (float)x1);
  }
  return o;
}

__device__ __forceinline__ void epi_store_lds(const Oct& o, bf16_t* H, bf16_t* L, int ob, int p31) {
  *(bf16x8*)(H + (ob + p31) * 8)      = o.h0;
  *(bf16x8*)(H + (ob + 32 + p31) * 8) = o.h1;
  *(bf16x8*)(L + (ob + p31) * 8)      = o.l0;
  *(bf16x8*)(L + (ob + 32 + p31) * 8) = o.l1;
}

__device__ __forceinline__ void binit2(f32x16 acc[2], const float* bias, int base, int hb) {
#pragma unroll
  for (int r = 0; r < 16; ++r) {
    float bv = bias[base + 8 * (r >> 2) + 4 * hb + (r & 3)];
    acc[0][r] = bv; acc[1][r] = bv;
  }
}

template <int NKC>
__device__ __forceinline__ void wgemm(const bf16_t* __restrict__ Wh, const bf16_t* __restrict__ Wl,
                                      int st, const bf16_t* act, int loOff, int lane,
                                      f32x16 acc[2]) {
#pragma unroll
  for (int kc = 0; kc < NKC; ++kc) {
    size_t wo = ((size_t)(st * NKC + kc) * 64 + lane) * 8;
    bf16x8 awh = *(const bf16x8*)(Wh + wo), awl = *(const bf16x8*)(Wl + wo);
    bf16x8 xh[2], xl[2];
#pragma unroll
    for (int mi = 0; mi < 2; ++mi) {
      const bf16_t* xp = act + ((kc * 2 + mi) * 64 + lane) * 8;
      xh[mi] = *(const bf16x8*)xp; xl[mi] = *(const bf16x8*)(xp + loOff);
    }
#pragma unroll
    for (int mi = 0; mi < 2; ++mi) acc[mi] = MFMA32(awh, xh[mi], acc[mi]);
#pragma unroll
    for (int mi = 0; mi < 2; ++mi) acc[mi] = MFMA32(awl, xh[mi], acc[mi]);
#pragma unroll
    for (int mi = 0; mi < 2; ++mi) acc[mi] = MFMA32(awh, xl[mi], acc[mi]);
  }
}

__global__ __launch_bounds__(256, 2) void mega2(
    const bf16_t* __restrict__ h2gh, const bf16_t* __restrict__ h2gl,
    const bf16_t* __restrict__ W5h, const bf16_t* __restrict__ W5l, const float* __restrict__ c5,
    const bf16_t* __restrict__ W6h, const bf16_t* __restrict__ W6l, const float* __restrict__ b6,
    const bf16_t* __restrict__ W7h, const bf16_t* __restrict__ W7l, const float* __restrict__ b7,
    const float* __restrict__ w8, const float* __restrict__ b8v, float* __restrict__ out) {
  // phase A: h2 pair [0,8192), z5buf pair [8192,24576). phase B: z6 pair [0,32768).
  __shared__ __align__(16) bf16_t smem[32768];
  __shared__ float sp[4][64];
  int tid = threadIdx.x, lane = tid & 63;
  int w = __builtin_amdgcn_readfirstlane(tid >> 6);
  int hb = lane >> 5, p31 = lane & 31;
  int b = blockIdx.x;
  int B = b >> 1, half = b & 1;   // R8 h2 layout: 128-pt block B, 64-pt half
  bf16_t* z5buf = smem + 8192;

  // stage h2: remap R8 octet ((B*4+kc)*4 + half*2 + mi2)*64+l -> internal (kc*2+mi2)*64+l
#pragma unroll
  for (int i = 0; i < 4; ++i) {
    int u = i * 256 + tid;             // [0,1024) staged octets (512 hi + 512 lo)
    int t = u >> 9, rem = u & 511;
    int kcmi = rem >> 6, l = rem & 63;
    int kc = kcmi >> 1, mi2 = kcmi & 1;
    size_t so = ((size_t)((B * 4 + kc) * 4 + half * 2 + mi2) * 64 + l) * 8;
    const bf16_t* src = (t ? h2gl : h2gh) + so;
    *(bf16x8*)(smem + t * 4096 + rem * 8) = *(const bf16x8*)src;
  }
  __syncthreads();

  // z6 accumulators: wave owns strips {2w, 2w+1} (64 ch) x 64 pts
  f32x16 z6a[2][2];
#pragma unroll
  for (int s = 0; s < 2; ++s)
#pragma unroll
    for (int r = 0; r < 16; ++r) {
      float bv = b6[(w * 2 + s) * 32 + 8 * (r >> 2) + 4 * hb + (r & 3)];
      z6a[s][0][r] = bv; z6a[s][1][r] = bv;
    }

  for (int g5 = 0; g5 < 4; ++g5) {
    // ---- L5 strip: z5 chans [(g5*4+w)*32, +32)
    int st5 = g5 * 4 + w;
    f32x16 a5[2];
    binit2(a5, c5, st5 * 32, hb);
    wgemm<4>(W5h, W5l, st5, smem, 4096, lane, a5);
    __syncthreads();  // prev group's L6 reads of z5buf complete
#pragma unroll
    for (int mi = 0; mi < 2; ++mi) {
      Oct o = epi_pack(a5[mi], hb);
      epi_store_lds(o, z5buf, z5buf + 8192, ((w * 2 + hb) * 2 + mi) * 64, p31);
    }
    __syncthreads();  // z5buf ready
    // ---- L6 partial accumulate over this 128-k chunk
#pragma unroll
    for (int kc = 0; kc < 8; ++kc) {
      bf16x8 awh[2], awl[2], xh[2], xl[2];
#pragma unroll
      for (int s = 0; s < 2; ++s) {
        size_t wo = ((size_t)((w * 2 + s) * 32 + g5 * 8 + kc) * 64 + lane) * 8;
        awh[s] = *(const bf16x8*)(W6h + wo);
        awl[s] = *(const bf16x8*)(W6l + wo);
      }
#pragma unroll
      for (int mi = 0; mi < 2; ++mi) {
        const bf16_t* xp = z5buf + ((kc * 2 + mi) * 64 + lane) * 8;
        xh[mi] = *(const bf16x8*)xp; xl[mi] = *(const bf16x8*)(xp + 8192);
      }
#pragma unroll
      for (int s = 0; s < 2; ++s)
#pragma unroll
        for (int mi = 0; mi < 2; ++mi) z6a[s][mi] = MFMA32(awh[s], xh[mi], z6a[s][mi]);
#pragma unroll
      for (int s = 0; s < 2; ++s)
#pragma unroll
        for (int mi = 0; mi < 2; ++mi) z6a[s][mi] = MFMA32(awl[s], xh[mi], z6a[s][mi]);
#pragma unroll
      for (int s = 0; s < 2; ++s)
#pragma unroll
        for (int mi = 0; mi < 2; ++mi) z6a[s][mi] = MFMA32(awh[s], xl[mi], z6a[s][mi]);
    }
  }
  __syncthreads();  // all phase-A reads done
  // ---- z6 epilogue -> smem [0,32768): hi [0,16384), lo [16384,32768)
#pragma unroll
  for (int s = 0; s < 2; ++s) {
    int kcb = (w * 2 + s) * 2 + hb;
#pragma unroll
    for (int mi = 0; mi < 2; ++mi) {
      Oct o = epi_pack(z6a[s][mi], hb);
      epi_store_lds(o, smem, smem + 16384, (kcb * 2 + mi) * 64, p31);
    }
  }
  __syncthreads();
  // ---- L7: wave strip w, K=256
  f32x16 a7[2];
  binit2(a7, b7, w * 32, hb);
  wgemm<16>(W7h, W7l, w, smem, 16384, lane, a7);
  // ---- L8: dot with w8
  float w8v[16];
#pragma unroll
  for (int r = 0; r < 16; ++r) w8v[r] = w8[w * 32 + 8 * (r >> 2) + 4 * hb + (r & 3)];
#pragma unroll
  for (int mi = 0; mi < 2; ++mi) {
    float s = 0.f;
#pragma unroll
    for (int r = 0; r < 16; ++r) s = fmaf(relu(a7[mi][r]), w8v[r], s);
    s += __shfl_xor(s, 32);
    if (hb == 0) sp[w][mi * 32 + p31] = s;
  }
  __syncthreads();
  if (tid < 64)
    out[b * 64 + tid] = sp[0][tid] + sp[1][tid] + sp[2][tid] + sp[3][tid] + b8v[0];
}

extern "C" void kernel_launch(void* const* d_in, const int* in_sizes, int n_in,
                              void* d_out, int out_size, void* d_ws, size_t ws_size,
                              hipStream_t stream) {
  const float* x  = (const float*)d_in[0];
  const float* W1 = (const float*)d_in[1];  const float* b1 = (const float*)d_in[2];
  const float* W2 = (const float*)d_in[3];  const float* b2 = (const float*)d_in[4];
  const float* W3 = (const float*)d_in[5];  const float* b3 = (const float*)d_in[6];
  const float* W4 = (const float*)d_in[7];  const float* b4 = (const float*)d_in[8];
  const float* W5 = (const float*)d_in[9];  const float* b5 = (const float*)d_in[10];
  const float* W6 = (const float*)d_in[11]; const float* b6 = (const float*)d_in[12];
  const float* W7 = (const float*)d_in[13]; const float* b7 = (const float*)d_in[14];
  const float* W8 = (const float*)d_in[15]; const float* b8 = (const float*)d_in[16];
  float* out = (float*)d_out;

  // Workspace overlays:
  //   h2 pair [128,136)+[136,144)  L2->mega2
  //   h1 pair [144,152)+[152,160)  k1a->L2
  //   y3 pair [144,160)+[160,176)  L3->L4  (over dead h1)
  //   gpart [208,210), g/c5 [210,..), weight frags after
  const size_t MB = 1ull << 20;
  char* ws = (char*)d_ws;
  bf16_t* h2h = (bf16_t*)(ws + 128 * MB);  bf16_t* h2l = (bf16_t*)(ws + 136 * MB);
  bf16_t* h1h = (bf16_t*)(ws + 144 * MB);  bf16_t* h1l = (bf16_t*)(ws + 152 * MB);
  bf16_t* y3h = (bf16_t*)(ws + 144 * MB);  bf16_t* y3l = (bf16_t*)(ws + 160 * MB);
  float* gpart = (float*)(ws + 208 * MB);
  float* g     = (float*)(ws + 210 * MB);
  float* c5    = (float*)(ws + 210 * MB + 4096);
  char* wb = ws + 210 * MB + 65536;
  bf16_t* W2h = (bf16_t*)(wb);             bf16_t* W2l = (bf16_t*)(wb + 8192);
  bf16_t* W3h = (bf16_t*)(wb + 16384);     bf16_t* W3l = (bf16_t*)(wb + 32768);
  bf16_t* W4h = (bf16_t*)(wb + 49152);     bf16_t* W4l = (bf16_t*)(wb + 311296);
  bf16_t* W5h = (bf16_t*)(wb + 573440);    bf16_t* W5l = (bf16_t*)(wb + 638976);
  bf16_t* W6h = (bf16_t*)(wb + 704512);    bf16_t* W6l = (bf16_t*)(wb + 966656);
  bf16_t* W7h = (bf16_t*)(wb + 1228800);   bf16_t* W7l = (bf16_t*)(wb + 1294336);

  hipMemsetAsync(g, 0, 1024 * sizeof(float), stream);  // max identity (relu outputs >= 0)

  PrepAll pa;
  pa.seg[0] = {W2, W2h, W2l, 64, 64, 2};
  pa.seg[1] = {W3, W3h, W3l, 64, 64, 4};
  pa.seg[2] = {W4, W4h, W4l, 128, 128, 64};
  pa.seg[3] = {W5, W5h, W5l, 1088, 64, 16};   // W5[:, :64]
  pa.seg[4] = {W6, W6h, W6l, 512, 512, 64};
  pa.seg[5] = {W7, W7h, W7l, 256, 256, 16};
  kprep<<<166, 256, 0, stream>>>(pa);

  k1a<<<256, 256, 0, stream>>>(x, W1, b1, h1h, h1l);
  gemmS<2, 64, 0><<<dim3(256, 1), 256, 0, stream>>>(
      h1h, h1l, W2h, W2l, b2, 4, h2h, h2l, nullptr, nullptr, nullptr);        // L2
  gemmS<1, 64, 0><<<dim3(512, 1), 256, 0, stream>>>(
      h2h, h2l, W3h, W3l, b3, 8, y3h, y3l, nullptr, nullptr, nullptr);        // L3
  kl4max<<<512, 256, 0, stream>>>(y3h, y3l, W4h, W4l, b4, gpart);             // L4 + max
  kgmax<<<32, 256, 0, stream>>>(gpart, g);
  kc5<<<16, 256, 0, stream>>>(W5, b5, g, c5);
  mega2<<<1024, 256, 0, stream>>>(h2h, h2l, W5h, W5l, c5, W6h, W6l, b6,
                                  W7h, W7l, b7, W8, b8, out);                 // L5..L8 fused
}

// Round 6
// 306.784 us; speedup vs baseline: 1.1183x; 1.1183x over previous
//
#include <hip/hip_runtime.h>

#define NPTS 65536

typedef __bf16 bf16_t;
typedef __bf16 bf16x8 __attribute__((ext_vector_type(8)));
typedef float f32x16 __attribute__((ext_vector_type(16)));

#define MFMA32(A, B, C) __builtin_amdgcn_mfma_f32_32x32x16_bf16(A, B, C, 0, 0, 0)

__device__ __forceinline__ float relu(float v) { return v > 0.f ? v : 0.f; }

// ======================================================================
// Layouts (128-pt blocks, 4 mi slots):
// Activation (C ch): octet idx = ((b*(C/16)+kc)*4+mi)*64 + l
//   point = b*128 + mi*32 + (l&31); channel = kc*16 + (l>>5)*8 + j
// Weight (N x K): octet idx = (st*(K/16)+kc)*64 + l; n = st*32+(l&31); k = kc*16+(l>>5)*8+j
// ======================================================================

struct PrepSeg { const float* src; bf16_t* h; bf16_t* l; int SW; int K; int nblk; };
struct PrepAll { PrepSeg seg[6]; };

__global__ __launch_bounds__(256) void kprep(PrepAll pa) {
  int blk = blockIdx.x, i = 0;
  while (blk >= pa.seg[i].nblk) { blk -= pa.seg[i].nblk; ++i; }
  const PrepSeg sg = pa.seg[i];
  int t8 = blk * 256 + threadIdx.x;
  int l = t8 & 63;
  int rest = t8 >> 6;
  int NKC = sg.K >> 4;
  int kc = rest % NKC, st = rest / NKC;
  int n = st * 32 + (l & 31);
  int k0 = kc * 16 + (l >> 5) * 8;
  const float* src = sg.src + (size_t)n * sg.SW + k0;
  bf16x8 hv, lv;
#pragma unroll
  for (int j = 0; j < 8; ++j) {
    float v = src[j];
    bf16_t h = (bf16_t)v;
    hv[j] = h; lv[j] = (bf16_t)(v - (float)h);
  }
  *(bf16x8*)(sg.h + (size_t)t8 * 8) = hv;
  *(bf16x8*)(sg.l + (size_t)t8 * 8) = lv;
}

// ============ k1a: h1 = relu(x@W1.T+b1) in activation order
__global__ __launch_bounds__(256, 2) void k1a(
    const float* __restrict__ x, const float* __restrict__ W1, const float* __restrict__ b1,
    bf16_t* __restrict__ h1h, bf16_t* __restrict__ h1l) {
  int p = blockIdx.x * 256 + threadIdx.x;
  float x0 = x[p * 3 + 0], x1 = x[p * 3 + 1], x2 = x[p * 3 + 2];
  int b = p >> 7, mi = (p >> 5) & 3, p31 = p & 31;
#pragma unroll
  for (int kc = 0; kc < 4; ++kc)
#pragma unroll
    for (int hbw = 0; hbw < 2; ++hbw) {
      bf16x8 hv, lv;
#pragma unroll
      for (int j = 0; j < 8; ++j) {
        int c = kc * 16 + hbw * 8 + j;
        float v = relu(fmaf(W1[c * 3], x0, fmaf(W1[c * 3 + 1], x1, fmaf(W1[c * 3 + 2], x2, b1[c]))));
        bf16_t h = (bf16_t)v;
        hv[j] = h; lv[j] = (bf16_t)(v - (float)h);
      }
      size_t off = (((size_t)(b * 4 + kc) * 4 + mi) * 64 + hbw * 32 + p31) * 8;
      *(bf16x8*)(h1h + off) = hv;
      *(bf16x8*)(h1l + off) = lv;
    }
}

// ============ shared epilogue helpers (used by gemmS, kl34max, mega2)
struct Oct { bf16x8 h0, l0, h1, l1; };
__device__ __forceinline__ Oct epi_pack(const f32x16& accv, int hb) {
  float a[16], rcv[8];
#pragma unroll
  for (int r = 0; r < 16; ++r) a[r] = relu(accv[r]);
#pragma unroll
  for (int j = 0; j < 8; ++j) rcv[j] = __shfl_xor(hb ? a[j] : a[8 + j], 32);
  float o0[8], o1[8];
#pragma unroll
  for (int j = 0; j < 4; ++j) {
    o0[j]     = hb ? rcv[j]     : a[j];
    o0[4 + j] = hb ? a[8 + j]   : rcv[j];
    o1[j]     = hb ? rcv[4 + j] : a[4 + j];
    o1[4 + j] = hb ? a[12 + j]  : rcv[4 + j];
  }
  Oct o;
#pragma unroll
  for (int j = 0; j < 8; ++j) {
    bf16_t x0 = (bf16_t)o0[j]; o.h0[j] = x0; o.l0[j] = (bf16_t)(o0[j] - (float)x0);
    bf16_t x1 = (bf16_t)o1[j]; o.h1[j] = x1; o.l1[j] = (bf16_t)(o1[j] - (float)x1);
  }
  return o;
}

__device__ __forceinline__ void epi_store_lds(const Oct& o, bf16_t* H, bf16_t* L, int ob, int p31) {
  *(bf16x8*)(H + (ob + p31) * 8)      = o.h0;
  *(bf16x8*)(H + (ob + 32 + p31) * 8) = o.h1;
  *(bf16x8*)(L + (ob + p31) * 8)      = o.l0;
  *(bf16x8*)(L + (ob + 32 + p31) * 8) = o.l1;
}

__device__ __forceinline__ void binit2(f32x16 acc[2], const float* bias, int base, int hb) {
#pragma unroll
  for (int r = 0; r < 16; ++r) {
    float bv = bias[base + 8 * (r >> 2) + 4 * hb + (r & 3)];
    acc[0][r] = bv; acc[1][r] = bv;
  }
}

// ============ gemmS: D = W·X^T, 3-term split 32x32x16 bf16 MFMA (L2 only now)
template <int PB, int K, int MODE>
__global__ __launch_bounds__(256, 3) void gemmS(
    const bf16_t* __restrict__ Ah, const bf16_t* __restrict__ Al,
    const bf16_t* __restrict__ Wh, const bf16_t* __restrict__ Wl,
    const float* __restrict__ bias, int nko,
    bf16_t* __restrict__ Oh, bf16_t* __restrict__ Ol,
    float* __restrict__ aux, const float* __restrict__ w8, const float* __restrict__ b8) {
  constexpr int WC = 4 / PB;
  constexpr int NKC = K / 16;
  constexpr int KG = 2;
  constexpr int NG = NKC / KG;
  __shared__ bf16_t smem[2][PB][2][KG * 2048];

  int tid = threadIdx.x;
  int lane = tid & 63;
  int w = __builtin_amdgcn_readfirstlane(tid >> 6);
  int rg = w / WC, cw = w % WC;
  int hb = lane >> 5, p31 = lane & 31;
  int bx = blockIdx.x;
  int st0 = blockIdx.y * WC + cw;
  int bblk = bx * PB + rg;

  f32x16 acc[4];
#pragma unroll
  for (int r = 0; r < 16; ++r) {
    float bv = bias[st0 * 32 + 8 * (r >> 2) + 4 * hb + (r & 3)];
#pragma unroll
    for (int mi = 0; mi < 4; ++mi) acc[mi][r] = bv;
  }

  auto stage = [&](int buf, int g) {
#pragma unroll
    for (int i = 0; i < PB * 4; ++i) {
      int u = i * 256 + tid;
      int rgs = u >> 10, rem = u & 1023;
      int t = rem >> 9, inner = rem & 511;
      const bf16_t* src = (t ? Al : Ah) +
          ((size_t)(bx * PB + rgs) * NKC + g * KG) * 2048 + inner * 8;
      *(bf16x8*)&smem[buf][rgs][t][inner * 8] = *(const bf16x8*)src;
    }
  };

  bf16x8 wch[KG], wcl[KG], wnh[KG], wnl[KG];
  auto wload = [&](int g, bf16x8* h, bf16x8* l) {
#pragma unroll
    for (int kcl = 0; kcl < KG; ++kcl) {
      size_t wo = (((size_t)st0 * NKC + g * KG + kcl) * 64 + lane) * 8;
      h[kcl] = *(const bf16x8*)(Wh + wo);
      l[kcl] = *(const bf16x8*)(Wl + wo);
    }
  };

  auto compute = [&](int buf, bf16x8* h, bf16x8* l) {
#pragma unroll
    for (int kcl = 0; kcl < KG; ++kcl)
#pragma unroll
      for (int mi = 0; mi < 4; ++mi) {
        const bf16_t* xp = &smem[buf][rg][0][((kcl * 4 + mi) * 64 + lane) * 8];
        bf16x8 xh = *(const bf16x8*)xp;
        bf16x8 xl = *(const bf16x8*)(xp + KG * 2048);
        acc[mi] = MFMA32(h[kcl], xh, acc[mi]);
        acc[mi] = MFMA32(l[kcl], xh, acc[mi]);
        acc[mi] = MFMA32(h[kcl], xl, acc[mi]);
      }
  };

  stage(0, 0);
  wload(0, wch, wcl);
  for (int g = 0; g < NG; ++g) {
    __syncthreads();
    if (g + 1 < NG) {
      stage((g + 1) & 1, g + 1);
      wload(g + 1, wnh, wnl);
    }
    compute(g & 1, wch, wcl);
#pragma unroll
    for (int kcl = 0; kcl < KG; ++kcl) { wch[kcl] = wnh[kcl]; wcl[kcl] = wnl[kcl]; }
  }

  if constexpr (MODE == 0) {
#pragma unroll
    for (int mi = 0; mi < 4; ++mi) {
      Oct o = epi_pack(acc[mi], hb);
      int kco = st0 * 2 + hb;
      size_t ob = ((size_t)(bblk * nko + kco) * 4 + mi) * 64;
      *(bf16x8*)(Oh + (ob + p31) * 8)      = o.h0;
      *(bf16x8*)(Ol + (ob + p31) * 8)      = o.l0;
      *(bf16x8*)(Oh + (ob + 32 + p31) * 8) = o.h1;
      *(bf16x8*)(Ol + (ob + 32 + p31) * 8) = o.l1;
    }
  } else if constexpr (MODE == 1) {
#pragma unroll
    for (int r = 0; r < 16; ++r) {
      float m = relu(acc[0][r]);
#pragma unroll
      for (int mi = 1; mi < 4; ++mi) m = fmaxf(m, relu(acc[mi][r]));
#pragma unroll
      for (int off = 1; off < 32; off <<= 1) m = fmaxf(m, __shfl_xor(m, off));
      if (p31 == 0)
        aux[(size_t)bx * 1024 + st0 * 32 + 8 * (r >> 2) + 4 * hb + (r & 3)] = m;
    }
  } else {
    __shared__ float sp[4][128];
    float w8v[16];
#pragma unroll
    for (int r = 0; r < 16; ++r) w8v[r] = w8[st0 * 32 + 8 * (r >> 2) + 4 * hb + (r & 3)];
#pragma unroll
    for (int mi = 0; mi < 4; ++mi) {
      float s = 0.f;
#pragma unroll
      for (int r = 0; r < 16; ++r) s = fmaf(relu(acc[mi][r]), w8v[r], s);
      s += __shfl_xor(s, 32);
      if (hb == 0) sp[w][mi * 32 + p31] = s;
    }
    __syncthreads();
    if (tid < 128)
      aux[(size_t)bx * 128 + tid] = sp[0][tid] + sp[1][tid] + sp[2][tid] + sp[3][tid] + b8[0];
  }
}

// ============ kl34max: FUSED L3+L4. Per 128-pt block:
//   phase 1: y3 = relu(h2@W3.T+b3) computed straight into LDS (per-wave mi
//            partition, strip-pair accumulators; same MFMA term order as the
//            old gemmS L3 -> bit-identical y3). Kills the separate L3 kernel,
//            32 MB y3 write + 32 MB y3 read.
//   phase 2: unchanged j-sweep: y4 = relu(y3@W4.T+b4), per-block channel max
//            -> gpart[512][1024].
__global__ __launch_bounds__(256, 2) void kl34max(
    const bf16_t* __restrict__ h2h, const bf16_t* __restrict__ h2l,
    const bf16_t* __restrict__ W3h, const bf16_t* __restrict__ W3l,
    const float* __restrict__ b3,
    const bf16_t* __restrict__ Wh, const bf16_t* __restrict__ Wl,
    const float* __restrict__ bias, float* __restrict__ gpart) {
  __shared__ __align__(16) bf16_t sA[32768];  // y3 tile: hi [0,16384), lo [16384,32768)
  int tid = threadIdx.x, lane = tid & 63;
  int w = __builtin_amdgcn_readfirstlane(tid >> 6);
  int hb = lane >> 5, p31 = lane & 31;
  int bx = blockIdx.x;
  int rot = (bx >> 3) & 7;

  // ---- phase 1: h2 B-frags for mi=w (coalesced, 32 VGPR)
  bf16x8 hx[4], lx[4];
#pragma unroll
  for (int kc = 0; kc < 4; ++kc) {
    size_t so = (((size_t)(bx * 4 + kc) * 4 + w) * 64 + lane) * 8;
    hx[kc] = *(const bf16x8*)(h2h + so);
    lx[kc] = *(const bf16x8*)(h2l + so);
  }
#pragma unroll
  for (int spr = 0; spr < 2; ++spr) {  // strip pairs (0,1), (2,3) of y3's 4 strips
    f32x16 a3[2];
#pragma unroll
    for (int s = 0; s < 2; ++s) {
      int st = spr * 2 + s;
#pragma unroll
      for (int r = 0; r < 16; ++r)
        a3[s][r] = b3[st * 32 + 8 * (r >> 2) + 4 * hb + (r & 3)];
    }
#pragma unroll
    for (int kc = 0; kc < 4; ++kc)
#pragma unroll
      for (int s = 0; s < 2; ++s) {
        int st = spr * 2 + s;
        size_t wo = ((size_t)(st * 4 + kc) * 64 + lane) * 8;  // same addr across waves -> L1
        bf16x8 wh3 = *(const bf16x8*)(W3h + wo);
        bf16x8 wl3 = *(const bf16x8*)(W3l + wo);
        a3[s] = MFMA32(wh3, hx[kc], a3[s]);
        a3[s] = MFMA32(wl3, hx[kc], a3[s]);
        a3[s] = MFMA32(wh3, lx[kc], a3[s]);
      }
#pragma unroll
    for (int s = 0; s < 2; ++s) {
      int st = spr * 2 + s;
      Oct o = epi_pack(a3[s], hb);
      epi_store_lds(o, sA, sA + 16384, ((st * 2 + hb) * 4 + w) * 64, p31);
    }
  }
  __syncthreads();

  // ---- phase 2: L4 sweep (unchanged from measured kl4max v5)
#pragma unroll 1
  for (int j = 0; j < 8; ++j) {
    int st = ((j + rot) & 7) * 4 + w;
    bf16x8 cwh, cwl, nwh, nwl;
    {
      size_t wo = ((size_t)(st * 8) * 64 + lane) * 8;
      cwh = *(const bf16x8*)(Wh + wo);
      cwl = *(const bf16x8*)(Wl + wo);
    }
    f32x16 acc[4];
#pragma unroll
    for (int r = 0; r < 16; ++r) {
      float bv = bias[st * 32 + 8 * (r >> 2) + 4 * hb + (r & 3)];
#pragma unroll
      for (int mi = 0; mi < 4; ++mi) acc[mi][r] = bv;
    }
#pragma unroll
    for (int kc = 0; kc < 8; ++kc) {
      if (kc < 7) {
        size_t wo = ((size_t)(st * 8 + kc + 1) * 64 + lane) * 8;
        nwh = *(const bf16x8*)(Wh + wo);
        nwl = *(const bf16x8*)(Wl + wo);
      }
      __builtin_amdgcn_s_setprio(1);
#pragma unroll
      for (int mi = 0; mi < 4; ++mi) {
        const bf16_t* xp = sA + ((kc * 4 + mi) * 64 + lane) * 8;
        bf16x8 xh = *(const bf16x8*)xp;
        bf16x8 xl = *(const bf16x8*)(xp + 16384);
        acc[mi] = MFMA32(cwh, xh, acc[mi]);
        acc[mi] = MFMA32(cwl, xh, acc[mi]);
        acc[mi] = MFMA32(cwh, xl, acc[mi]);
      }
      __builtin_amdgcn_s_setprio(0);
      cwh = nwh; cwl = nwl;
    }
#pragma unroll
    for (int r = 0; r < 16; ++r) {
      float m = fmaxf(fmaxf(acc[0][r], acc[1][r]), fmaxf(acc[2][r], acc[3][r]));
      m = fmaxf(m, 0.f);  // relu folded into the max
#pragma unroll
      for (int off = 1; off < 32; off <<= 1) m = fmaxf(m, __shfl_xor(m, off));
      if (p31 == 0)
        __builtin_nontemporal_store(
            m, gpart + (size_t)bx * 1024 + st * 32 + 8 * (r >> 2) + 4 * hb + (r & 3));
    }
  }
}

// ============ kgmax: g[c] = max over 512 rows of gpart[512][1024]
__global__ __launch_bounds__(256) void kgmax(const float* __restrict__ gpart, float* __restrict__ g) {
  int t = blockIdx.x * 256 + threadIdx.x;  // 8192 threads
  int c = t & 1023, rg = t >> 10;
  const float* gp = gpart + (size_t)rg * 64 * 1024 + c;
  float m = 0.f;
#pragma unroll 8
  for (int r = 0; r < 64; ++r) m = fmaxf(m, gp[(size_t)r * 1024]);
  atomicMax((unsigned int*)(g + c), __float_as_uint(m));  // all values >= 0
}

// ============ kc5: c5[c] = W5[c][64:1088] @ g + b5[c]
__global__ __launch_bounds__(256) void kc5(
    const float* __restrict__ W5, const float* __restrict__ b5,
    const float* __restrict__ g, float* __restrict__ c5) {
  int tid = threadIdx.x;
  int ci = tid >> 3, kg = tid & 7;
  int c = blockIdx.x * 32 + ci;
  const float* wrow = W5 + (size_t)c * 1088 + 64 + kg * 128;
  const float* gp = g + kg * 128;
  float acc = 0.f;
#pragma unroll 8
  for (int k = 0; k < 128; ++k) acc += wrow[k] * gp[k];
#pragma unroll
  for (int off = 1; off <= 4; off <<= 1) acc += __shfl_xor(acc, off);
  if (kg == 0) c5[c] = acc + b5[c];
}

// ======================================================================
// mega2 v2 (restored: cross-round differencing R2 vs R3 shows ~69 us vs 85):
// h2 -> z5 -> z6 -> z7 -> out, 64-pt blocks. h2 B-frags in registers; z5
// double-buffered in LDS (1 barrier/group); W5/W6/W7 register prefetch
// pipelines; s_setprio around MFMA clusters.
// Internal contract (2 mi slots): octet idx = (kc*2+mi)*64+l;
//   point = mi*32+(l&31), channel = kc*16+(l>>5)*8+j.
// ======================================================================

__global__ __launch_bounds__(256, 2) void mega2(
    const bf16_t* __restrict__ h2gh, const bf16_t* __restrict__ h2gl,
    const bf16_t* __restrict__ W5h, const bf16_t* __restrict__ W5l, const float* __restrict__ c5,
    const bf16_t* __restrict__ W6h, const bf16_t* __restrict__ W6l, const float* __restrict__ b6,
    const bf16_t* __restrict__ W7h, const bf16_t* __restrict__ W7l, const float* __restrict__ b7,
    const float* __restrict__ w8, const float* __restrict__ b8v, float* __restrict__ out) {
  // LDS: phase A: z5 dbuf = [0,16384) + [16384,32768) elems (each: hi 8192 | lo 8192)
  //      phase B: z6 pair [0,32768): hi [0,16384), lo [16384,32768)
  __shared__ __align__(16) bf16_t smem[32768];
  __shared__ float sp[4][64];
  int tid = threadIdx.x, lane = tid & 63;
  int w = __builtin_amdgcn_readfirstlane(tid >> 6);
  int hb = lane >> 5, p31 = lane & 31;
  int b = blockIdx.x;
  int B = b >> 1, half = b & 1;   // R8 h2 layout: 128-pt block B, 64-pt half

  // ---- h2 B-fragments -> registers (reused by all 4 L5 groups; coalesced)
  bf16x8 xh[4][2], xl[4][2];
#pragma unroll
  for (int kc = 0; kc < 4; ++kc)
#pragma unroll
    for (int mi = 0; mi < 2; ++mi) {
      size_t so = (((size_t)((B * 4 + kc) * 4 + half * 2 + mi)) * 64 + lane) * 8;
      xh[kc][mi] = *(const bf16x8*)(h2gh + so);
      xl[kc][mi] = *(const bf16x8*)(h2gl + so);
    }

  // z6 accumulators: wave owns strips {2w, 2w+1} (64 ch) x 64 pts
  f32x16 z6a[2][2];
#pragma unroll
  for (int s = 0; s < 2; ++s)
#pragma unroll
    for (int r = 0; r < 16; ++r) {
      float bv = b6[(w * 2 + s) * 32 + 8 * (r >> 2) + 4 * hb + (r & 3)];
      z6a[s][0][r] = bv; z6a[s][1][r] = bv;
    }

  bf16x8 w5h[4], w5l[4];
  auto w5load = [&](int g) {
#pragma unroll
    for (int kc = 0; kc < 4; ++kc) {
      size_t wo = (((size_t)(g * 4 + w) * 4 + kc) * 64 + lane) * 8;
      w5h[kc] = *(const bf16x8*)(W5h + wo);
      w5l[kc] = *(const bf16x8*)(W5l + wo);
    }
  };
  w5load(0);

  bf16x8 cwh[2], cwl[2], nwh[2], nwl[2];
  auto w6load = [&](int g, int kc, bf16x8* hh, bf16x8* ll) {
#pragma unroll
    for (int s = 0; s < 2; ++s) {
      size_t wo = ((size_t)((w * 2 + s) * 32 + g * 8 + kc) * 64 + lane) * 8;
      hh[s] = *(const bf16x8*)(W6h + wo);
      ll[s] = *(const bf16x8*)(W6l + wo);
    }
  };

  for (int g5 = 0; g5 < 4; ++g5) {
    bf16_t* zbuf = smem + (g5 & 1) * 16384;
    // ---- L5 strip: z5 chans [(g5*4+w)*32, +32), K=64 from h2 regs
    int st5 = g5 * 4 + w;
    f32x16 a5[2];
    binit2(a5, c5, st5 * 32, hb);
    __builtin_amdgcn_s_setprio(1);
#pragma unroll
    for (int kc = 0; kc < 4; ++kc) {
#pragma unroll
      for (int mi = 0; mi < 2; ++mi) a5[mi] = MFMA32(w5h[kc], xh[kc][mi], a5[mi]);
#pragma unroll
      for (int mi = 0; mi < 2; ++mi) a5[mi] = MFMA32(w5l[kc], xh[kc][mi], a5[mi]);
#pragma unroll
      for (int mi = 0; mi < 2; ++mi) a5[mi] = MFMA32(w5h[kc], xl[kc][mi], a5[mi]);
    }
    __builtin_amdgcn_s_setprio(0);
    if (g5 < 3) w5load(g5 + 1);  // overlap next W5 with epi + barrier + L6
#pragma unroll
    for (int mi = 0; mi < 2; ++mi) {
      Oct o = epi_pack(a5[mi], hb);
      epi_store_lds(o, zbuf, zbuf + 8192, ((w * 2 + hb) * 2 + mi) * 64, p31);
    }
    w6load(g5, 0, cwh, cwl);  // issue before barrier so latency hides under it
    __syncthreads();          // z5[g5&1] ready (dbuf: WAR across groups is barrier-ordered)
    // ---- L6 partial accumulate over this 128-k chunk, 1-deep W pipeline
#pragma unroll
    for (int kc = 0; kc < 8; ++kc) {
      if (kc < 7) w6load(g5, kc + 1, nwh, nwl);
      bf16x8 zxh[2], zxl[2];
#pragma unroll
      for (int mi = 0; mi < 2; ++mi) {
        const bf16_t* xp = zbuf + ((kc * 2 + mi) * 64 + lane) * 8;
        zxh[mi] = *(const bf16x8*)xp;
        zxl[mi] = *(const bf16x8*)(xp + 8192);
      }
      __builtin_amdgcn_s_setprio(1);
#pragma unroll
      for (int s = 0; s < 2; ++s)
#pragma unroll
        for (int mi = 0; mi < 2; ++mi) z6a[s][mi] = MFMA32(cwh[s], zxh[mi], z6a[s][mi]);
#pragma unroll
      for (int s = 0; s < 2; ++s)
#pragma unroll
        for (int mi = 0; mi < 2; ++mi) z6a[s][mi] = MFMA32(cwl[s], zxh[mi], z6a[s][mi]);
#pragma unroll
      for (int s = 0; s < 2; ++s)
#pragma unroll
        for (int mi = 0; mi < 2; ++mi) z6a[s][mi] = MFMA32(cwh[s], zxl[mi], z6a[s][mi]);
      __builtin_amdgcn_s_setprio(0);
#pragma unroll
      for (int s = 0; s < 2; ++s) { cwh[s] = nwh[s]; cwl[s] = nwl[s]; }
    }
  }
  __syncthreads();  // all phase-A LDS reads done
  // ---- z6 epilogue -> smem [0,32768): hi [0,16384), lo [16384,32768)
#pragma unroll
  for (int s = 0; s < 2; ++s) {
    int kcb = (w * 2 + s) * 2 + hb;
#pragma unroll
    for (int mi = 0; mi < 2; ++mi) {
      Oct o = epi_pack(z6a[s][mi], hb);
      epi_store_lds(o, smem, smem + 16384, (kcb * 2 + mi) * 64, p31);
    }
  }
  // prefetch W7 kc=0 under the barrier
  bf16x8 a7wh, a7wl, n7h, n7l;
  {
    size_t wo = ((size_t)(w * 16) * 64 + lane) * 8;
    a7wh = *(const bf16x8*)(W7h + wo);
    a7wl = *(const bf16x8*)(W7l + wo);
  }
  __syncthreads();
  // ---- L7: wave strip w, K=256, 1-deep W pipeline
  f32x16 a7[2];
  binit2(a7, b7, w * 32, hb);
#pragma unroll
  for (int kc = 0; kc < 16; ++kc) {
    if (kc < 15) {
      size_t wo = ((size_t)(w * 16 + kc + 1) * 64 + lane) * 8;
      n7h = *(const bf16x8*)(W7h + wo);
      n7l = *(const bf16x8*)(W7l + wo);
    }
    bf16x8 zxh[2], zxl[2];
#pragma unroll
    for (int mi = 0; mi < 2; ++mi) {
      const bf16_t* xp = smem + ((kc * 2 + mi) * 64 + lane) * 8;
      zxh[mi] = *(const bf16x8*)xp;
      zxl[mi] = *(const bf16x8*)(xp + 16384);
    }
    __builtin_amdgcn_s_setprio(1);
#pragma unroll
    for (int mi = 0; mi < 2; ++mi) a7[mi] = MFMA32(a7wh, zxh[mi], a7[mi]);
#pragma unroll
    for (int mi = 0; mi < 2; ++mi) a7[mi] = MFMA32(a7wl, zxh[mi], a7[mi]);
#pragma unroll
    for (int mi = 0; mi < 2; ++mi) a7[mi] = MFMA32(a7wh, zxl[mi], a7[mi]);
    __builtin_amdgcn_s_setprio(0);
    a7wh = n7h; a7wl = n7l;
  }
  // ---- L8: dot with w8
  float w8v[16];
#pragma unroll
  for (int r = 0; r < 16; ++r) w8v[r] = w8[w * 32 + 8 * (r >> 2) + 4 * hb + (r & 3)];
#pragma unroll
  for (int mi = 0; mi < 2; ++mi) {
    float s = 0.f;
#pragma unroll
    for (int r = 0; r < 16; ++r) s = fmaf(relu(a7[mi][r]), w8v[r], s);
    s += __shfl_xor(s, 32);
    if (hb == 0) sp[w][mi * 32 + p31] = s;
  }
  __syncthreads();
  if (tid < 64)
    out[b * 64 + tid] = sp[0][tid] + sp[1][tid] + sp[2][tid] + sp[3][tid] + b8v[0];
}

extern "C" void kernel_launch(void* const* d_in, const int* in_sizes, int n_in,
                              void* d_out, int out_size, void* d_ws, size_t ws_size,
                              hipStream_t stream) {
  const float* x  = (const float*)d_in[0];
  const float* W1 = (const float*)d_in[1];  const float* b1 = (const float*)d_in[2];
  const float* W2 = (const float*)d_in[3];  const float* b2 = (const float*)d_in[4];
  const float* W3 = (const float*)d_in[5];  const float* b3 = (const float*)d_in[6];
  const float* W4 = (const float*)d_in[7];  const float* b4 = (const float*)d_in[8];
  const float* W5 = (const float*)d_in[9];  const float* b5 = (const float*)d_in[10];
  const float* W6 = (const float*)d_in[11]; const float* b6 = (const float*)d_in[12];
  const float* W7 = (const float*)d_in[13]; const float* b7 = (const float*)d_in[14];
  const float* W8 = (const float*)d_in[15]; const float* b8 = (const float*)d_in[16];
  float* out = (float*)d_out;

  // Workspace overlays:
  //   h2 pair [128,136)+[136,144)  L2->kl34max,mega2
  //   h1 pair [144,152)+[152,160)  k1a->L2
  //   gpart [208,210), g/c5 [210,..), weight frags after
  const size_t MB = 1ull << 20;
  char* ws = (char*)d_ws;
  bf16_t* h2h = (bf16_t*)(ws + 128 * MB);  bf16_t* h2l = (bf16_t*)(ws + 136 * MB);
  bf16_t* h1h = (bf16_t*)(ws + 144 * MB);  bf16_t* h1l = (bf16_t*)(ws + 152 * MB);
  float* gpart = (float*)(ws + 208 * MB);
  float* g     = (float*)(ws + 210 * MB);
  float* c5    = (float*)(ws + 210 * MB + 4096);
  char* wb = ws + 210 * MB + 65536;
  bf16_t* W2h = (bf16_t*)(wb);             bf16_t* W2l = (bf16_t*)(wb + 8192);
  bf16_t* W3h = (bf16_t*)(wb + 16384);     bf16_t* W3l = (bf16_t*)(wb + 32768);
  bf16_t* W4h = (bf16_t*)(wb + 49152);     bf16_t* W4l = (bf16_t*)(wb + 311296);
  bf16_t* W5h = (bf16_t*)(wb + 573440);    bf16_t* W5l = (bf16_t*)(wb + 638976);
  bf16_t* W6h = (bf16_t*)(wb + 704512);    bf16_t* W6l = (bf16_t*)(wb + 966656);
  bf16_t* W7h = (bf16_t*)(wb + 1228800);   bf16_t* W7l = (bf16_t*)(wb + 1294336);

  hipMemsetAsync(g, 0, 1024 * sizeof(float), stream);  // max identity (relu outputs >= 0)

  PrepAll pa;
  pa.seg[0] = {W2, W2h, W2l, 64, 64, 2};
  pa.seg[1] = {W3, W3h, W3l, 64, 64, 4};
  pa.seg[2] = {W4, W4h, W4l, 128, 128, 64};
  pa.seg[3] = {W5, W5h, W5l, 1088, 64, 16};   // W5[:, :64]
  pa.seg[4] = {W6, W6h, W6l, 512, 512, 64};
  pa.seg[5] = {W7, W7h, W7l, 256, 256, 16};
  kprep<<<166, 256, 0, stream>>>(pa);

  k1a<<<256, 256, 0, stream>>>(x, W1, b1, h1h, h1l);
  gemmS<2, 64, 0><<<dim3(256, 1), 256, 0, stream>>>(
      h1h, h1l, W2h, W2l, b2, 4, h2h, h2l, nullptr, nullptr, nullptr);        // L2
  kl34max<<<512, 256, 0, stream>>>(h2h, h2l, W3h, W3l, b3, W4h, W4l, b4, gpart);  // L3+L4+max
  kgmax<<<32, 256, 0, stream>>>(gpart, g);
  kc5<<<16, 256, 0, stream>>>(W5, b5, g, c5);
  mega2<<<1024, 256, 0, stream>>>(h2h, h2l, W5h, W5l, c5, W6h, W6l, b6,
                                  W7h, W7l, b7, W8, b8, out);                 // L5..L8 fused
}

// Round 7
// 305.520 us; speedup vs baseline: 1.1230x; 1.0041x over previous
//
#include <hip/hip_runtime.h>

#define NPTS 65536

typedef __bf16 bf16_t;
typedef __bf16 bf16x8 __attribute__((ext_vector_type(8)));
typedef float f32x16 __attribute__((ext_vector_type(16)));

#define MFMA32(A, B, C) __builtin_amdgcn_mfma_f32_32x32x16_bf16(A, B, C, 0, 0, 0)

__device__ __forceinline__ float relu(float v) { return v > 0.f ? v : 0.f; }

// ======================================================================
// Layouts (128-pt blocks, 4 mi slots):
// Activation (C ch): octet idx = ((b*(C/16)+kc)*4+mi)*64 + l
//   point = b*128 + mi*32 + (l&31); channel = kc*16 + (l>>5)*8 + j
// Weight (N x K): octet idx = (st*(K/16)+kc)*64 + l; n = st*32+(l&31); k = kc*16+(l>>5)*8+j
// ======================================================================

struct PrepSeg { const float* src; bf16_t* h; bf16_t* l; int SW; int K; int nblk; };
struct PrepAll { PrepSeg seg[6]; };

__global__ __launch_bounds__(256) void kprep(PrepAll pa) {
  int blk = blockIdx.x, i = 0;
  while (blk >= pa.seg[i].nblk) { blk -= pa.seg[i].nblk; ++i; }
  const PrepSeg sg = pa.seg[i];
  int t8 = blk * 256 + threadIdx.x;
  int l = t8 & 63;
  int rest = t8 >> 6;
  int NKC = sg.K >> 4;
  int kc = rest % NKC, st = rest / NKC;
  int n = st * 32 + (l & 31);
  int k0 = kc * 16 + (l >> 5) * 8;
  const float* src = sg.src + (size_t)n * sg.SW + k0;
  bf16x8 hv, lv;
#pragma unroll
  for (int j = 0; j < 8; ++j) {
    float v = src[j];
    bf16_t h = (bf16_t)v;
    hv[j] = h; lv[j] = (bf16_t)(v - (float)h);
  }
  *(bf16x8*)(sg.h + (size_t)t8 * 8) = hv;
  *(bf16x8*)(sg.l + (size_t)t8 * 8) = lv;
}

// ============ k1a: h1 = relu(x@W1.T+b1) in activation order
__global__ __launch_bounds__(256, 2) void k1a(
    const float* __restrict__ x, const float* __restrict__ W1, const float* __restrict__ b1,
    bf16_t* __restrict__ h1h, bf16_t* __restrict__ h1l) {
  int p = blockIdx.x * 256 + threadIdx.x;
  float x0 = x[p * 3 + 0], x1 = x[p * 3 + 1], x2 = x[p * 3 + 2];
  int b = p >> 7, mi = (p >> 5) & 3, p31 = p & 31;
#pragma unroll
  for (int kc = 0; kc < 4; ++kc)
#pragma unroll
    for (int hbw = 0; hbw < 2; ++hbw) {
      bf16x8 hv, lv;
#pragma unroll
      for (int j = 0; j < 8; ++j) {
        int c = kc * 16 + hbw * 8 + j;
        float v = relu(fmaf(W1[c * 3], x0, fmaf(W1[c * 3 + 1], x1, fmaf(W1[c * 3 + 2], x2, b1[c]))));
        bf16_t h = (bf16_t)v;
        hv[j] = h; lv[j] = (bf16_t)(v - (float)h);
      }
      size_t off = (((size_t)(b * 4 + kc) * 4 + mi) * 64 + hbw * 32 + p31) * 8;
      *(bf16x8*)(h1h + off) = hv;
      *(bf16x8*)(h1l + off) = lv;
    }
}

// ============ shared epilogue helpers (used by gemmS, kl34max, mega2)
struct Oct { bf16x8 h0, l0, h1, l1; };
__device__ __forceinline__ Oct epi_pack(const f32x16& accv, int hb) {
  float a[16], rcv[8];
#pragma unroll
  for (int r = 0; r < 16; ++r) a[r] = relu(accv[r]);
#pragma unroll
  for (int j = 0; j < 8; ++j) rcv[j] = __shfl_xor(hb ? a[j] : a[8 + j], 32);
  float o0[8], o1[8];
#pragma unroll
  for (int j = 0; j < 4; ++j) {
    o0[j]     = hb ? rcv[j]     : a[j];
    o0[4 + j] = hb ? a[8 + j]   : rcv[j];
    o1[j]     = hb ? rcv[4 + j] : a[4 + j];
    o1[4 + j] = hb ? a[12 + j]  : rcv[4 + j];
  }
  Oct o;
#pragma unroll
  for (int j = 0; j < 8; ++j) {
    bf16_t x0 = (bf16_t)o0[j]; o.h0[j] = x0; o.l0[j] = (bf16_t)(o0[j] - (float)x0);
    bf16_t x1 = (bf16_t)o1[j]; o.h1[j] = x1; o.l1[j] = (bf16_t)(o1[j] - (float)x1);
  }
  return o;
}

__device__ __forceinline__ void epi_store_lds(const Oct& o, bf16_t* H, bf16_t* L, int ob, int p31) {
  *(bf16x8*)(H + (ob + p31) * 8)      = o.h0;
  *(bf16x8*)(H + (ob + 32 + p31) * 8) = o.h1;
  *(bf16x8*)(L + (ob + p31) * 8)      = o.l0;
  *(bf16x8*)(L + (ob + 32 + p31) * 8) = o.l1;
}

__device__ __forceinline__ void binit2(f32x16 acc[2], const float* bias, int base, int hb) {
#pragma unroll
  for (int r = 0; r < 16; ++r) {
    float bv = bias[base + 8 * (r >> 2) + 4 * hb + (r & 3)];
    acc[0][r] = bv; acc[1][r] = bv;
  }
}

// ============ gemmS: D = W·X^T, 3-term split 32x32x16 bf16 MFMA (L2 only now)
template <int PB, int K, int MODE>
__global__ __launch_bounds__(256, 3) void gemmS(
    const bf16_t* __restrict__ Ah, const bf16_t* __restrict__ Al,
    const bf16_t* __restrict__ Wh, const bf16_t* __restrict__ Wl,
    const float* __restrict__ bias, int nko,
    bf16_t* __restrict__ Oh, bf16_t* __restrict__ Ol,
    float* __restrict__ aux, const float* __restrict__ w8, const float* __restrict__ b8) {
  constexpr int WC = 4 / PB;
  constexpr int NKC = K / 16;
  constexpr int KG = 2;
  constexpr int NG = NKC / KG;
  __shared__ bf16_t smem[2][PB][2][KG * 2048];

  int tid = threadIdx.x;
  int lane = tid & 63;
  int w = __builtin_amdgcn_readfirstlane(tid >> 6);
  int rg = w / WC, cw = w % WC;
  int hb = lane >> 5, p31 = lane & 31;
  int bx = blockIdx.x;
  int st0 = blockIdx.y * WC + cw;
  int bblk = bx * PB + rg;

  f32x16 acc[4];
#pragma unroll
  for (int r = 0; r < 16; ++r) {
    float bv = bias[st0 * 32 + 8 * (r >> 2) + 4 * hb + (r & 3)];
#pragma unroll
    for (int mi = 0; mi < 4; ++mi) acc[mi][r] = bv;
  }

  auto stage = [&](int buf, int g) {
#pragma unroll
    for (int i = 0; i < PB * 4; ++i) {
      int u = i * 256 + tid;
      int rgs = u >> 10, rem = u & 1023;
      int t = rem >> 9, inner = rem & 511;
      const bf16_t* src = (t ? Al : Ah) +
          ((size_t)(bx * PB + rgs) * NKC + g * KG) * 2048 + inner * 8;
      *(bf16x8*)&smem[buf][rgs][t][inner * 8] = *(const bf16x8*)src;
    }
  };

  bf16x8 wch[KG], wcl[KG], wnh[KG], wnl[KG];
  auto wload = [&](int g, bf16x8* h, bf16x8* l) {
#pragma unroll
    for (int kcl = 0; kcl < KG; ++kcl) {
      size_t wo = (((size_t)st0 * NKC + g * KG + kcl) * 64 + lane) * 8;
      h[kcl] = *(const bf16x8*)(Wh + wo);
      l[kcl] = *(const bf16x8*)(Wl + wo);
    }
  };

  auto compute = [&](int buf, bf16x8* h, bf16x8* l) {
#pragma unroll
    for (int kcl = 0; kcl < KG; ++kcl)
#pragma unroll
      for (int mi = 0; mi < 4; ++mi) {
        const bf16_t* xp = &smem[buf][rg][0][((kcl * 4 + mi) * 64 + lane) * 8];
        bf16x8 xh = *(const bf16x8*)xp;
        bf16x8 xl = *(const bf16x8*)(xp + KG * 2048);
        acc[mi] = MFMA32(h[kcl], xh, acc[mi]);
        acc[mi] = MFMA32(l[kcl], xh, acc[mi]);
        acc[mi] = MFMA32(h[kcl], xl, acc[mi]);
      }
  };

  stage(0, 0);
  wload(0, wch, wcl);
  for (int g = 0; g < NG; ++g) {
    __syncthreads();
    if (g + 1 < NG) {
      stage((g + 1) & 1, g + 1);
      wload(g + 1, wnh, wnl);
    }
    compute(g & 1, wch, wcl);
#pragma unroll
    for (int kcl = 0; kcl < KG; ++kcl) { wch[kcl] = wnh[kcl]; wcl[kcl] = wnl[kcl]; }
  }

  if constexpr (MODE == 0) {
#pragma unroll
    for (int mi = 0; mi < 4; ++mi) {
      Oct o = epi_pack(acc[mi], hb);
      int kco = st0 * 2 + hb;
      size_t ob = ((size_t)(bblk * nko + kco) * 4 + mi) * 64;
      *(bf16x8*)(Oh + (ob + p31) * 8)      = o.h0;
      *(bf16x8*)(Ol + (ob + p31) * 8)      = o.l0;
      *(bf16x8*)(Oh + (ob + 32 + p31) * 8) = o.h1;
      *(bf16x8*)(Ol + (ob + 32 + p31) * 8) = o.l1;
    }
  } else if constexpr (MODE == 1) {
#pragma unroll
    for (int r = 0; r < 16; ++r) {
      float m = relu(acc[0][r]);
#pragma unroll
      for (int mi = 1; mi < 4; ++mi) m = fmaxf(m, relu(acc[mi][r]));
#pragma unroll
      for (int off = 1; off < 32; off <<= 1) m = fmaxf(m, __shfl_xor(m, off));
      if (p31 == 0)
        aux[(size_t)bx * 1024 + st0 * 32 + 8 * (r >> 2) + 4 * hb + (r & 3)] = m;
    }
  } else {
    __shared__ float sp[4][128];
    float w8v[16];
#pragma unroll
    for (int r = 0; r < 16; ++r) w8v[r] = w8[st0 * 32 + 8 * (r >> 2) + 4 * hb + (r & 3)];
#pragma unroll
    for (int mi = 0; mi < 4; ++mi) {
      float s = 0.f;
#pragma unroll
      for (int r = 0; r < 16; ++r) s = fmaf(relu(acc[mi][r]), w8v[r], s);
      s += __shfl_xor(s, 32);
      if (hb == 0) sp[w][mi * 32 + p31] = s;
    }
    __syncthreads();
    if (tid < 128)
      aux[(size_t)bx * 128 + tid] = sp[0][tid] + sp[1][tid] + sp[2][tid] + sp[3][tid] + b8[0];
  }
}

// ============ kl34max v2: FUSED L3+L4, TWO 128-pt tiles per block (512 thr, 8 waves,
// 128 KB LDS, 1 block/CU -> occupancy unchanged at 8 waves/CU, grid 256 = exactly
// 1 round, zero tail).
//   Waves 0-3 own tile A (pt-block 2bx), waves 4-7 own tile B (2bx+1).
//   Phase 2: wave pairs (w, w+4) load the SAME W4 line -> one L2 miss serves both
//   (halves logical W4 traffic: 256 x 512 KB = 134 MB) and while the missing wave
//   stalls its SIMD co-resident computes. Per-tile MFMA order identical -> bit-exact.
__global__ __launch_bounds__(512, 1) void kl34max(
    const bf16_t* __restrict__ h2h, const bf16_t* __restrict__ h2l,
    const bf16_t* __restrict__ W3h, const bf16_t* __restrict__ W3l,
    const float* __restrict__ b3,
    const bf16_t* __restrict__ Wh, const bf16_t* __restrict__ Wl,
    const float* __restrict__ bias, float* __restrict__ gpart) {
  __shared__ __align__(16) bf16_t sA[65536];  // tile t at t*32768: hi [0,16384), lo [16384,32768)
  int tid = threadIdx.x, lane = tid & 63;
  int w = __builtin_amdgcn_readfirstlane(tid >> 6);   // 0..7
  int w3 = w & 3, t = w >> 2;                         // strip-slot, tile
  int hb = lane >> 5, p31 = lane & 31;
  int bx = blockIdx.x;
  int pb = bx * 2 + t;                                // this wave-group's 128-pt block
  int rot = (bx >> 2) & 7;
  bf16_t* sT = sA + t * 32768;

  // ---- phase 1: y3(tile t) = relu(h2@W3.T+b3) -> LDS. h2 B-frags for mi=w3.
  bf16x8 hx[4], lx[4];
#pragma unroll
  for (int kc = 0; kc < 4; ++kc) {
    size_t so = (((size_t)(pb * 4 + kc) * 4 + w3) * 64 + lane) * 8;
    hx[kc] = *(const bf16x8*)(h2h + so);
    lx[kc] = *(const bf16x8*)(h2l + so);
  }
#pragma unroll
  for (int spr = 0; spr < 2; ++spr) {  // strip pairs (0,1), (2,3) of y3's 4 strips
    f32x16 a3[2];
#pragma unroll
    for (int s = 0; s < 2; ++s) {
      int st = spr * 2 + s;
#pragma unroll
      for (int r = 0; r < 16; ++r)
        a3[s][r] = b3[st * 32 + 8 * (r >> 2) + 4 * hb + (r & 3)];
    }
#pragma unroll
    for (int kc = 0; kc < 4; ++kc)
#pragma unroll
      for (int s = 0; s < 2; ++s) {
        int st = spr * 2 + s;
        size_t wo = ((size_t)(st * 4 + kc) * 64 + lane) * 8;  // same addr across waves -> L1
        bf16x8 wh3 = *(const bf16x8*)(W3h + wo);
        bf16x8 wl3 = *(const bf16x8*)(W3l + wo);
        a3[s] = MFMA32(wh3, hx[kc], a3[s]);
        a3[s] = MFMA32(wl3, hx[kc], a3[s]);
        a3[s] = MFMA32(wh3, lx[kc], a3[s]);
      }
#pragma unroll
    for (int s = 0; s < 2; ++s) {
      int st = spr * 2 + s;
      Oct o = epi_pack(a3[s], hb);
      epi_store_lds(o, sT, sT + 16384, ((st * 2 + hb) * 4 + w3) * 64, p31);
    }
  }
  __syncthreads();

  // ---- phase 2: L4 sweep; wave pair (w3 fixed, t=0/1) shares weight lines.
#pragma unroll 1
  for (int j = 0; j < 8; ++j) {
    int st = ((j + rot) & 7) * 4 + w3;
    bf16x8 cwh, cwl, nwh, nwl;
    {
      size_t wo = ((size_t)(st * 8) * 64 + lane) * 8;
      cwh = *(const bf16x8*)(Wh + wo);
      cwl = *(const bf16x8*)(Wl + wo);
    }
    f32x16 acc[4];
#pragma unroll
    for (int r = 0; r < 16; ++r) {
      float bv = bias[st * 32 + 8 * (r >> 2) + 4 * hb + (r & 3)];
#pragma unroll
      for (int mi = 0; mi < 4; ++mi) acc[mi][r] = bv;
    }
#pragma unroll
    for (int kc = 0; kc < 8; ++kc) {
      if (kc < 7) {
        size_t wo = ((size_t)(st * 8 + kc + 1) * 64 + lane) * 8;
        nwh = *(const bf16x8*)(Wh + wo);
        nwl = *(const bf16x8*)(Wl + wo);
      }
      __builtin_amdgcn_s_setprio(1);
#pragma unroll
      for (int mi = 0; mi < 4; ++mi) {
        const bf16_t* xp = sT + ((kc * 4 + mi) * 64 + lane) * 8;
        bf16x8 xh = *(const bf16x8*)xp;
        bf16x8 xl = *(const bf16x8*)(xp + 16384);
        acc[mi] = MFMA32(cwh, xh, acc[mi]);
        acc[mi] = MFMA32(cwl, xh, acc[mi]);
        acc[mi] = MFMA32(cwh, xl, acc[mi]);
      }
      __builtin_amdgcn_s_setprio(0);
      cwh = nwh; cwl = nwl;
    }
#pragma unroll
    for (int r = 0; r < 16; ++r) {
      float m = fmaxf(fmaxf(acc[0][r], acc[1][r]), fmaxf(acc[2][r], acc[3][r]));
      m = fmaxf(m, 0.f);  // relu folded into the max
#pragma unroll
      for (int off = 1; off < 32; off <<= 1) m = fmaxf(m, __shfl_xor(m, off));
      if (p31 == 0)
        __builtin_nontemporal_store(
            m, gpart + (size_t)pb * 1024 + st * 32 + 8 * (r >> 2) + 4 * hb + (r & 3));
    }
  }
}

// ============ kgmax: g[c] = max over 512 rows of gpart[512][1024]
__global__ __launch_bounds__(256) void kgmax(const float* __restrict__ gpart, float* __restrict__ g) {
  int t = blockIdx.x * 256 + threadIdx.x;  // 8192 threads
  int c = t & 1023, rg = t >> 10;
  const float* gp = gpart + (size_t)rg * 64 * 1024 + c;
  float m = 0.f;
#pragma unroll 8
  for (int r = 0; r < 64; ++r) m = fmaxf(m, gp[(size_t)r * 1024]);
  atomicMax((unsigned int*)(g + c), __float_as_uint(m));  // all values >= 0
}

// ============ kc5: c5[c] = W5[c][64:1088] @ g + b5[c]
__global__ __launch_bounds__(256) void kc5(
    const float* __restrict__ W5, const float* __restrict__ b5,
    const float* __restrict__ g, float* __restrict__ c5) {
  int tid = threadIdx.x;
  int ci = tid >> 3, kg = tid & 7;
  int c = blockIdx.x * 32 + ci;
  const float* wrow = W5 + (size_t)c * 1088 + 64 + kg * 128;
  const float* gp = g + kg * 128;
  float acc = 0.f;
#pragma unroll 8
  for (int k = 0; k < 128; ++k) acc += wrow[k] * gp[k];
#pragma unroll
  for (int off = 1; off <= 4; off <<= 1) acc += __shfl_xor(acc, off);
  if (kg == 0) c5[c] = acc + b5[c];
}

// ======================================================================
// mega2 v2: h2 -> z5 -> z6 -> z7 -> out, 64-pt blocks. h2 B-frags in regs;
// z5 double-buffered in LDS (1 barrier/group); W5/W6/W7 register prefetch
// pipelines; s_setprio around MFMA clusters.
// Internal contract (2 mi slots): octet idx = (kc*2+mi)*64+l;
//   point = mi*32+(l&31), channel = kc*16+(l>>5)*8+j.
// ======================================================================

__global__ __launch_bounds__(256, 2) void mega2(
    const bf16_t* __restrict__ h2gh, const bf16_t* __restrict__ h2gl,
    const bf16_t* __restrict__ W5h, const bf16_t* __restrict__ W5l, const float* __restrict__ c5,
    const bf16_t* __restrict__ W6h, const bf16_t* __restrict__ W6l, const float* __restrict__ b6,
    const bf16_t* __restrict__ W7h, const bf16_t* __restrict__ W7l, const float* __restrict__ b7,
    const float* __restrict__ w8, const float* __restrict__ b8v, float* __restrict__ out) {
  // LDS: phase A: z5 dbuf = [0,16384) + [16384,32768) elems (each: hi 8192 | lo 8192)
  //      phase B: z6 pair [0,32768): hi [0,16384), lo [16384,32768)
  __shared__ __align__(16) bf16_t smem[32768];
  __shared__ float sp[4][64];
  int tid = threadIdx.x, lane = tid & 63;
  int w = __builtin_amdgcn_readfirstlane(tid >> 6);
  int hb = lane >> 5, p31 = lane & 31;
  int b = blockIdx.x;
  int B = b >> 1, half = b & 1;   // R8 h2 layout: 128-pt block B, 64-pt half

  // ---- h2 B-fragments -> registers (reused by all 4 L5 groups; coalesced)
  bf16x8 xh[4][2], xl[4][2];
#pragma unroll
  for (int kc = 0; kc < 4; ++kc)
#pragma unroll
    for (int mi = 0; mi < 2; ++mi) {
      size_t so = (((size_t)((B * 4 + kc) * 4 + half * 2 + mi)) * 64 + lane) * 8;
      xh[kc][mi] = *(const bf16x8*)(h2gh + so);
      xl[kc][mi] = *(const bf16x8*)(h2gl + so);
    }

  // z6 accumulators: wave owns strips {2w, 2w+1} (64 ch) x 64 pts
  f32x16 z6a[2][2];
#pragma unroll
  for (int s = 0; s < 2; ++s)
#pragma unroll
    for (int r = 0; r < 16; ++r) {
      float bv = b6[(w * 2 + s) * 32 + 8 * (r >> 2) + 4 * hb + (r & 3)];
      z6a[s][0][r] = bv; z6a[s][1][r] = bv;
    }

  bf16x8 w5h[4], w5l[4];
  auto w5load = [&](int g) {
#pragma unroll
    for (int kc = 0; kc < 4; ++kc) {
      size_t wo = (((size_t)(g * 4 + w) * 4 + kc) * 64 + lane) * 8;
      w5h[kc] = *(const bf16x8*)(W5h + wo);
      w5l[kc] = *(const bf16x8*)(W5l + wo);
    }
  };
  w5load(0);

  bf16x8 cwh[2], cwl[2], nwh[2], nwl[2];
  auto w6load = [&](int g, int kc, bf16x8* hh, bf16x8* ll) {
#pragma unroll
    for (int s = 0; s < 2; ++s) {
      size_t wo = ((size_t)((w * 2 + s) * 32 + g * 8 + kc) * 64 + lane) * 8;
      hh[s] = *(const bf16x8*)(W6h + wo);
      ll[s] = *(const bf16x8*)(W6l + wo);
    }
  };

  for (int g5 = 0; g5 < 4; ++g5) {
    bf16_t* zbuf = smem + (g5 & 1) * 16384;
    // ---- L5 strip: z5 chans [(g5*4+w)*32, +32), K=64 from h2 regs
    int st5 = g5 * 4 + w;
    f32x16 a5[2];
    binit2(a5, c5, st5 * 32, hb);
    __builtin_amdgcn_s_setprio(1);
#pragma unroll
    for (int kc = 0; kc < 4; ++kc) {
#pragma unroll
      for (int mi = 0; mi < 2; ++mi) a5[mi] = MFMA32(w5h[kc], xh[kc][mi], a5[mi]);
#pragma unroll
      for (int mi = 0; mi < 2; ++mi) a5[mi] = MFMA32(w5l[kc], xh[kc][mi], a5[mi]);
#pragma unroll
      for (int mi = 0; mi < 2; ++mi) a5[mi] = MFMA32(w5h[kc], xl[kc][mi], a5[mi]);
    }
    __builtin_amdgcn_s_setprio(0);
    if (g5 < 3) w5load(g5 + 1);  // overlap next W5 with epi + barrier + L6
#pragma unroll
    for (int mi = 0; mi < 2; ++mi) {
      Oct o = epi_pack(a5[mi], hb);
      epi_store_lds(o, zbuf, zbuf + 8192, ((w * 2 + hb) * 2 + mi) * 64, p31);
    }
    w6load(g5, 0, cwh, cwl);  // issue before barrier so latency hides under it
    __syncthreads();          // z5[g5&1] ready (dbuf: WAR across groups is barrier-ordered)
    // ---- L6 partial accumulate over this 128-k chunk, 1-deep W pipeline
#pragma unroll
    for (int kc = 0; kc < 8; ++kc) {
      if (kc < 7) w6load(g5, kc + 1, nwh, nwl);
      bf16x8 zxh[2], zxl[2];
#pragma unroll
      for (int mi = 0; mi < 2; ++mi) {
        const bf16_t* xp = zbuf + ((kc * 2 + mi) * 64 + lane) * 8;
        zxh[mi] = *(const bf16x8*)xp;
        zxl[mi] = *(const bf16x8*)(xp + 8192);
      }
      __builtin_amdgcn_s_setprio(1);
#pragma unroll
      for (int s = 0; s < 2; ++s)
#pragma unroll
        for (int mi = 0; mi < 2; ++mi) z6a[s][mi] = MFMA32(cwh[s], zxh[mi], z6a[s][mi]);
#pragma unroll
      for (int s = 0; s < 2; ++s)
#pragma unroll
        for (int mi = 0; mi < 2; ++mi) z6a[s][mi] = MFMA32(cwl[s], zxh[mi], z6a[s][mi]);
#pragma unroll
      for (int s = 0; s < 2; ++s)
#pragma unroll
        for (int mi = 0; mi < 2; ++mi) z6a[s][mi] = MFMA32(cwh[s], zxl[mi], z6a[s][mi]);
      __builtin_amdgcn_s_setprio(0);
#pragma unroll
      for (int s = 0; s < 2; ++s) { cwh[s] = nwh[s]; cwl[s] = nwl[s]; }
    }
  }
  __syncthreads();  // all phase-A LDS reads done
  // ---- z6 epilogue -> smem [0,32768): hi [0,16384), lo [16384,32768)
#pragma unroll
  for (int s = 0; s < 2; ++s) {
    int kcb = (w * 2 + s) * 2 + hb;
#pragma unroll
    for (int mi = 0; mi < 2; ++mi) {
      Oct o = epi_pack(z6a[s][mi], hb);
      epi_store_lds(o, smem, smem + 16384, (kcb * 2 + mi) * 64, p31);
    }
  }
  // prefetch W7 kc=0 under the barrier
  bf16x8 a7wh, a7wl, n7h, n7l;
  {
    size_t wo = ((size_t)(w * 16) * 64 + lane) * 8;
    a7wh = *(const bf16x8*)(W7h + wo);
    a7wl = *(const bf16x8*)(W7l + wo);
  }
  __syncthreads();
  // ---- L7: wave strip w, K=256, 1-deep W pipeline
  f32x16 a7[2];
  binit2(a7, b7, w * 32, hb);
#pragma unroll
  for (int kc = 0; kc < 16; ++kc) {
    if (kc < 15) {
      size_t wo = ((size_t)(w * 16 + kc + 1) * 64 + lane) * 8;
      n7h = *(const bf16x8*)(W7h + wo);
      n7l = *(const bf16x8*)(W7l + wo);
    }
    bf16x8 zxh[2], zxl[2];
#pragma unroll
    for (int mi = 0; mi < 2; ++mi) {
      const bf16_t* xp = smem + ((kc * 2 + mi) * 64 + lane) * 8;
      zxh[mi] = *(const bf16x8*)xp;
      zxl[mi] = *(const bf16x8*)(xp + 16384);
    }
    __builtin_amdgcn_s_setprio(1);
#pragma unroll
    for (int mi = 0; mi < 2; ++mi) a7[mi] = MFMA32(a7wh, zxh[mi], a7[mi]);
#pragma unroll
    for (int mi = 0; mi < 2; ++mi) a7[mi] = MFMA32(a7wl, zxh[mi], a7[mi]);
#pragma unroll
    for (int mi = 0; mi < 2; ++mi) a7[mi] = MFMA32(a7wh, zxl[mi], a7[mi]);
    __builtin_amdgcn_s_setprio(0);
    a7wh = n7h; a7wl = n7l;
  }
  // ---- L8: dot with w8
  float w8v[16];
#pragma unroll
  for (int r = 0; r < 16; ++r) w8v[r] = w8[w * 32 + 8 * (r >> 2) + 4 * hb + (r & 3)];
#pragma unroll
  for (int mi = 0; mi < 2; ++mi) {
    float s = 0.f;
#pragma unroll
    for (int r = 0; r < 16; ++r) s = fmaf(relu(a7[mi][r]), w8v[r], s);
    s += __shfl_xor(s, 32);
    if (hb == 0) sp[w][mi * 32 + p31] = s;
  }
  __syncthreads();
  if (tid < 64)
    out[b * 64 + tid] = sp[0][tid] + sp[1][tid] + sp[2][tid] + sp[3][tid] + b8v[0];
}

extern "C" void kernel_launch(void* const* d_in, const int* in_sizes, int n_in,
                              void* d_out, int out_size, void* d_ws, size_t ws_size,
                              hipStream_t stream) {
  const float* x  = (const float*)d_in[0];
  const float* W1 = (const float*)d_in[1];  const float* b1 = (const float*)d_in[2];
  const float* W2 = (const float*)d_in[3];  const float* b2 = (const float*)d_in[4];
  const float* W3 = (const float*)d_in[5];  const float* b3 = (const float*)d_in[6];
  const float* W4 = (const float*)d_in[7];  const float* b4 = (const float*)d_in[8];
  const float* W5 = (const float*)d_in[9];  const float* b5 = (const float*)d_in[10];
  const float* W6 = (const float*)d_in[11]; const float* b6 = (const float*)d_in[12];
  const float* W7 = (const float*)d_in[13]; const float* b7 = (const float*)d_in[14];
  const float* W8 = (const float*)d_in[15]; const float* b8 = (const float*)d_in[16];
  float* out = (float*)d_out;

  // Workspace overlays:
  //   h2 pair [128,136)+[136,144)  L2->kl34max,mega2
  //   h1 pair [144,152)+[152,160)  k1a->L2
  //   gpart [208,210), g/c5 [210,..), weight frags after
  const size_t MB = 1ull << 20;
  char* ws = (char*)d_ws;
  bf16_t* h2h = (bf16_t*)(ws + 128 * MB);  bf16_t* h2l = (bf16_t*)(ws + 136 * MB);
  bf16_t* h1h = (bf16_t*)(ws + 144 * MB);  bf16_t* h1l = (bf16_t*)(ws + 152 * MB);
  float* gpart = (float*)(ws + 208 * MB);
  float* g     = (float*)(ws + 210 * MB);
  float* c5    = (float*)(ws + 210 * MB + 4096);
  char* wb = ws + 210 * MB + 65536;
  bf16_t* W2h = (bf16_t*)(wb);             bf16_t* W2l = (bf16_t*)(wb + 8192);
  bf16_t* W3h = (bf16_t*)(wb + 16384);     bf16_t* W3l = (bf16_t*)(wb + 32768);
  bf16_t* W4h = (bf16_t*)(wb + 49152);     bf16_t* W4l = (bf16_t*)(wb + 311296);
  bf16_t* W5h = (bf16_t*)(wb + 573440);    bf16_t* W5l = (bf16_t*)(wb + 638976);
  bf16_t* W6h = (bf16_t*)(wb + 704512);    bf16_t* W6l = (bf16_t*)(wb + 966656);
  bf16_t* W7h = (bf16_t*)(wb + 1228800);   bf16_t* W7l = (bf16_t*)(wb + 1294336);

  hipMemsetAsync(g, 0, 1024 * sizeof(float), stream);  // max identity (relu outputs >= 0)

  PrepAll pa;
  pa.seg[0] = {W2, W2h, W2l, 64, 64, 2};
  pa.seg[1] = {W3, W3h, W3l, 64, 64, 4};
  pa.seg[2] = {W4, W4h, W4l, 128, 128, 64};
  pa.seg[3] = {W5, W5h, W5l, 1088, 64, 16};   // W5[:, :64]
  pa.seg[4] = {W6, W6h, W6l, 512, 512, 64};
  pa.seg[5] = {W7, W7h, W7l, 256, 256, 16};
  kprep<<<166, 256, 0, stream>>>(pa);

  k1a<<<256, 256, 0, stream>>>(x, W1, b1, h1h, h1l);
  gemmS<2, 64, 0><<<dim3(256, 1), 256, 0, stream>>>(
      h1h, h1l, W2h, W2l, b2, 4, h2h, h2l, nullptr, nullptr, nullptr);        // L2
  kl34max<<<256, 512, 0, stream>>>(h2h, h2l, W3h, W3l, b3, W4h, W4l, b4, gpart);  // L3+L4+max
  kgmax<<<32, 256, 0, stream>>>(gpart, g);
  kc5<<<16, 256, 0, stream>>>(W5, b5, g, c5);
  mega2<<<1024, 256, 0, stream>>>(h2h, h2l, W5h, W5l, c5, W6h, W6l, b6,
                                  W7h, W7l, b7, W8, b8, out);                 // L5..L8 fused
}

// Round 8
// 267.022 us; speedup vs baseline: 1.2849x; 1.1442x over previous
//
#include <hip/hip_runtime.h>

#define NPTS 65536

typedef __bf16 bf16_t;
typedef __bf16 bf16x8 __attribute__((ext_vector_type(8)));
typedef float f32x16 __attribute__((ext_vector_type(16)));

#define MFMA32(A, B, C) __builtin_amdgcn_mfma_f32_32x32x16_bf16(A, B, C, 0, 0, 0)

__device__ __forceinline__ float relu(float v) { return v > 0.f ? v : 0.f; }

// ======================================================================
// Layouts (128-pt blocks, 4 mi slots):
// Activation (C ch): octet idx = ((b*(C/16)+kc)*4+mi)*64 + l
//   point = b*128 + mi*32 + (l&31); channel = kc*16 + (l>>5)*8 + j
// Weight (N x K): octet idx = (st*(K/16)+kc)*64 + l; n = st*32+(l&31); k = kc*16+(l>>5)*8+j
// ======================================================================

struct PrepSeg { const float* src; bf16_t* h; bf16_t* l; int SW; int K; int nblk; };
struct PrepAll { PrepSeg seg[6]; };

__global__ __launch_bounds__(256) void kprep(PrepAll pa) {
  int blk = blockIdx.x, i = 0;
  while (blk >= pa.seg[i].nblk) { blk -= pa.seg[i].nblk; ++i; }
  const PrepSeg sg = pa.seg[i];
  int t8 = blk * 256 + threadIdx.x;
  int l = t8 & 63;
  int rest = t8 >> 6;
  int NKC = sg.K >> 4;
  int kc = rest % NKC, st = rest / NKC;
  int n = st * 32 + (l & 31);
  int k0 = kc * 16 + (l >> 5) * 8;
  const float* src = sg.src + (size_t)n * sg.SW + k0;
  bf16x8 hv, lv;
#pragma unroll
  for (int j = 0; j < 8; ++j) {
    float v = src[j];
    bf16_t h = (bf16_t)v;
    hv[j] = h; lv[j] = (bf16_t)(v - (float)h);
  }
  *(bf16x8*)(sg.h + (size_t)t8 * 8) = hv;
  *(bf16x8*)(sg.l + (size_t)t8 * 8) = lv;
}

// ============ k1a: h1 = relu(x@W1.T+b1) in activation order
__global__ __launch_bounds__(256, 2) void k1a(
    const float* __restrict__ x, const float* __restrict__ W1, const float* __restrict__ b1,
    bf16_t* __restrict__ h1h, bf16_t* __restrict__ h1l) {
  int p = blockIdx.x * 256 + threadIdx.x;
  float x0 = x[p * 3 + 0], x1 = x[p * 3 + 1], x2 = x[p * 3 + 2];
  int b = p >> 7, mi = (p >> 5) & 3, p31 = p & 31;
#pragma unroll
  for (int kc = 0; kc < 4; ++kc)
#pragma unroll
    for (int hbw = 0; hbw < 2; ++hbw) {
      bf16x8 hv, lv;
#pragma unroll
      for (int j = 0; j < 8; ++j) {
        int c = kc * 16 + hbw * 8 + j;
        float v = relu(fmaf(W1[c * 3], x0, fmaf(W1[c * 3 + 1], x1, fmaf(W1[c * 3 + 2], x2, b1[c]))));
        bf16_t h = (bf16_t)v;
        hv[j] = h; lv[j] = (bf16_t)(v - (float)h);
      }
      size_t off = (((size_t)(b * 4 + kc) * 4 + mi) * 64 + hbw * 32 + p31) * 8;
      *(bf16x8*)(h1h + off) = hv;
      *(bf16x8*)(h1l + off) = lv;
    }
}

// ============ shared epilogue helpers (used by gemmS, kl34max, mega2)
struct Oct { bf16x8 h0, l0, h1, l1; };
__device__ __forceinline__ Oct epi_pack(const f32x16& accv, int hb) {
  float a[16], rcv[8];
#pragma unroll
  for (int r = 0; r < 16; ++r) a[r] = relu(accv[r]);
#pragma unroll
  for (int j = 0; j < 8; ++j) rcv[j] = __shfl_xor(hb ? a[j] : a[8 + j], 32);
  float o0[8], o1[8];
#pragma unroll
  for (int j = 0; j < 4; ++j) {
    o0[j]     = hb ? rcv[j]     : a[j];
    o0[4 + j] = hb ? a[8 + j]   : rcv[j];
    o1[j]     = hb ? rcv[4 + j] : a[4 + j];
    o1[4 + j] = hb ? a[12 + j]  : rcv[4 + j];
  }
  Oct o;
#pragma unroll
  for (int j = 0; j < 8; ++j) {
    bf16_t x0 = (bf16_t)o0[j]; o.h0[j] = x0; o.l0[j] = (bf16_t)(o0[j] - (float)x0);
    bf16_t x1 = (bf16_t)o1[j]; o.h1[j] = x1; o.l1[j] = (bf16_t)(o1[j] - (float)x1);
  }
  return o;
}

__device__ __forceinline__ void epi_store_lds(const Oct& o, bf16_t* H, bf16_t* L, int ob, int p31) {
  *(bf16x8*)(H + (ob + p31) * 8)      = o.h0;
  *(bf16x8*)(H + (ob + 32 + p31) * 8) = o.h1;
  *(bf16x8*)(L + (ob + p31) * 8)      = o.l0;
  *(bf16x8*)(L + (ob + 32 + p31) * 8) = o.l1;
}

__device__ __forceinline__ void binit2(f32x16 acc[2], const float* bias, int base, int hb) {
#pragma unroll
  for (int r = 0; r < 16; ++r) {
    float bv = bias[base + 8 * (r >> 2) + 4 * hb + (r & 3)];
    acc[0][r] = bv; acc[1][r] = bv;
  }
}

// ============ gemmS: D = W·X^T, 3-term split 32x32x16 bf16 MFMA (L2 only now)
template <int PB, int K, int MODE>
__global__ __launch_bounds__(256, 3) void gemmS(
    const bf16_t* __restrict__ Ah, const bf16_t* __restrict__ Al,
    const bf16_t* __restrict__ Wh, const bf16_t* __restrict__ Wl,
    const float* __restrict__ bias, int nko,
    bf16_t* __restrict__ Oh, bf16_t* __restrict__ Ol,
    float* __restrict__ aux, const float* __restrict__ w8, const float* __restrict__ b8) {
  constexpr int WC = 4 / PB;
  constexpr int NKC = K / 16;
  constexpr int KG = 2;
  constexpr int NG = NKC / KG;
  __shared__ bf16_t smem[2][PB][2][KG * 2048];

  int tid = threadIdx.x;
  int lane = tid & 63;
  int w = __builtin_amdgcn_readfirstlane(tid >> 6);
  int rg = w / WC, cw = w % WC;
  int hb = lane >> 5, p31 = lane & 31;
  int bx = blockIdx.x;
  int st0 = blockIdx.y * WC + cw;
  int bblk = bx * PB + rg;

  f32x16 acc[4];
#pragma unroll
  for (int r = 0; r < 16; ++r) {
    float bv = bias[st0 * 32 + 8 * (r >> 2) + 4 * hb + (r & 3)];
#pragma unroll
    for (int mi = 0; mi < 4; ++mi) acc[mi][r] = bv;
  }

  auto stage = [&](int buf, int g) {
#pragma unroll
    for (int i = 0; i < PB * 4; ++i) {
      int u = i * 256 + tid;
      int rgs = u >> 10, rem = u & 1023;
      int t = rem >> 9, inner = rem & 511;
      const bf16_t* src = (t ? Al : Ah) +
          ((size_t)(bx * PB + rgs) * NKC + g * KG) * 2048 + inner * 8;
      *(bf16x8*)&smem[buf][rgs][t][inner * 8] = *(const bf16x8*)src;
    }
  };

  bf16x8 wch[KG], wcl[KG], wnh[KG], wnl[KG];
  auto wload = [&](int g, bf16x8* h, bf16x8* l) {
#pragma unroll
    for (int kcl = 0; kcl < KG; ++kcl) {
      size_t wo = (((size_t)st0 * NKC + g * KG + kcl) * 64 + lane) * 8;
      h[kcl] = *(const bf16x8*)(Wh + wo);
      l[kcl] = *(const bf16x8*)(Wl + wo);
    }
  };

  auto compute = [&](int buf, bf16x8* h, bf16x8* l) {
#pragma unroll
    for (int kcl = 0; kcl < KG; ++kcl)
#pragma unroll
      for (int mi = 0; mi < 4; ++mi) {
        const bf16_t* xp = &smem[buf][rg][0][((kcl * 4 + mi) * 64 + lane) * 8];
        bf16x8 xh = *(const bf16x8*)xp;
        bf16x8 xl = *(const bf16x8*)(xp + KG * 2048);
        acc[mi] = MFMA32(h[kcl], xh, acc[mi]);
        acc[mi] = MFMA32(l[kcl], xh, acc[mi]);
        acc[mi] = MFMA32(h[kcl], xl, acc[mi]);
      }
  };

  stage(0, 0);
  wload(0, wch, wcl);
  for (int g = 0; g < NG; ++g) {
    __syncthreads();
    if (g + 1 < NG) {
      stage((g + 1) & 1, g + 1);
      wload(g + 1, wnh, wnl);
    }
    compute(g & 1, wch, wcl);
#pragma unroll
    for (int kcl = 0; kcl < KG; ++kcl) { wch[kcl] = wnh[kcl]; wcl[kcl] = wnl[kcl]; }
  }

  if constexpr (MODE == 0) {
#pragma unroll
    for (int mi = 0; mi < 4; ++mi) {
      Oct o = epi_pack(acc[mi], hb);
      int kco = st0 * 2 + hb;
      size_t ob = ((size_t)(bblk * nko + kco) * 4 + mi) * 64;
      *(bf16x8*)(Oh + (ob + p31) * 8)      = o.h0;
      *(bf16x8*)(Ol + (ob + p31) * 8)      = o.l0;
      *(bf16x8*)(Oh + (ob + 32 + p31) * 8) = o.h1;
      *(bf16x8*)(Ol + (ob + 32 + p31) * 8) = o.l1;
    }
  } else if constexpr (MODE == 1) {
#pragma unroll
    for (int r = 0; r < 16; ++r) {
      float m = relu(acc[0][r]);
#pragma unroll
      for (int mi = 1; mi < 4; ++mi) m = fmaxf(m, relu(acc[mi][r]));
#pragma unroll
      for (int off = 1; off < 32; off <<= 1) m = fmaxf(m, __shfl_xor(m, off));
      if (p31 == 0)
        aux[(size_t)bx * 1024 + st0 * 32 + 8 * (r >> 2) + 4 * hb + (r & 3)] = m;
    }
  } else {
    __shared__ float sp[4][128];
    float w8v[16];
#pragma unroll
    for (int r = 0; r < 16; ++r) w8v[r] = w8[st0 * 32 + 8 * (r >> 2) + 4 * hb + (r & 3)];
#pragma unroll
    for (int mi = 0; mi < 4; ++mi) {
      float s = 0.f;
#pragma unroll
      for (int r = 0; r < 16; ++r) s = fmaf(relu(acc[mi][r]), w8v[r], s);
      s += __shfl_xor(s, 32);
      if (hb == 0) sp[w][mi * 32 + p31] = s;
    }
    __syncthreads();
    if (tid < 128)
      aux[(size_t)bx * 128 + tid] = sp[0][tid] + sp[1][tid] + sp[2][tid] + sp[3][tid] + b8[0];
  }
}

// ============ kl34max v3: FUSED L3+L4, 2 tiles/block, ASYNC-DMA weight pipeline.
// Phase 2 = 64 flat (j,kc) phases. Per phase the block cooperatively stages one
// 8 KB weight set via global_load_lds (512 thr x 16 B = ONE request per line,
// vs 8 wave-loads before) into a 4-deep LDS quad-buffer; raw s_barrier + counted
// s_waitcnt vmcnt(2) keeps 3 stages in flight (never drains to 0 mid-loop).
// Stage issue is AFTER the barrier so the recycled buffer is provably dead.
// MFMA order/operands bit-identical to v2. LDS = 128K y3 + 32K wq = 160 KiB.
__global__ __launch_bounds__(512, 1) void kl34max(
    const bf16_t* __restrict__ h2h, const bf16_t* __restrict__ h2l,
    const bf16_t* __restrict__ W3h, const bf16_t* __restrict__ W3l,
    const float* __restrict__ b3,
    const bf16_t* __restrict__ Wh, const bf16_t* __restrict__ Wl,
    const float* __restrict__ bias, float* __restrict__ gpart) {
  __shared__ __align__(16) bf16_t sA[81920];  // y3 [0,65536); wq [65536,81920)
  bf16_t* wq = sA + 65536;
  int tid = threadIdx.x, lane = tid & 63;
  int w = __builtin_amdgcn_readfirstlane(tid >> 6);   // 0..7
  int w3 = w & 3, t = w >> 2;                         // compute role: strip-slot, tile
  int sslot = w >> 1, part = w & 1;                   // staging role: strip-slot, h/l
  int hb = lane >> 5, p31 = lane & 31;
  int bx = blockIdx.x;
  int pb = bx * 2 + t;
  int rot = (bx >> 2) & 7;
  bf16_t* sT = sA + t * 32768;

  // ---- phase 1: y3(tile t) = relu(h2@W3.T+b3) -> LDS. h2 B-frags for mi=w3.
  bf16x8 hx[4], lx[4];
#pragma unroll
  for (int kc = 0; kc < 4; ++kc) {
    size_t so = (((size_t)(pb * 4 + kc) * 4 + w3) * 64 + lane) * 8;
    hx[kc] = *(const bf16x8*)(h2h + so);
    lx[kc] = *(const bf16x8*)(h2l + so);
  }
#pragma unroll
  for (int spr = 0; spr < 2; ++spr) {
    f32x16 a3[2];
#pragma unroll
    for (int s = 0; s < 2; ++s) {
      int st = spr * 2 + s;
#pragma unroll
      for (int r = 0; r < 16; ++r)
        a3[s][r] = b3[st * 32 + 8 * (r >> 2) + 4 * hb + (r & 3)];
    }
#pragma unroll
    for (int kc = 0; kc < 4; ++kc)
#pragma unroll
      for (int s = 0; s < 2; ++s) {
        int st = spr * 2 + s;
        size_t wo = ((size_t)(st * 4 + kc) * 64 + lane) * 8;
        bf16x8 wh3 = *(const bf16x8*)(W3h + wo);
        bf16x8 wl3 = *(const bf16x8*)(W3l + wo);
        a3[s] = MFMA32(wh3, hx[kc], a3[s]);
        a3[s] = MFMA32(wl3, hx[kc], a3[s]);
        a3[s] = MFMA32(wh3, lx[kc], a3[s]);
      }
#pragma unroll
    for (int s = 0; s < 2; ++s) {
      int st = spr * 2 + s;
      Oct o = epi_pack(a3[s], hb);
      epi_store_lds(o, sT, sT + 16384, ((st * 2 + hb) * 4 + w3) * 64, p31);
    }
  }
  __syncthreads();  // y3 ready (full barrier; drains everything once)

  // ---- phase 2: async-DMA weight pipeline over 64 (j,kc) phases
  auto issueS = [&](int u) {
    int jj = u >> 3, kc = u & 7;
    int st = ((jj + rot) & 7) * 4 + sslot;
    const bf16_t* W = part ? Wl : Wh;
    const bf16_t* gp = W + ((size_t)(st * 8 + kc) * 64 + lane) * 8;
    bf16_t* lp = wq + (u & 3) * 4096 + sslot * 1024 + part * 512;  // wave-uniform base
    __builtin_amdgcn_global_load_lds(
        (const __attribute__((address_space(1))) void*)gp,
        (__attribute__((address_space(3))) void*)lp, 16, 0, 0);
  };
  issueS(0); issueS(1); issueS(2);

  f32x16 acc[4];
#pragma unroll 1
  for (int u = 0; u < 64; ++u) {
    // wait for stage u (in-order vmcnt: at most the 2 newest may remain)
    if (u <= 61)      asm volatile("s_waitcnt vmcnt(2)" ::: "memory");
    else if (u == 62) asm volatile("s_waitcnt vmcnt(1)" ::: "memory");
    else              asm volatile("s_waitcnt vmcnt(0)" ::: "memory");
    __builtin_amdgcn_sched_barrier(0);
    __builtin_amdgcn_s_barrier();   // raw barrier: no vmcnt drain
    if (u + 3 < 64) issueS(u + 3);  // after barrier: recycled buffer is dead
    int jj = u >> 3, kc = u & 7;
    int st = ((jj + rot) & 7) * 4 + w3;
    if (kc == 0) {
#pragma unroll
      for (int r = 0; r < 16; ++r) {
        float bv = bias[st * 32 + 8 * (r >> 2) + 4 * hb + (r & 3)];
#pragma unroll
        for (int mi = 0; mi < 4; ++mi) acc[mi][r] = bv;
      }
    }
    const bf16_t* wb = wq + (u & 3) * 4096 + w3 * 1024;
    bf16x8 cwh = *(const bf16x8*)(wb + lane * 8);
    bf16x8 cwl = *(const bf16x8*)(wb + 512 + lane * 8);
    __builtin_amdgcn_s_setprio(1);
#pragma unroll
    for (int mi = 0; mi < 4; ++mi) {
      const bf16_t* xp = sT + ((kc * 4 + mi) * 64 + lane) * 8;
      bf16x8 xh = *(const bf16x8*)xp;
      bf16x8 xl = *(const bf16x8*)(xp + 16384);
      acc[mi] = MFMA32(cwh, xh, acc[mi]);
      acc[mi] = MFMA32(cwl, xh, acc[mi]);
      acc[mi] = MFMA32(cwh, xl, acc[mi]);
    }
    __builtin_amdgcn_s_setprio(0);
    if (kc == 7) {
#pragma unroll
      for (int r = 0; r < 16; ++r) {
        float m = fmaxf(fmaxf(acc[0][r], acc[1][r]), fmaxf(acc[2][r], acc[3][r]));
        m = fmaxf(m, 0.f);  // relu folded into the max
#pragma unroll
        for (int off = 1; off < 32; off <<= 1) m = fmaxf(m, __shfl_xor(m, off));
        if (p31 == 0)
          __builtin_nontemporal_store(
              m, gpart + (size_t)pb * 1024 + st * 32 + 8 * (r >> 2) + 4 * hb + (r & 3));
      }
    }
  }
}

// ============ kgmax: g[c] = max over 512 rows of gpart[512][1024]
__global__ __launch_bounds__(256) void kgmax(const float* __restrict__ gpart, float* __restrict__ g) {
  int t = blockIdx.x * 256 + threadIdx.x;  // 8192 threads
  int c = t & 1023, rg = t >> 10;
  const float* gp = gpart + (size_t)rg * 64 * 1024 + c;
  float m = 0.f;
#pragma unroll 8
  for (int r = 0; r < 64; ++r) m = fmaxf(m, gp[(size_t)r * 1024]);
  atomicMax((unsigned int*)(g + c), __float_as_uint(m));  // all values >= 0
}

// ============ kc5: c5[c] = W5[c][64:1088] @ g + b5[c]
__global__ __launch_bounds__(256) void kc5(
    const float* __restrict__ W5, const float* __restrict__ b5,
    const float* __restrict__ g, float* __restrict__ c5) {
  int tid = threadIdx.x;
  int ci = tid >> 3, kg = tid & 7;
  int c = blockIdx.x * 32 + ci;
  const float* wrow = W5 + (size_t)c * 1088 + 64 + kg * 128;
  const float* gp = g + kg * 128;
  float acc = 0.f;
#pragma unroll 8
  for (int k = 0; k < 128; ++k) acc += wrow[k] * gp[k];
#pragma unroll
  for (int off = 1; off <= 4; off <<= 1) acc += __shfl_xor(acc, off);
  if (kg == 0) c5[c] = acc + b5[c];
}

// ======================================================================
// mega2 v2: h2 -> z5 -> z6 -> z7 -> out, 64-pt blocks. h2 B-frags in regs;
// z5 double-buffered in LDS (1 barrier/group); W5/W6/W7 register prefetch
// pipelines; s_setprio around MFMA clusters.
// Internal contract (2 mi slots): octet idx = (kc*2+mi)*64+l;
//   point = mi*32+(l&31), channel = kc*16+(l>>5)*8+j.
// ======================================================================

__global__ __launch_bounds__(256, 2) void mega2(
    const bf16_t* __restrict__ h2gh, const bf16_t* __restrict__ h2gl,
    const bf16_t* __restrict__ W5h, const bf16_t* __restrict__ W5l, const float* __restrict__ c5,
    const bf16_t* __restrict__ W6h, const bf16_t* __restrict__ W6l, const float* __restrict__ b6,
    const bf16_t* __restrict__ W7h, const bf16_t* __restrict__ W7l, const float* __restrict__ b7,
    const float* __restrict__ w8, const float* __restrict__ b8v, float* __restrict__ out) {
  // LDS: phase A: z5 dbuf = [0,16384) + [16384,32768) elems (each: hi 8192 | lo 8192)
  //      phase B: z6 pair [0,32768): hi [0,16384), lo [16384,32768)
  __shared__ __align__(16) bf16_t smem[32768];
  __shared__ float sp[4][64];
  int tid = threadIdx.x, lane = tid & 63;
  int w = __builtin_amdgcn_readfirstlane(tid >> 6);
  int hb = lane >> 5, p31 = lane & 31;
  int b = blockIdx.x;
  int B = b >> 1, half = b & 1;   // R8 h2 layout: 128-pt block B, 64-pt half

  // ---- h2 B-fragments -> registers (reused by all 4 L5 groups; coalesced)
  bf16x8 xh[4][2], xl[4][2];
#pragma unroll
  for (int kc = 0; kc < 4; ++kc)
#pragma unroll
    for (int mi = 0; mi < 2; ++mi) {
      size_t so = (((size_t)((B * 4 + kc) * 4 + half * 2 + mi)) * 64 + lane) * 8;
      xh[kc][mi] = *(const bf16x8*)(h2gh + so);
      xl[kc][mi] = *(const bf16x8*)(h2gl + so);
    }

  // z6 accumulators: wave owns strips {2w, 2w+1} (64 ch) x 64 pts
  f32x16 z6a[2][2];
#pragma unroll
  for (int s = 0; s < 2; ++s)
#pragma unroll
    for (int r = 0; r < 16; ++r) {
      float bv = b6[(w * 2 + s) * 32 + 8 * (r >> 2) + 4 * hb + (r & 3)];
      z6a[s][0][r] = bv; z6a[s][1][r] = bv;
    }

  bf16x8 w5h[4], w5l[4];
  auto w5load = [&](int g) {
#pragma unroll
    for (int kc = 0; kc < 4; ++kc) {
      size_t wo = (((size_t)(g * 4 + w) * 4 + kc) * 64 + lane) * 8;
      w5h[kc] = *(const bf16x8*)(W5h + wo);
      w5l[kc] = *(const bf16x8*)(W5l + wo);
    }
  };
  w5load(0);

  bf16x8 cwh[2], cwl[2], nwh[2], nwl[2];
  auto w6load = [&](int g, int kc, bf16x8* hh, bf16x8* ll) {
#pragma unroll
    for (int s = 0; s < 2; ++s) {
      size_t wo = ((size_t)((w * 2 + s) * 32 + g * 8 + kc) * 64 + lane) * 8;
      hh[s] = *(const bf16x8*)(W6h + wo);
      ll[s] = *(const bf16x8*)(W6l + wo);
    }
  };

  for (int g5 = 0; g5 < 4; ++g5) {
    bf16_t* zbuf = smem + (g5 & 1) * 16384;
    // ---- L5 strip: z5 chans [(g5*4+w)*32, +32), K=64 from h2 regs
    int st5 = g5 * 4 + w;
    f32x16 a5[2];
    binit2(a5, c5, st5 * 32, hb);
    __builtin_amdgcn_s_setprio(1);
#pragma unroll
    for (int kc = 0; kc < 4; ++kc) {
#pragma unroll
      for (int mi = 0; mi < 2; ++mi) a5[mi] = MFMA32(w5h[kc], xh[kc][mi], a5[mi]);
#pragma unroll
      for (int mi = 0; mi < 2; ++mi) a5[mi] = MFMA32(w5l[kc], xh[kc][mi], a5[mi]);
#pragma unroll
      for (int mi = 0; mi < 2; ++mi) a5[mi] = MFMA32(w5h[kc], xl[kc][mi], a5[mi]);
    }
    __builtin_amdgcn_s_setprio(0);
    if (g5 < 3) w5load(g5 + 1);  // overlap next W5 with epi + barrier + L6
#pragma unroll
    for (int mi = 0; mi < 2; ++mi) {
      Oct o = epi_pack(a5[mi], hb);
      epi_store_lds(o, zbuf, zbuf + 8192, ((w * 2 + hb) * 2 + mi) * 64, p31);
    }
    w6load(g5, 0, cwh, cwl);  // issue before barrier so latency hides under it
    __syncthreads();          // z5[g5&1] ready (dbuf: WAR across groups is barrier-ordered)
    // ---- L6 partial accumulate over this 128-k chunk, 1-deep W pipeline
#pragma unroll
    for (int kc = 0; kc < 8; ++kc) {
      if (kc < 7) w6load(g5, kc + 1, nwh, nwl);
      bf16x8 zxh[2], zxl[2];
#pragma unroll
      for (int mi = 0; mi < 2; ++mi) {
        const bf16_t* xp = zbuf + ((kc * 2 + mi) * 64 + lane) * 8;
        zxh[mi] = *(const bf16x8*)xp;
        zxl[mi] = *(const bf16x8*)(xp + 8192);
      }
      __builtin_amdgcn_s_setprio(1);
#pragma unroll
      for (int s = 0; s < 2; ++s)
#pragma unroll
        for (int mi = 0; mi < 2; ++mi) z6a[s][mi] = MFMA32(cwh[s], zxh[mi], z6a[s][mi]);
#pragma unroll
      for (int s = 0; s < 2; ++s)
#pragma unroll
        for (int mi = 0; mi < 2; ++mi) z6a[s][mi] = MFMA32(cwl[s], zxh[mi], z6a[s][mi]);
#pragma unroll
      for (int s = 0; s < 2; ++s)
#pragma unroll
        for (int mi = 0; mi < 2; ++mi) z6a[s][mi] = MFMA32(cwh[s], zxl[mi], z6a[s][mi]);
      __builtin_amdgcn_s_setprio(0);
#pragma unroll
      for (int s = 0; s < 2; ++s) { cwh[s] = nwh[s]; cwl[s] = nwl[s]; }
    }
  }
  __syncthreads();  // all phase-A LDS reads done
  // ---- z6 epilogue -> smem [0,32768): hi [0,16384), lo [16384,32768)
#pragma unroll
  for (int s = 0; s < 2; ++s) {
    int kcb = (w * 2 + s) * 2 + hb;
#pragma unroll
    for (int mi = 0; mi < 2; ++mi) {
      Oct o = epi_pack(z6a[s][mi], hb);
      epi_store_lds(o, smem, smem + 16384, (kcb * 2 + mi) * 64, p31);
    }
  }
  // prefetch W7 kc=0 under the barrier
  bf16x8 a7wh, a7wl, n7h, n7l;
  {
    size_t wo = ((size_t)(w * 16) * 64 + lane) * 8;
    a7wh = *(const bf16x8*)(W7h + wo);
    a7wl = *(const bf16x8*)(W7l + wo);
  }
  __syncthreads();
  // ---- L7: wave strip w, K=256, 1-deep W pipeline
  f32x16 a7[2];
  binit2(a7, b7, w * 32, hb);
#pragma unroll
  for (int kc = 0; kc < 16; ++kc) {
    if (kc < 15) {
      size_t wo = ((size_t)(w * 16 + kc + 1) * 64 + lane) * 8;
      n7h = *(const bf16x8*)(W7h + wo);
      n7l = *(const bf16x8*)(W7l + wo);
    }
    bf16x8 zxh[2], zxl[2];
#pragma unroll
    for (int mi = 0; mi < 2; ++mi) {
      const bf16_t* xp = smem + ((kc * 2 + mi) * 64 + lane) * 8;
      zxh[mi] = *(const bf16x8*)xp;
      zxl[mi] = *(const bf16x8*)(xp + 16384);
    }
    __builtin_amdgcn_s_setprio(1);
#pragma unroll
    for (int mi = 0; mi < 2; ++mi) a7[mi] = MFMA32(a7wh, zxh[mi], a7[mi]);
#pragma unroll
    for (int mi = 0; mi < 2; ++mi) a7[mi] = MFMA32(a7wl, zxh[mi], a7[mi]);
#pragma unroll
    for (int mi = 0; mi < 2; ++mi) a7[mi] = MFMA32(a7wh, zxl[mi], a7[mi]);
    __builtin_amdgcn_s_setprio(0);
    a7wh = n7h; a7wl = n7l;
  }
  // ---- L8: dot with w8
  float w8v[16];
#pragma unroll
  for (int r = 0; r < 16; ++r) w8v[r] = w8[w * 32 + 8 * (r >> 2) + 4 * hb + (r & 3)];
#pragma unroll
  for (int mi = 0; mi < 2; ++mi) {
    float s = 0.f;
#pragma unroll
    for (int r = 0; r < 16; ++r) s = fmaf(relu(a7[mi][r]), w8v[r], s);
    s += __shfl_xor(s, 32);
    if (hb == 0) sp[w][mi * 32 + p31] = s;
  }
  __syncthreads();
  if (tid < 64)
    out[b * 64 + tid] = sp[0][tid] + sp[1][tid] + sp[2][tid] + sp[3][tid] + b8v[0];
}

extern "C" void kernel_launch(void* const* d_in, const int* in_sizes, int n_in,
                              void* d_out, int out_size, void* d_ws, size_t ws_size,
                              hipStream_t stream) {
  const float* x  = (const float*)d_in[0];
  const float* W1 = (const float*)d_in[1];  const float* b1 = (const float*)d_in[2];
  const float* W2 = (const float*)d_in[3];  const float* b2 = (const float*)d_in[4];
  const float* W3 = (const float*)d_in[5];  const float* b3 = (const float*)d_in[6];
  const float* W4 = (const float*)d_in[7];  const float* b4 = (const float*)d_in[8];
  const float* W5 = (const float*)d_in[9];  const float* b5 = (const float*)d_in[10];
  const float* W6 = (const float*)d_in[11]; const float* b6 = (const float*)d_in[12];
  const float* W7 = (const float*)d_in[13]; const float* b7 = (const float*)d_in[14];
  const float* W8 = (const float*)d_in[15]; const float* b8 = (const float*)d_in[16];
  float* out = (float*)d_out;

  // Workspace overlays:
  //   h2 pair [128,136)+[136,144)  L2->kl34max,mega2
  //   h1 pair [144,152)+[152,160)  k1a->L2
  //   gpart [208,210), g/c5 [210,..), weight frags after
  const size_t MB = 1ull << 20;
  char* ws = (char*)d_ws;
  bf16_t* h2h = (bf16_t*)(ws + 128 * MB);  bf16_t* h2l = (bf16_t*)(ws + 136 * MB);
  bf16_t* h1h = (bf16_t*)(ws + 144 * MB);  bf16_t* h1l = (bf16_t*)(ws + 152 * MB);
  float* gpart = (float*)(ws + 208 * MB);
  float* g     = (float*)(ws + 210 * MB);
  float* c5    = (float*)(ws + 210 * MB + 4096);
  char* wb = ws + 210 * MB + 65536;
  bf16_t* W2h = (bf16_t*)(wb);             bf16_t* W2l = (bf16_t*)(wb + 8192);
  bf16_t* W3h = (bf16_t*)(wb + 16384);     bf16_t* W3l = (bf16_t*)(wb + 32768);
  bf16_t* W4h = (bf16_t*)(wb + 49152);     bf16_t* W4l = (bf16_t*)(wb + 311296);
  bf16_t* W5h = (bf16_t*)(wb + 573440);    bf16_t* W5l = (bf16_t*)(wb + 638976);
  bf16_t* W6h = (bf16_t*)(wb + 704512);    bf16_t* W6l = (bf16_t*)(wb + 966656);
  bf16_t* W7h = (bf16_t*)(wb + 1228800);   bf16_t* W7l = (bf16_t*)(wb + 1294336);

  hipMemsetAsync(g, 0, 1024 * sizeof(float), stream);  // max identity (relu outputs >= 0)

  PrepAll pa;
  pa.seg[0] = {W2, W2h, W2l, 64, 64, 2};
  pa.seg[1] = {W3, W3h, W3l, 64, 64, 4};
  pa.seg[2] = {W4, W4h, W4l, 128, 128, 64};
  pa.seg[3] = {W5, W5h, W5l, 1088, 64, 16};   // W5[:, :64]
  pa.seg[4] = {W6, W6h, W6l, 512, 512, 64};
  pa.seg[5] = {W7, W7h, W7l, 256, 256, 16};
  kprep<<<166, 256, 0, stream>>>(pa);

  k1a<<<256, 256, 0, stream>>>(x, W1, b1, h1h, h1l);
  gemmS<2, 64, 0><<<dim3(256, 1), 256, 0, stream>>>(
      h1h, h1l, W2h, W2l, b2, 4, h2h, h2l, nullptr, nullptr, nullptr);        // L2
  kl34max<<<256, 512, 0, stream>>>(h2h, h2l, W3h, W3l, b3, W4h, W4l, b4, gpart);  // L3+L4+max
  kgmax<<<32, 256, 0, stream>>>(gpart, g);
  kc5<<<16, 256, 0, stream>>>(W5, b5, g, c5);
  mega2<<<1024, 256, 0, stream>>>(h2h, h2l, W5h, W5l, c5, W6h, W6l, b6,
                                  W7h, W7l, b7, W8, b8, out);                 // L5..L8 fused
}

// Round 9
// 258.926 us; speedup vs baseline: 1.3250x; 1.0313x over previous
//
#include <hip/hip_runtime.h>

#define NPTS 65536

typedef __bf16 bf16_t;
typedef __bf16 bf16x8 __attribute__((ext_vector_type(8)));
typedef float f32x16 __attribute__((ext_vector_type(16)));

#define MFMA32(A, B, C) __builtin_amdgcn_mfma_f32_32x32x16_bf16(A, B, C, 0, 0, 0)

__device__ __forceinline__ float relu(float v) { return v > 0.f ? v : 0.f; }

// ======================================================================
// Layouts (128-pt blocks, 4 mi slots):
// Activation (C ch): octet idx = ((b*(C/16)+kc)*4+mi)*64 + l
//   point = b*128 + mi*32 + (l&31); channel = kc*16 + (l>>5)*8 + j
// Weight (N x K): octet idx = (st*(K/16)+kc)*64 + l; n = st*32+(l&31); k = kc*16+(l>>5)*8+j
// ======================================================================

struct PrepSeg { const float* src; bf16_t* h; bf16_t* l; int SW; int K; int nblk; };
struct PrepAll { PrepSeg seg[6]; };

__global__ __launch_bounds__(256) void kprep(PrepAll pa) {
  int blk = blockIdx.x, i = 0;
  while (blk >= pa.seg[i].nblk) { blk -= pa.seg[i].nblk; ++i; }
  const PrepSeg sg = pa.seg[i];
  int t8 = blk * 256 + threadIdx.x;
  int l = t8 & 63;
  int rest = t8 >> 6;
  int NKC = sg.K >> 4;
  int kc = rest % NKC, st = rest / NKC;
  int n = st * 32 + (l & 31);
  int k0 = kc * 16 + (l >> 5) * 8;
  const float* src = sg.src + (size_t)n * sg.SW + k0;
  bf16x8 hv, lv;
#pragma unroll
  for (int j = 0; j < 8; ++j) {
    float v = src[j];
    bf16_t h = (bf16_t)v;
    hv[j] = h; lv[j] = (bf16_t)(v - (float)h);
  }
  *(bf16x8*)(sg.h + (size_t)t8 * 8) = hv;
  *(bf16x8*)(sg.l + (size_t)t8 * 8) = lv;
}

// ============ k1a: h1 = relu(x@W1.T+b1) in activation order
__global__ __launch_bounds__(256, 2) void k1a(
    const float* __restrict__ x, const float* __restrict__ W1, const float* __restrict__ b1,
    bf16_t* __restrict__ h1h, bf16_t* __restrict__ h1l) {
  int p = blockIdx.x * 256 + threadIdx.x;
  float x0 = x[p * 3 + 0], x1 = x[p * 3 + 1], x2 = x[p * 3 + 2];
  int b = p >> 7, mi = (p >> 5) & 3, p31 = p & 31;
#pragma unroll
  for (int kc = 0; kc < 4; ++kc)
#pragma unroll
    for (int hbw = 0; hbw < 2; ++hbw) {
      bf16x8 hv, lv;
#pragma unroll
      for (int j = 0; j < 8; ++j) {
        int c = kc * 16 + hbw * 8 + j;
        float v = relu(fmaf(W1[c * 3], x0, fmaf(W1[c * 3 + 1], x1, fmaf(W1[c * 3 + 2], x2, b1[c]))));
        bf16_t h = (bf16_t)v;
        hv[j] = h; lv[j] = (bf16_t)(v - (float)h);
      }
      size_t off = (((size_t)(b * 4 + kc) * 4 + mi) * 64 + hbw * 32 + p31) * 8;
      *(bf16x8*)(h1h + off) = hv;
      *(bf16x8*)(h1l + off) = lv;
    }
}

// ============ shared epilogue helpers (used by gemmS, kl34max, mega2)
struct Oct { bf16x8 h0, l0, h1, l1; };
__device__ __forceinline__ Oct epi_pack(const f32x16& accv, int hb) {
  float a[16], rcv[8];
#pragma unroll
  for (int r = 0; r < 16; ++r) a[r] = relu(accv[r]);
#pragma unroll
  for (int j = 0; j < 8; ++j) rcv[j] = __shfl_xor(hb ? a[j] : a[8 + j], 32);
  float o0[8], o1[8];
#pragma unroll
  for (int j = 0; j < 4; ++j) {
    o0[j]     = hb ? rcv[j]     : a[j];
    o0[4 + j] = hb ? a[8 + j]   : rcv[j];
    o1[j]     = hb ? rcv[4 + j] : a[4 + j];
    o1[4 + j] = hb ? a[12 + j]  : rcv[4 + j];
  }
  Oct o;
#pragma unroll
  for (int j = 0; j < 8; ++j) {
    bf16_t x0 = (bf16_t)o0[j]; o.h0[j] = x0; o.l0[j] = (bf16_t)(o0[j] - (float)x0);
    bf16_t x1 = (bf16_t)o1[j]; o.h1[j] = x1; o.l1[j] = (bf16_t)(o1[j] - (float)x1);
  }
  return o;
}

__device__ __forceinline__ void epi_store_lds(const Oct& o, bf16_t* H, bf16_t* L, int ob, int p31) {
  *(bf16x8*)(H + (ob + p31) * 8)      = o.h0;
  *(bf16x8*)(H + (ob + 32 + p31) * 8) = o.h1;
  *(bf16x8*)(L + (ob + p31) * 8)      = o.l0;
  *(bf16x8*)(L + (ob + 32 + p31) * 8) = o.l1;
}

__device__ __forceinline__ void binit2(f32x16 acc[2], const float* bias, int base, int hb) {
#pragma unroll
  for (int r = 0; r < 16; ++r) {
    float bv = bias[base + 8 * (r >> 2) + 4 * hb + (r & 3)];
    acc[0][r] = bv; acc[1][r] = bv;
  }
}

// ============ gemmS: D = W·X^T, 3-term split 32x32x16 bf16 MFMA (L2 only now)
template <int PB, int K, int MODE>
__global__ __launch_bounds__(256, 3) void gemmS(
    const bf16_t* __restrict__ Ah, const bf16_t* __restrict__ Al,
    const bf16_t* __restrict__ Wh, const bf16_t* __restrict__ Wl,
    const float* __restrict__ bias, int nko,
    bf16_t* __restrict__ Oh, bf16_t* __restrict__ Ol,
    float* __restrict__ aux, const float* __restrict__ w8, const float* __restrict__ b8) {
  constexpr int WC = 4 / PB;
  constexpr int NKC = K / 16;
  constexpr int KG = 2;
  constexpr int NG = NKC / KG;
  __shared__ bf16_t smem[2][PB][2][KG * 2048];

  int tid = threadIdx.x;
  int lane = tid & 63;
  int w = __builtin_amdgcn_readfirstlane(tid >> 6);
  int rg = w / WC, cw = w % WC;
  int hb = lane >> 5, p31 = lane & 31;
  int bx = blockIdx.x;
  int st0 = blockIdx.y * WC + cw;
  int bblk = bx * PB + rg;

  f32x16 acc[4];
#pragma unroll
  for (int r = 0; r < 16; ++r) {
    float bv = bias[st0 * 32 + 8 * (r >> 2) + 4 * hb + (r & 3)];
#pragma unroll
    for (int mi = 0; mi < 4; ++mi) acc[mi][r] = bv;
  }

  auto stage = [&](int buf, int g) {
#pragma unroll
    for (int i = 0; i < PB * 4; ++i) {
      int u = i * 256 + tid;
      int rgs = u >> 10, rem = u & 1023;
      int t = rem >> 9, inner = rem & 511;
      const bf16_t* src = (t ? Al : Ah) +
          ((size_t)(bx * PB + rgs) * NKC + g * KG) * 2048 + inner * 8;
      *(bf16x8*)&smem[buf][rgs][t][inner * 8] = *(const bf16x8*)src;
    }
  };

  bf16x8 wch[KG], wcl[KG], wnh[KG], wnl[KG];
  auto wload = [&](int g, bf16x8* h, bf16x8* l) {
#pragma unroll
    for (int kcl = 0; kcl < KG; ++kcl) {
      size_t wo = (((size_t)st0 * NKC + g * KG + kcl) * 64 + lane) * 8;
      h[kcl] = *(const bf16x8*)(Wh + wo);
      l[kcl] = *(const bf16x8*)(Wl + wo);
    }
  };

  auto compute = [&](int buf, bf16x8* h, bf16x8* l) {
#pragma unroll
    for (int kcl = 0; kcl < KG; ++kcl)
#pragma unroll
      for (int mi = 0; mi < 4; ++mi) {
        const bf16_t* xp = &smem[buf][rg][0][((kcl * 4 + mi) * 64 + lane) * 8];
        bf16x8 xh = *(const bf16x8*)xp;
        bf16x8 xl = *(const bf16x8*)(xp + KG * 2048);
        acc[mi] = MFMA32(h[kcl], xh, acc[mi]);
        acc[mi] = MFMA32(l[kcl], xh, acc[mi]);
        acc[mi] = MFMA32(h[kcl], xl, acc[mi]);
      }
  };

  stage(0, 0);
  wload(0, wch, wcl);
  for (int g = 0; g < NG; ++g) {
    __syncthreads();
    if (g + 1 < NG) {
      stage((g + 1) & 1, g + 1);
      wload(g + 1, wnh, wnl);
    }
    compute(g & 1, wch, wcl);
#pragma unroll
    for (int kcl = 0; kcl < KG; ++kcl) { wch[kcl] = wnh[kcl]; wcl[kcl] = wnl[kcl]; }
  }

  if constexpr (MODE == 0) {
#pragma unroll
    for (int mi = 0; mi < 4; ++mi) {
      Oct o = epi_pack(acc[mi], hb);
      int kco = st0 * 2 + hb;
      size_t ob = ((size_t)(bblk * nko + kco) * 4 + mi) * 64;
      *(bf16x8*)(Oh + (ob + p31) * 8)      = o.h0;
      *(bf16x8*)(Ol + (ob + p31) * 8)      = o.l0;
      *(bf16x8*)(Oh + (ob + 32 + p31) * 8) = o.h1;
      *(bf16x8*)(Ol + (ob + 32 + p31) * 8) = o.l1;
    }
  } else if constexpr (MODE == 1) {
#pragma unroll
    for (int r = 0; r < 16; ++r) {
      float m = relu(acc[0][r]);
#pragma unroll
      for (int mi = 1; mi < 4; ++mi) m = fmaxf(m, relu(acc[mi][r]));
#pragma unroll
      for (int off = 1; off < 32; off <<= 1) m = fmaxf(m, __shfl_xor(m, off));
      if (p31 == 0)
        aux[(size_t)bx * 1024 + st0 * 32 + 8 * (r >> 2) + 4 * hb + (r & 3)] = m;
    }
  } else {
    __shared__ float sp[4][128];
    float w8v[16];
#pragma unroll
    for (int r = 0; r < 16; ++r) w8v[r] = w8[st0 * 32 + 8 * (r >> 2) + 4 * hb + (r & 3)];
#pragma unroll
    for (int mi = 0; mi < 4; ++mi) {
      float s = 0.f;
#pragma unroll
      for (int r = 0; r < 16; ++r) s = fmaf(relu(acc[mi][r]), w8v[r], s);
      s += __shfl_xor(s, 32);
      if (hb == 0) sp[w][mi * 32 + p31] = s;
    }
    __syncthreads();
    if (tid < 128)
      aux[(size_t)bx * 128 + tid] = sp[0][tid] + sp[1][tid] + sp[2][tid] + sp[3][tid] + b8[0];
  }
}

// ============ kl34max v4: FUSED L3+L4, 2 tiles/block, BARRIER-FREE per-wave
// weight self-staging. v3 post-mortem: FETCH 211->10.5 MB proved request-
// amplification was the cost; remaining 55% no-issue stall = 64 full-block
// barrier+vmcnt convoys (8-wave rendezvous per 8 KB stage, NT-store HBM acks
// force-drained by in-order vmcnt, 1 block/CU = no cover). v4: each wave DMAs
// its OWN strip weights (2x global_load_lds/phase, 2-deep per-wave dbuf,
// 4 KB/wave = 32 KB). Consumer == stager -> wave-local vmcnt is the only sync;
// ZERO barriers in the 64-phase loop; waves free-run. gpart stores back to
// normal (L2) stores. 2 reqs/line (tile A+B) vs v3's 1 - still cache-resident.
// MFMA order/operands bit-identical. LDS = 128K y3 + 32K wq = 160 KiB.
__global__ __launch_bounds__(512, 1) void kl34max(
    const bf16_t* __restrict__ h2h, const bf16_t* __restrict__ h2l,
    const bf16_t* __restrict__ W3h, const bf16_t* __restrict__ W3l,
    const float* __restrict__ b3,
    const bf16_t* __restrict__ Wh, const bf16_t* __restrict__ Wl,
    const float* __restrict__ bias, float* __restrict__ gpart) {
  __shared__ __align__(16) bf16_t sA[81920];  // y3 [0,65536); wq [65536,81920)
  bf16_t* wq = sA + 65536;
  int tid = threadIdx.x, lane = tid & 63;
  int w = __builtin_amdgcn_readfirstlane(tid >> 6);   // 0..7
  int w3 = w & 3, t = w >> 2;                         // strip-slot, tile
  int hb = lane >> 5, p31 = lane & 31;
  int bx = blockIdx.x;
  int pb = bx * 2 + t;
  int rot = (bx >> 2) & 7;
  bf16_t* sT = sA + t * 32768;
  bf16_t* wbuf = wq + w * 2048;  // per-wave 4 KB: 2 buffers x (512 el h + 512 el l)

  // ---- phase 1: y3(tile t) = relu(h2@W3.T+b3) -> LDS. h2 B-frags for mi=w3.
  bf16x8 hx[4], lx[4];
#pragma unroll
  for (int kc = 0; kc < 4; ++kc) {
    size_t so = (((size_t)(pb * 4 + kc) * 4 + w3) * 64 + lane) * 8;
    hx[kc] = *(const bf16x8*)(h2h + so);
    lx[kc] = *(const bf16x8*)(h2l + so);
  }
#pragma unroll
  for (int spr = 0; spr < 2; ++spr) {
    f32x16 a3[2];
#pragma unroll
    for (int s = 0; s < 2; ++s) {
      int st = spr * 2 + s;
#pragma unroll
      for (int r = 0; r < 16; ++r)
        a3[s][r] = b3[st * 32 + 8 * (r >> 2) + 4 * hb + (r & 3)];
    }
#pragma unroll
    for (int kc = 0; kc < 4; ++kc)
#pragma unroll
      for (int s = 0; s < 2; ++s) {
        int st = spr * 2 + s;
        size_t wo = ((size_t)(st * 4 + kc) * 64 + lane) * 8;
        bf16x8 wh3 = *(const bf16x8*)(W3h + wo);
        bf16x8 wl3 = *(const bf16x8*)(W3l + wo);
        a3[s] = MFMA32(wh3, hx[kc], a3[s]);
        a3[s] = MFMA32(wl3, hx[kc], a3[s]);
        a3[s] = MFMA32(wh3, lx[kc], a3[s]);
      }
#pragma unroll
    for (int s = 0; s < 2; ++s) {
      int st = spr * 2 + s;
      Oct o = epi_pack(a3[s], hb);
      epi_store_lds(o, sT, sT + 16384, ((st * 2 + hb) * 4 + w3) * 64, p31);
    }
  }
  __syncthreads();  // y3 ready — the ONLY block-wide barrier

  // ---- phase 2: barrier-free per-wave weight pipeline over 64 (j,kc) phases
  auto issueW = [&](int u) {
    int jj = u >> 3, kc = u & 7;
    int st = ((jj + rot) & 7) * 4 + w3;
    const bf16_t* gph = Wh + ((size_t)(st * 8 + kc) * 64 + lane) * 8;
    const bf16_t* gpl = Wl + ((size_t)(st * 8 + kc) * 64 + lane) * 8;
    bf16_t* lp = wbuf + (u & 1) * 1024;  // wave-uniform base; DMA writes lane*16B
    __builtin_amdgcn_global_load_lds(
        (const __attribute__((address_space(1))) void*)gph,
        (__attribute__((address_space(3))) void*)lp, 16, 0, 0);
    __builtin_amdgcn_global_load_lds(
        (const __attribute__((address_space(1))) void*)gpl,
        (__attribute__((address_space(3))) void*)(lp + 512), 16, 0, 0);
  };
  issueW(0);

  f32x16 acc[4];
#pragma unroll 1
  for (int u = 0; u < 64; ++u) {
    if (u + 1 < 64) {
      issueW(u + 1);
      asm volatile("s_waitcnt vmcnt(2)" ::: "memory");  // DMA(u) landed; DMA(u+1) in flight
    } else {
      asm volatile("s_waitcnt vmcnt(0)" ::: "memory");
    }
    __builtin_amdgcn_sched_barrier(0);  // rule #18: pin reads after the wait
    int jj = u >> 3, kc = u & 7;
    int st = ((jj + rot) & 7) * 4 + w3;
    if (kc == 0) {
#pragma unroll
      for (int r = 0; r < 16; ++r) {
        float bv = bias[st * 32 + 8 * (r >> 2) + 4 * hb + (r & 3)];
#pragma unroll
        for (int mi = 0; mi < 4; ++mi) acc[mi][r] = bv;
      }
    }
    const bf16_t* wb = wbuf + (u & 1) * 1024;
    bf16x8 cwh = *(const bf16x8*)(wb + lane * 8);
    bf16x8 cwl = *(const bf16x8*)(wb + 512 + lane * 8);
    __builtin_amdgcn_s_setprio(1);
#pragma unroll
    for (int mi = 0; mi < 4; ++mi) {
      const bf16_t* xp = sT + ((kc * 4 + mi) * 64 + lane) * 8;
      bf16x8 xh = *(const bf16x8*)xp;
      bf16x8 xl = *(const bf16x8*)(xp + 16384);
      acc[mi] = MFMA32(cwh, xh, acc[mi]);
      acc[mi] = MFMA32(cwl, xh, acc[mi]);
      acc[mi] = MFMA32(cwh, xl, acc[mi]);
    }
    __builtin_amdgcn_s_setprio(0);
    if (kc == 7) {
#pragma unroll
      for (int r = 0; r < 16; ++r) {
        float m = fmaxf(fmaxf(acc[0][r], acc[1][r]), fmaxf(acc[2][r], acc[3][r]));
        m = fmaxf(m, 0.f);  // relu folded into the max
#pragma unroll
        for (int off = 1; off < 32; off <<= 1) m = fmaxf(m, __shfl_xor(m, off));
        if (p31 == 0)
          gpart[(size_t)pb * 1024 + st * 32 + 8 * (r >> 2) + 4 * hb + (r & 3)] = m;
      }
    }
  }
}

// ============ kgmax: g[c] = max over 512 rows of gpart[512][1024]
__global__ __launch_bounds__(256) void kgmax(const float* __restrict__ gpart, float* __restrict__ g) {
  int t = blockIdx.x * 256 + threadIdx.x;  // 8192 threads
  int c = t & 1023, rg = t >> 10;
  const float* gp = gpart + (size_t)rg * 64 * 1024 + c;
  float m = 0.f;
#pragma unroll 8
  for (int r = 0; r < 64; ++r) m = fmaxf(m, gp[(size_t)r * 1024]);
  atomicMax((unsigned int*)(g + c), __float_as_uint(m));  // all values >= 0
}

// ============ kc5: c5[c] = W5[c][64:1088] @ g + b5[c]
__global__ __launch_bounds__(256) void kc5(
    const float* __restrict__ W5, const float* __restrict__ b5,
    const float* __restrict__ g, float* __restrict__ c5) {
  int tid = threadIdx.x;
  int ci = tid >> 3, kg = tid & 7;
  int c = blockIdx.x * 32 + ci;
  const float* wrow = W5 + (size_t)c * 1088 + 64 + kg * 128;
  const float* gp = g + kg * 128;
  float acc = 0.f;
#pragma unroll 8
  for (int k = 0; k < 128; ++k) acc += wrow[k] * gp[k];
#pragma unroll
  for (int off = 1; off <= 4; off <<= 1) acc += __shfl_xor(acc, off);
  if (kg == 0) c5[c] = acc + b5[c];
}

// ======================================================================
// mega2 v2: h2 -> z5 -> z6 -> z7 -> out, 64-pt blocks. h2 B-frags in regs;
// z5 double-buffered in LDS (1 barrier/group); W5/W6/W7 register prefetch
// pipelines; s_setprio around MFMA clusters.
// Internal contract (2 mi slots): octet idx = (kc*2+mi)*64+l;
//   point = mi*32+(l&31), channel = kc*16+(l>>5)*8+j.
// ======================================================================

__global__ __launch_bounds__(256, 2) void mega2(
    const bf16_t* __restrict__ h2gh, const bf16_t* __restrict__ h2gl,
    const bf16_t* __restrict__ W5h, const bf16_t* __restrict__ W5l, const float* __restrict__ c5,
    const bf16_t* __restrict__ W6h, const bf16_t* __restrict__ W6l, const float* __restrict__ b6,
    const bf16_t* __restrict__ W7h, const bf16_t* __restrict__ W7l, const float* __restrict__ b7,
    const float* __restrict__ w8, const float* __restrict__ b8v, float* __restrict__ out) {
  // LDS: phase A: z5 dbuf = [0,16384) + [16384,32768) elems (each: hi 8192 | lo 8192)
  //      phase B: z6 pair [0,32768): hi [0,16384), lo [16384,32768)
  __shared__ __align__(16) bf16_t smem[32768];
  __shared__ float sp[4][64];
  int tid = threadIdx.x, lane = tid & 63;
  int w = __builtin_amdgcn_readfirstlane(tid >> 6);
  int hb = lane >> 5, p31 = lane & 31;
  int b = blockIdx.x;
  int B = b >> 1, half = b & 1;   // R8 h2 layout: 128-pt block B, 64-pt half

  // ---- h2 B-fragments -> registers (reused by all 4 L5 groups; coalesced)
  bf16x8 xh[4][2], xl[4][2];
#pragma unroll
  for (int kc = 0; kc < 4; ++kc)
#pragma unroll
    for (int mi = 0; mi < 2; ++mi) {
      size_t so = (((size_t)((B * 4 + kc) * 4 + half * 2 + mi)) * 64 + lane) * 8;
      xh[kc][mi] = *(const bf16x8*)(h2gh + so);
      xl[kc][mi] = *(const bf16x8*)(h2gl + so);
    }

  // z6 accumulators: wave owns strips {2w, 2w+1} (64 ch) x 64 pts
  f32x16 z6a[2][2];
#pragma unroll
  for (int s = 0; s < 2; ++s)
#pragma unroll
    for (int r = 0; r < 16; ++r) {
      float bv = b6[(w * 2 + s) * 32 + 8 * (r >> 2) + 4 * hb + (r & 3)];
      z6a[s][0][r] = bv; z6a[s][1][r] = bv;
    }

  bf16x8 w5h[4], w5l[4];
  auto w5load = [&](int g) {
#pragma unroll
    for (int kc = 0; kc < 4; ++kc) {
      size_t wo = (((size_t)(g * 4 + w) * 4 + kc) * 64 + lane) * 8;
      w5h[kc] = *(const bf16x8*)(W5h + wo);
      w5l[kc] = *(const bf16x8*)(W5l + wo);
    }
  };
  w5load(0);

  bf16x8 cwh[2], cwl[2], nwh[2], nwl[2];
  auto w6load = [&](int g, int kc, bf16x8* hh, bf16x8* ll) {
#pragma unroll
    for (int s = 0; s < 2; ++s) {
      size_t wo = ((size_t)((w * 2 + s) * 32 + g * 8 + kc) * 64 + lane) * 8;
      hh[s] = *(const bf16x8*)(W6h + wo);
      ll[s] = *(const bf16x8*)(W6l + wo);
    }
  };

  for (int g5 = 0; g5 < 4; ++g5) {
    bf16_t* zbuf = smem + (g5 & 1) * 16384;
    // ---- L5 strip: z5 chans [(g5*4+w)*32, +32), K=64 from h2 regs
    int st5 = g5 * 4 + w;
    f32x16 a5[2];
    binit2(a5, c5, st5 * 32, hb);
    __builtin_amdgcn_s_setprio(1);
#pragma unroll
    for (int kc = 0; kc < 4; ++kc) {
#pragma unroll
      for (int mi = 0; mi < 2; ++mi) a5[mi] = MFMA32(w5h[kc], xh[kc][mi], a5[mi]);
#pragma unroll
      for (int mi = 0; mi < 2; ++mi) a5[mi] = MFMA32(w5l[kc], xh[kc][mi], a5[mi]);
#pragma unroll
      for (int mi = 0; mi < 2; ++mi) a5[mi] = MFMA32(w5h[kc], xl[kc][mi], a5[mi]);
    }
    __builtin_amdgcn_s_setprio(0);
    if (g5 < 3) w5load(g5 + 1);  // overlap next W5 with epi + barrier + L6
#pragma unroll
    for (int mi = 0; mi < 2; ++mi) {
      Oct o = epi_pack(a5[mi], hb);
      epi_store_lds(o, zbuf, zbuf + 8192, ((w * 2 + hb) * 2 + mi) * 64, p31);
    }
    w6load(g5, 0, cwh, cwl);  // issue before barrier so latency hides under it
    __syncthreads();          // z5[g5&1] ready (dbuf: WAR across groups is barrier-ordered)
    // ---- L6 partial accumulate over this 128-k chunk, 1-deep W pipeline
#pragma unroll
    for (int kc = 0; kc < 8; ++kc) {
      if (kc < 7) w6load(g5, kc + 1, nwh, nwl);
      bf16x8 zxh[2], zxl[2];
#pragma unroll
      for (int mi = 0; mi < 2; ++mi) {
        const bf16_t* xp = zbuf + ((kc * 2 + mi) * 64 + lane) * 8;
        zxh[mi] = *(const bf16x8*)xp;
        zxl[mi] = *(const bf16x8*)(xp + 8192);
      }
      __builtin_amdgcn_s_setprio(1);
#pragma unroll
      for (int s = 0; s < 2; ++s)
#pragma unroll
        for (int mi = 0; mi < 2; ++mi) z6a[s][mi] = MFMA32(cwh[s], zxh[mi], z6a[s][mi]);
#pragma unroll
      for (int s = 0; s < 2; ++s)
#pragma unroll
        for (int mi = 0; mi < 2; ++mi) z6a[s][mi] = MFMA32(cwl[s], zxh[mi], z6a[s][mi]);
#pragma unroll
      for (int s = 0; s < 2; ++s)
#pragma unroll
        for (int mi = 0; mi < 2; ++mi) z6a[s][mi] = MFMA32(cwh[s], zxl[mi], z6a[s][mi]);
      __builtin_amdgcn_s_setprio(0);
#pragma unroll
      for (int s = 0; s < 2; ++s) { cwh[s] = nwh[s]; cwl[s] = nwl[s]; }
    }
  }
  __syncthreads();  // all phase-A LDS reads done
  // ---- z6 epilogue -> smem [0,32768): hi [0,16384), lo [16384,32768)
#pragma unroll
  for (int s = 0; s < 2; ++s) {
    int kcb = (w * 2 + s) * 2 + hb;
#pragma unroll
    for (int mi = 0; mi < 2; ++mi) {
      Oct o = epi_pack(z6a[s][mi], hb);
      epi_store_lds(o, smem, smem + 16384, (kcb * 2 + mi) * 64, p31);
    }
  }
  // prefetch W7 kc=0 under the barrier
  bf16x8 a7wh, a7wl, n7h, n7l;
  {
    size_t wo = ((size_t)(w * 16) * 64 + lane) * 8;
    a7wh = *(const bf16x8*)(W7h + wo);
    a7wl = *(const bf16x8*)(W7l + wo);
  }
  __syncthreads();
  // ---- L7: wave strip w, K=256, 1-deep W pipeline
  f32x16 a7[2];
  binit2(a7, b7, w * 32, hb);
#pragma unroll
  for (int kc = 0; kc < 16; ++kc) {
    if (kc < 15) {
      size_t wo = ((size_t)(w * 16 + kc + 1) * 64 + lane) * 8;
      n7h = *(const bf16x8*)(W7h + wo);
      n7l = *(const bf16x8*)(W7l + wo);
    }
    bf16x8 zxh[2], zxl[2];
#pragma unroll
    for (int mi = 0; mi < 2; ++mi) {
      const bf16_t* xp = smem + ((kc * 2 + mi) * 64 + lane) * 8;
      zxh[mi] = *(const bf16x8*)xp;
      zxl[mi] = *(const bf16x8*)(xp + 16384);
    }
    __builtin_amdgcn_s_setprio(1);
#pragma unroll
    for (int mi = 0; mi < 2; ++mi) a7[mi] = MFMA32(a7wh, zxh[mi], a7[mi]);
#pragma unroll
    for (int mi = 0; mi < 2; ++mi) a7[mi] = MFMA32(a7wl, zxh[mi], a7[mi]);
#pragma unroll
    for (int mi = 0; mi < 2; ++mi) a7[mi] = MFMA32(a7wh, zxl[mi], a7[mi]);
    __builtin_amdgcn_s_setprio(0);
    a7wh = n7h; a7wl = n7l;
  }
  // ---- L8: dot with w8
  float w8v[16];
#pragma unroll
  for (int r = 0; r < 16; ++r) w8v[r] = w8[w * 32 + 8 * (r >> 2) + 4 * hb + (r & 3)];
#pragma unroll
  for (int mi = 0; mi < 2; ++mi) {
    float s = 0.f;
#pragma unroll
    for (int r = 0; r < 16; ++r) s = fmaf(relu(a7[mi][r]), w8v[r], s);
    s += __shfl_xor(s, 32);
    if (hb == 0) sp[w][mi * 32 + p31] = s;
  }
  __syncthreads();
  if (tid < 64)
    out[b * 64 + tid] = sp[0][tid] + sp[1][tid] + sp[2][tid] + sp[3][tid] + b8v[0];
}

extern "C" void kernel_launch(void* const* d_in, const int* in_sizes, int n_in,
                              void* d_out, int out_size, void* d_ws, size_t ws_size,
                              hipStream_t stream) {
  const float* x  = (const float*)d_in[0];
  const float* W1 = (const float*)d_in[1];  const float* b1 = (const float*)d_in[2];
  const float* W2 = (const float*)d_in[3];  const float* b2 = (const float*)d_in[4];
  const float* W3 = (const float*)d_in[5];  const float* b3 = (const float*)d_in[6];
  const float* W4 = (const float*)d_in[7];  const float* b4 = (const float*)d_in[8];
  const float* W5 = (const float*)d_in[9];  const float* b5 = (const float*)d_in[10];
  const float* W6 = (const float*)d_in[11]; const float* b6 = (const float*)d_in[12];
  const float* W7 = (const float*)d_in[13]; const float* b7 = (const float*)d_in[14];
  const float* W8 = (const float*)d_in[15]; const float* b8 = (const float*)d_in[16];
  float* out = (float*)d_out;

  // Workspace overlays:
  //   h2 pair [128,136)+[136,144)  L2->kl34max,mega2
  //   h1 pair [144,152)+[152,160)  k1a->L2
  //   gpart [208,210), g/c5 [210,..), weight frags after
  const size_t MB = 1ull << 20;
  char* ws = (char*)d_ws;
  bf16_t* h2h = (bf16_t*)(ws + 128 * MB);  bf16_t* h2l = (bf16_t*)(ws + 136 * MB);
  bf16_t* h1h = (bf16_t*)(ws + 144 * MB);  bf16_t* h1l = (bf16_t*)(ws + 152 * MB);
  float* gpart = (float*)(ws + 208 * MB);
  float* g     = (float*)(ws + 210 * MB);
  float* c5    = (float*)(ws + 210 * MB + 4096);
  char* wb = ws + 210 * MB + 65536;
  bf16_t* W2h = (bf16_t*)(wb);             bf16_t* W2l = (bf16_t*)(wb + 8192);
  bf16_t* W3h = (bf16_t*)(wb + 16384);     bf16_t* W3l = (bf16_t*)(wb + 32768);
  bf16_t* W4h = (bf16_t*)(wb + 49152);     bf16_t* W4l = (bf16_t*)(wb + 311296);
  bf16_t* W5h = (bf16_t*)(wb + 573440);    bf16_t* W5l = (bf16_t*)(wb + 638976);
  bf16_t* W6h = (bf16_t*)(wb + 704512);    bf16_t* W6l = (bf16_t*)(wb + 966656);
  bf16_t* W7h = (bf16_t*)(wb + 1228800);   bf16_t* W7l = (bf16_t*)(wb + 1294336);

  hipMemsetAsync(g, 0, 1024 * sizeof(float), stream);  // max identity (relu outputs >= 0)

  PrepAll pa;
  pa.seg[0] = {W2, W2h, W2l, 64, 64, 2};
  pa.seg[1] = {W3, W3h, W3l, 64, 64, 4};
  pa.seg[2] = {W4, W4h, W4l, 128, 128, 64};
  pa.seg[3] = {W5, W5h, W5l, 1088, 64, 16};   // W5[:, :64]
  pa.seg[4] = {W6, W6h, W6l, 512, 512, 64};
  pa.seg[5] = {W7, W7h, W7l, 256, 256, 16};
  kprep<<<166, 256, 0, stream>>>(pa);

  k1a<<<256, 256, 0, stream>>>(x, W1, b1, h1h, h1l);
  gemmS<2, 64, 0><<<dim3(256, 1), 256, 0, stream>>>(
      h1h, h1l, W2h, W2l, b2, 4, h2h, h2l, nullptr, nullptr, nullptr);        // L2
  kl34max<<<256, 512, 0, stream>>>(h2h, h2l, W3h, W3l, b3, W4h, W4l, b4, gpart);  // L3+L4+max
  kgmax<<<32, 256, 0, stream>>>(gpart, g);
  kc5<<<16, 256, 0, stream>>>(W5, b5, g, c5);
  mega2<<<1024, 256, 0, stream>>>(h2h, h2l, W5h, W5l, c5, W6h, W6l, b6,
                                  W7h, W7l, b7, W8, b8, out);                 // L5..L8 fused
}

// Round 11
// 258.161 us; speedup vs baseline: 1.3290x; 1.0030x over previous
//
#include <hip/hip_runtime.h>

#define NPTS 65536

typedef __bf16 bf16_t;
typedef __bf16 bf16x8 __attribute__((ext_vector_type(8)));
typedef float f32x16 __attribute__((ext_vector_type(16)));

#define MFMA32(A, B, C) __builtin_amdgcn_mfma_f32_32x32x16_bf16(A, B, C, 0, 0, 0)

__device__ __forceinline__ float relu(float v) { return v > 0.f ? v : 0.f; }

// ======================================================================
// Layouts (128-pt blocks, 4 mi slots):
// Activation (C ch): octet idx = ((b*(C/16)+kc)*4+mi)*64 + l
//   point = b*128 + mi*32 + (l&31); channel = kc*16 + (l>>5)*8 + j
// Weight (N x K): octet idx = (st*(K/16)+kc)*64 + l; n = st*32+(l&31); k = kc*16+(l>>5)*8+j
// ======================================================================

struct PrepSeg { const float* src; bf16_t* h; bf16_t* l; int SW; int K; int nblk; };
struct PrepAll { PrepSeg seg[6]; };

__global__ __launch_bounds__(256) void kprep(PrepAll pa) {
  int blk = blockIdx.x, i = 0;
  while (blk >= pa.seg[i].nblk) { blk -= pa.seg[i].nblk; ++i; }
  const PrepSeg sg = pa.seg[i];
  int t8 = blk * 256 + threadIdx.x;
  int l = t8 & 63;
  int rest = t8 >> 6;
  int NKC = sg.K >> 4;
  int kc = rest % NKC, st = rest / NKC;
  int n = st * 32 + (l & 31);
  int k0 = kc * 16 + (l >> 5) * 8;
  const float* src = sg.src + (size_t)n * sg.SW + k0;
  bf16x8 hv, lv;
#pragma unroll
  for (int j = 0; j < 8; ++j) {
    float v = src[j];
    bf16_t h = (bf16_t)v;
    hv[j] = h; lv[j] = (bf16_t)(v - (float)h);
  }
  *(bf16x8*)(sg.h + (size_t)t8 * 8) = hv;
  *(bf16x8*)(sg.l + (size_t)t8 * 8) = lv;
}

// ============ k1a: h1 = relu(x@W1.T+b1) in activation order
__global__ __launch_bounds__(256, 2) void k1a(
    const float* __restrict__ x, const float* __restrict__ W1, const float* __restrict__ b1,
    bf16_t* __restrict__ h1h, bf16_t* __restrict__ h1l) {
  int p = blockIdx.x * 256 + threadIdx.x;
  float x0 = x[p * 3 + 0], x1 = x[p * 3 + 1], x2 = x[p * 3 + 2];
  int b = p >> 7, mi = (p >> 5) & 3, p31 = p & 31;
#pragma unroll
  for (int kc = 0; kc < 4; ++kc)
#pragma unroll
    for (int hbw = 0; hbw < 2; ++hbw) {
      bf16x8 hv, lv;
#pragma unroll
      for (int j = 0; j < 8; ++j) {
        int c = kc * 16 + hbw * 8 + j;
        float v = relu(fmaf(W1[c * 3], x0, fmaf(W1[c * 3 + 1], x1, fmaf(W1[c * 3 + 2], x2, b1[c]))));
        bf16_t h = (bf16_t)v;
        hv[j] = h; lv[j] = (bf16_t)(v - (float)h);
      }
      size_t off = (((size_t)(b * 4 + kc) * 4 + mi) * 64 + hbw * 32 + p31) * 8;
      *(bf16x8*)(h1h + off) = hv;
      *(bf16x8*)(h1l + off) = lv;
    }
}

// ============ shared epilogue helpers (used by gemmS, kl34max, mega2)
struct Oct { bf16x8 h0, l0, h1, l1; };
__device__ __forceinline__ Oct epi_pack(const f32x16& accv, int hb) {
  float a[16], rcv[8];
#pragma unroll
  for (int r = 0; r < 16; ++r) a[r] = relu(accv[r]);
#pragma unroll
  for (int j = 0; j < 8; ++j) rcv[j] = __shfl_xor(hb ? a[j] : a[8 + j], 32);
  float o0[8], o1[8];
#pragma unroll
  for (int j = 0; j < 4; ++j) {
    o0[j]     = hb ? rcv[j]     : a[j];
    o0[4 + j] = hb ? a[8 + j]   : rcv[j];
    o1[j]     = hb ? rcv[4 + j] : a[4 + j];
    o1[4 + j] = hb ? a[12 + j]  : rcv[4 + j];
  }
  Oct o;
#pragma unroll
  for (int j = 0; j < 8; ++j) {
    bf16_t x0 = (bf16_t)o0[j]; o.h0[j] = x0; o.l0[j] = (bf16_t)(o0[j] - (float)x0);
    bf16_t x1 = (bf16_t)o1[j]; o.h1[j] = x1; o.l1[j] = (bf16_t)(o1[j] - (float)x1);
  }
  return o;
}

__device__ __forceinline__ void epi_store_lds(const Oct& o, bf16_t* H, bf16_t* L, int ob, int p31) {
  *(bf16x8*)(H + (ob + p31) * 8)      = o.h0;
  *(bf16x8*)(H + (ob + 32 + p31) * 8) = o.h1;
  *(bf16x8*)(L + (ob + p31) * 8)      = o.l0;
  *(bf16x8*)(L + (ob + 32 + p31) * 8) = o.l1;
}

__device__ __forceinline__ void binit2(f32x16 acc[2], const float* bias, int base, int hb) {
#pragma unroll
  for (int r = 0; r < 16; ++r) {
    float bv = bias[base + 8 * (r >> 2) + 4 * hb + (r & 3)];
    acc[0][r] = bv; acc[1][r] = bv;
  }
}

// ============ gemmS: D = W·X^T, 3-term split 32x32x16 bf16 MFMA (L2 only now)
template <int PB, int K, int MODE>
__global__ __launch_bounds__(256, 3) void gemmS(
    const bf16_t* __restrict__ Ah, const bf16_t* __restrict__ Al,
    const bf16_t* __restrict__ Wh, const bf16_t* __restrict__ Wl,
    const float* __restrict__ bias, int nko,
    bf16_t* __restrict__ Oh, bf16_t* __restrict__ Ol,
    float* __restrict__ aux, const float* __restrict__ w8, const float* __restrict__ b8) {
  constexpr int WC = 4 / PB;
  constexpr int NKC = K / 16;
  constexpr int KG = 2;
  constexpr int NG = NKC / KG;
  __shared__ bf16_t smem[2][PB][2][KG * 2048];

  int tid = threadIdx.x;
  int lane = tid & 63;
  int w = __builtin_amdgcn_readfirstlane(tid >> 6);
  int rg = w / WC, cw = w % WC;
  int hb = lane >> 5, p31 = lane & 31;
  int bx = blockIdx.x;
  int st0 = blockIdx.y * WC + cw;
  int bblk = bx * PB + rg;

  f32x16 acc[4];
#pragma unroll
  for (int r = 0; r < 16; ++r) {
    float bv = bias[st0 * 32 + 8 * (r >> 2) + 4 * hb + (r & 3)];
#pragma unroll
    for (int mi = 0; mi < 4; ++mi) acc[mi][r] = bv;
  }

  auto stage = [&](int buf, int g) {
#pragma unroll
    for (int i = 0; i < PB * 4; ++i) {
      int u = i * 256 + tid;
      int rgs = u >> 10, rem = u & 1023;
      int t = rem >> 9, inner = rem & 511;
      const bf16_t* src = (t ? Al : Ah) +
          ((size_t)(bx * PB + rgs) * NKC + g * KG) * 2048 + inner * 8;
      *(bf16x8*)&smem[buf][rgs][t][inner * 8] = *(const bf16x8*)src;
    }
  };

  bf16x8 wch[KG], wcl[KG], wnh[KG], wnl[KG];
  auto wload = [&](int g, bf16x8* h, bf16x8* l) {
#pragma unroll
    for (int kcl = 0; kcl < KG; ++kcl) {
      size_t wo = (((size_t)st0 * NKC + g * KG + kcl) * 64 + lane) * 8;
      h[kcl] = *(const bf16x8*)(Wh + wo);
      l[kcl] = *(const bf16x8*)(Wl + wo);
    }
  };

  auto compute = [&](int buf, bf16x8* h, bf16x8* l) {
#pragma unroll
    for (int kcl = 0; kcl < KG; ++kcl)
#pragma unroll
      for (int mi = 0; mi < 4; ++mi) {
        const bf16_t* xp = &smem[buf][rg][0][((kcl * 4 + mi) * 64 + lane) * 8];
        bf16x8 xh = *(const bf16x8*)xp;
        bf16x8 xl = *(const bf16x8*)(xp + KG * 2048);
        acc[mi] = MFMA32(h[kcl], xh, acc[mi]);
        acc[mi] = MFMA32(l[kcl], xh, acc[mi]);
        acc[mi] = MFMA32(h[kcl], xl, acc[mi]);
      }
  };

  stage(0, 0);
  wload(0, wch, wcl);
  for (int g = 0; g < NG; ++g) {
    __syncthreads();
    if (g + 1 < NG) {
      stage((g + 1) & 1, g + 1);
      wload(g + 1, wnh, wnl);
    }
    compute(g & 1, wch, wcl);
#pragma unroll
    for (int kcl = 0; kcl < KG; ++kcl) { wch[kcl] = wnh[kcl]; wcl[kcl] = wnl[kcl]; }
  }

  if constexpr (MODE == 0) {
#pragma unroll
    for (int mi = 0; mi < 4; ++mi) {
      Oct o = epi_pack(acc[mi], hb);
      int kco = st0 * 2 + hb;
      size_t ob = ((size_t)(bblk * nko + kco) * 4 + mi) * 64;
      *(bf16x8*)(Oh + (ob + p31) * 8)      = o.h0;
      *(bf16x8*)(Ol + (ob + p31) * 8)      = o.l0;
      *(bf16x8*)(Oh + (ob + 32 + p31) * 8) = o.h1;
      *(bf16x8*)(Ol + (ob + 32 + p31) * 8) = o.l1;
    }
  } else if constexpr (MODE == 1) {
#pragma unroll
    for (int r = 0; r < 16; ++r) {
      float m = relu(acc[0][r]);
#pragma unroll
      for (int mi = 1; mi < 4; ++mi) m = fmaxf(m, relu(acc[mi][r]));
#pragma unroll
      for (int off = 1; off < 32; off <<= 1) m = fmaxf(m, __shfl_xor(m, off));
      if (p31 == 0)
        aux[(size_t)bx * 1024 + st0 * 32 + 8 * (r >> 2) + 4 * hb + (r & 3)] = m;
    }
  } else {
    __shared__ float sp[4][128];
    float w8v[16];
#pragma unroll
    for (int r = 0; r < 16; ++r) w8v[r] = w8[st0 * 32 + 8 * (r >> 2) + 4 * hb + (r & 3)];
#pragma unroll
    for (int mi = 0; mi < 4; ++mi) {
      float s = 0.f;
#pragma unroll
      for (int r = 0; r < 16; ++r) s = fmaf(relu(acc[mi][r]), w8v[r], s);
      s += __shfl_xor(s, 32);
      if (hb == 0) sp[w][mi * 32 + p31] = s;
    }
    __syncthreads();
    if (tid < 128)
      aux[(size_t)bx * 128 + tid] = sp[0][tid] + sp[1][tid] + sp[2][tid] + sp[3][tid] + b8[0];
  }
}

// ============ kl34max v5 (resubmit — R10 was an infra failure, kernel unmeasured):
// FUSED L3+L4, 2 tiles/block, barrier-free DMA staging + ONE-PHASE REGISTER
// PREFETCH. DMA 2-deep (issueW(u+2), steady vmcnt(2)); per iter: lgkmcnt(0)
// drain at top (regs(u) ready + WAR-protects buf(u&1) before DMA(u+2) retargets
// it), then issue phase-(u+1) ds_reads into the OTHER reg set, then run phase-u
// MFMAs with ZERO LDS dependency -> read latency hides under the MFMA cluster.
// #pragma unroll 2 keeps all (u&1) indices compile-time (no scratch). MFMA
// order/operands bit-identical. LDS = 128K y3 + 32K wq = 160 KiB.
__global__ __launch_bounds__(512, 1) void kl34max(
    const bf16_t* __restrict__ h2h, const bf16_t* __restrict__ h2l,
    const bf16_t* __restrict__ W3h, const bf16_t* __restrict__ W3l,
    const float* __restrict__ b3,
    const bf16_t* __restrict__ Wh, const bf16_t* __restrict__ Wl,
    const float* __restrict__ bias, float* __restrict__ gpart) {
  __shared__ __align__(16) bf16_t sA[81920];  // y3 [0,65536); wq [65536,81920)
  bf16_t* wq = sA + 65536;
  int tid = threadIdx.x, lane = tid & 63;
  int w = __builtin_amdgcn_readfirstlane(tid >> 6);   // 0..7
  int w3 = w & 3, t = w >> 2;                         // strip-slot, tile
  int hb = lane >> 5, p31 = lane & 31;
  int bx = blockIdx.x;
  int pb = bx * 2 + t;
  int rot = (bx >> 2) & 7;
  bf16_t* sT = sA + t * 32768;
  bf16_t* wbuf = wq + w * 2048;  // per-wave 4 KB: 2 buffers x (512 el h + 512 el l)

  // ---- phase 1: y3(tile t) = relu(h2@W3.T+b3) -> LDS. h2 B-frags for mi=w3.
  {
    bf16x8 hx[4], lx[4];
#pragma unroll
    for (int kc = 0; kc < 4; ++kc) {
      size_t so = (((size_t)(pb * 4 + kc) * 4 + w3) * 64 + lane) * 8;
      hx[kc] = *(const bf16x8*)(h2h + so);
      lx[kc] = *(const bf16x8*)(h2l + so);
    }
#pragma unroll
    for (int spr = 0; spr < 2; ++spr) {
      f32x16 a3[2];
#pragma unroll
      for (int s = 0; s < 2; ++s) {
        int st = spr * 2 + s;
#pragma unroll
        for (int r = 0; r < 16; ++r)
          a3[s][r] = b3[st * 32 + 8 * (r >> 2) + 4 * hb + (r & 3)];
      }
#pragma unroll
      for (int kc = 0; kc < 4; ++kc)
#pragma unroll
        for (int s = 0; s < 2; ++s) {
          int st = spr * 2 + s;
          size_t wo = ((size_t)(st * 4 + kc) * 64 + lane) * 8;
          bf16x8 wh3 = *(const bf16x8*)(W3h + wo);
          bf16x8 wl3 = *(const bf16x8*)(W3l + wo);
          a3[s] = MFMA32(wh3, hx[kc], a3[s]);
          a3[s] = MFMA32(wl3, hx[kc], a3[s]);
          a3[s] = MFMA32(wh3, lx[kc], a3[s]);
        }
#pragma unroll
      for (int s = 0; s < 2; ++s) {
        int st = spr * 2 + s;
        Oct o = epi_pack(a3[s], hb);
        epi_store_lds(o, sT, sT + 16384, ((st * 2 + hb) * 4 + w3) * 64, p31);
      }
    }
  }
  __syncthreads();  // y3 ready — the ONLY block-wide barrier

  // ---- phase 2: 2-deep DMA + 1-phase register-prefetch pipeline, 64 phases
  auto issueW = [&](int u) {
    int jj = u >> 3, kc = u & 7;
    int st = ((jj + rot) & 7) * 4 + w3;
    const bf16_t* gph = Wh + ((size_t)(st * 8 + kc) * 64 + lane) * 8;
    const bf16_t* gpl = Wl + ((size_t)(st * 8 + kc) * 64 + lane) * 8;
    bf16_t* lp = wbuf + (u & 1) * 1024;  // wave-uniform base; DMA writes lane*16B
    __builtin_amdgcn_global_load_lds(
        (const __attribute__((address_space(1))) void*)gph,
        (__attribute__((address_space(3))) void*)lp, 16, 0, 0);
    __builtin_amdgcn_global_load_lds(
        (const __attribute__((address_space(1))) void*)gpl,
        (__attribute__((address_space(3))) void*)(lp + 512), 16, 0, 0);
  };

  bf16x8 pw_h[2], pw_l[2];      // weight regs, ping-pong by u&1
  bf16x8 px_h[2][4], px_l[2][4]; // activation regs, ping-pong by u&1
  auto ldregs = [&](int u) {
    int slot = u & 1, kc = u & 7;
    const bf16_t* wp = wbuf + slot * 1024;
    pw_h[slot] = *(const bf16x8*)(wp + lane * 8);
    pw_l[slot] = *(const bf16x8*)(wp + 512 + lane * 8);
#pragma unroll
    for (int mi = 0; mi < 4; ++mi) {
      const bf16_t* xp = sT + ((kc * 4 + mi) * 64 + lane) * 8;
      px_h[slot][mi] = *(const bf16x8*)xp;
      px_l[slot][mi] = *(const bf16x8*)(xp + 16384);
    }
  };

  issueW(0); issueW(1);
  asm volatile("s_waitcnt vmcnt(2)" ::: "memory");  // pair 0 landed
  __builtin_amdgcn_sched_barrier(0);
  ldregs(0);

  f32x16 acc[4];
#pragma unroll 2
  for (int u = 0; u < 64; ++u) {
    int slot = u & 1;
    // regs(u) ready + WAR guard: all our ds_reads (incl. w(u) from buf(slot))
    // complete before DMA(u+2) retargets buf(slot).
    asm volatile("s_waitcnt lgkmcnt(0)" ::: "memory");
    __builtin_amdgcn_sched_barrier(0);
    if (u + 2 < 64) issueW(u + 2);
    if (u < 62)       { asm volatile("s_waitcnt vmcnt(2)" ::: "memory"); }  // pair u+1 landed
    else if (u == 62) { asm volatile("s_waitcnt vmcnt(0)" ::: "memory"); }
    __builtin_amdgcn_sched_barrier(0);
    int jj = u >> 3, kc = u & 7;
    int st = ((jj + rot) & 7) * 4 + w3;
    if (kc == 0) {
#pragma unroll
      for (int r = 0; r < 16; ++r) {
        float bv = bias[st * 32 + 8 * (r >> 2) + 4 * hb + (r & 3)];
#pragma unroll
        for (int mi = 0; mi < 4; ++mi) acc[mi][r] = bv;
      }
    }
    if (u + 1 < 64) ldregs(u + 1);  // prefetch next phase under this phase's MFMAs
    __builtin_amdgcn_s_setprio(1);
#pragma unroll
    for (int mi = 0; mi < 4; ++mi) {
      acc[mi] = MFMA32(pw_h[slot], px_h[slot][mi], acc[mi]);
      acc[mi] = MFMA32(pw_l[slot], px_h[slot][mi], acc[mi]);
      acc[mi] = MFMA32(pw_h[slot], px_l[slot][mi], acc[mi]);
    }
    __builtin_amdgcn_s_setprio(0);
    if (kc == 7) {
#pragma unroll
      for (int r = 0; r < 16; ++r) {
        float m = fmaxf(fmaxf(acc[0][r], acc[1][r]), fmaxf(acc[2][r], acc[3][r]));
        m = fmaxf(m, 0.f);  // relu folded into the max
#pragma unroll
        for (int off = 1; off < 32; off <<= 1) m = fmaxf(m, __shfl_xor(m, off));
        if (p31 == 0)
          gpart[(size_t)pb * 1024 + st * 32 + 8 * (r >> 2) + 4 * hb + (r & 3)] = m;
      }
    }
  }
}

// ============ kgmax: g[c] = max over 512 rows of gpart[512][1024]
__global__ __launch_bounds__(256) void kgmax(const float* __restrict__ gpart, float* __restrict__ g) {
  int t = blockIdx.x * 256 + threadIdx.x;  // 8192 threads
  int c = t & 1023, rg = t >> 10;
  const float* gp = gpart + (size_t)rg * 64 * 1024 + c;
  float m = 0.f;
#pragma unroll 8
  for (int r = 0; r < 64; ++r) m = fmaxf(m, gp[(size_t)r * 1024]);
  atomicMax((unsigned int*)(g + c), __float_as_uint(m));  // all values >= 0
}

// ============ kc5: c5[c] = W5[c][64:1088] @ g + b5[c]
__global__ __launch_bounds__(256) void kc5(
    const float* __restrict__ W5, const float* __restrict__ b5,
    const float* __restrict__ g, float* __restrict__ c5) {
  int tid = threadIdx.x;
  int ci = tid >> 3, kg = tid & 7;
  int c = blockIdx.x * 32 + ci;
  const float* wrow = W5 + (size_t)c * 1088 + 64 + kg * 128;
  const float* gp = g + kg * 128;
  float acc = 0.f;
#pragma unroll 8
  for (int k = 0; k < 128; ++k) acc += wrow[k] * gp[k];
#pragma unroll
  for (int off = 1; off <= 4; off <<= 1) acc += __shfl_xor(acc, off);
  if (kg == 0) c5[c] = acc + b5[c];
}

// ======================================================================
// mega2 v2: h2 -> z5 -> z6 -> z7 -> out, 64-pt blocks. h2 B-frags in regs;
// z5 double-buffered in LDS (1 barrier/group); W5/W6/W7 register prefetch
// pipelines; s_setprio around MFMA clusters.
// Internal contract (2 mi slots): octet idx = (kc*2+mi)*64+l;
//   point = mi*32+(l&31), channel = kc*16+(l>>5)*8+j.
// ======================================================================

__global__ __launch_bounds__(256, 2) void mega2(
    const bf16_t* __restrict__ h2gh, const bf16_t* __restrict__ h2gl,
    const bf16_t* __restrict__ W5h, const bf16_t* __restrict__ W5l, const float* __restrict__ c5,
    const bf16_t* __restrict__ W6h, const bf16_t* __restrict__ W6l, const float* __restrict__ b6,
    const bf16_t* __restrict__ W7h, const bf16_t* __restrict__ W7l, const float* __restrict__ b7,
    const float* __restrict__ w8, const float* __restrict__ b8v, float* __restrict__ out) {
  // LDS: phase A: z5 dbuf = [0,16384) + [16384,32768) elems (each: hi 8192 | lo 8192)
  //      phase B: z6 pair [0,32768): hi [0,16384), lo [16384,32768)
  __shared__ __align__(16) bf16_t smem[32768];
  __shared__ float sp[4][64];
  int tid = threadIdx.x, lane = tid & 63;
  int w = __builtin_amdgcn_readfirstlane(tid >> 6);
  int hb = lane >> 5, p31 = lane & 31;
  int b = blockIdx.x;
  int B = b >> 1, half = b & 1;   // R8 h2 layout: 128-pt block B, 64-pt half

  // ---- h2 B-fragments -> registers (reused by all 4 L5 groups; coalesced)
  bf16x8 xh[4][2], xl[4][2];
#pragma unroll
  for (int kc = 0; kc < 4; ++kc)
#pragma unroll
    for (int mi = 0; mi < 2; ++mi) {
      size_t so = (((size_t)((B * 4 + kc) * 4 + half * 2 + mi)) * 64 + lane) * 8;
      xh[kc][mi] = *(const bf16x8*)(h2gh + so);
      xl[kc][mi] = *(const bf16x8*)(h2gl + so);
    }

  // z6 accumulators: wave owns strips {2w, 2w+1} (64 ch) x 64 pts
  f32x16 z6a[2][2];
#pragma unroll
  for (int s = 0; s < 2; ++s)
#pragma unroll
    for (int r = 0; r < 16; ++r) {
      float bv = b6[(w * 2 + s) * 32 + 8 * (r >> 2) + 4 * hb + (r & 3)];
      z6a[s][0][r] = bv; z6a[s][1][r] = bv;
    }

  bf16x8 w5h[4], w5l[4];
  auto w5load = [&](int g) {
#pragma unroll
    for (int kc = 0; kc < 4; ++kc) {
      size_t wo = (((size_t)(g * 4 + w) * 4 + kc) * 64 + lane) * 8;
      w5h[kc] = *(const bf16x8*)(W5h + wo);
      w5l[kc] = *(const bf16x8*)(W5l + wo);
    }
  };
  w5load(0);

  bf16x8 cwh[2], cwl[2], nwh[2], nwl[2];
  auto w6load = [&](int g, int kc, bf16x8* hh, bf16x8* ll) {
#pragma unroll
    for (int s = 0; s < 2; ++s) {
      size_t wo = ((size_t)((w * 2 + s) * 32 + g * 8 + kc) * 64 + lane) * 8;
      hh[s] = *(const bf16x8*)(W6h + wo);
      ll[s] = *(const bf16x8*)(W6l + wo);
    }
  };

  for (int g5 = 0; g5 < 4; ++g5) {
    bf16_t* zbuf = smem + (g5 & 1) * 16384;
    // ---- L5 strip: z5 chans [(g5*4+w)*32, +32), K=64 from h2 regs
    int st5 = g5 * 4 + w;
    f32x16 a5[2];
    binit2(a5, c5, st5 * 32, hb);
    __builtin_amdgcn_s_setprio(1);
#pragma unroll
    for (int kc = 0; kc < 4; ++kc) {
#pragma unroll
      for (int mi = 0; mi < 2; ++mi) a5[mi] = MFMA32(w5h[kc], xh[kc][mi], a5[mi]);
#pragma unroll
      for (int mi = 0; mi < 2; ++mi) a5[mi] = MFMA32(w5l[kc], xh[kc][mi], a5[mi]);
#pragma unroll
      for (int mi = 0; mi < 2; ++mi) a5[mi] = MFMA32(w5h[kc], xl[kc][mi], a5[mi]);
    }
    __builtin_amdgcn_s_setprio(0);
    if (g5 < 3) w5load(g5 + 1);  // overlap next W5 with epi + barrier + L6
#pragma unroll
    for (int mi = 0; mi < 2; ++mi) {
      Oct o = epi_pack(a5[mi], hb);
      epi_store_lds(o, zbuf, zbuf + 8192, ((w * 2 + hb) * 2 + mi) * 64, p31);
    }
    w6load(g5, 0, cwh, cwl);  // issue before barrier so latency hides under it
    __syncthreads();          // z5[g5&1] ready (dbuf: WAR across groups is barrier-ordered)
    // ---- L6 partial accumulate over this 128-k chunk, 1-deep W pipeline
#pragma unroll
    for (int kc = 0; kc < 8; ++kc) {
      if (kc < 7) w6load(g5, kc + 1, nwh, nwl);
      bf16x8 zxh[2], zxl[2];
#pragma unroll
      for (int mi = 0; mi < 2; ++mi) {
        const bf16_t* xp = zbuf + ((kc * 2 + mi) * 64 + lane) * 8;
        zxh[mi] = *(const bf16x8*)xp;
        zxl[mi] = *(const bf16x8*)(xp + 8192);
      }
      __builtin_amdgcn_s_setprio(1);
#pragma unroll
      for (int s = 0; s < 2; ++s)
#pragma unroll
        for (int mi = 0; mi < 2; ++mi) z6a[s][mi] = MFMA32(cwh[s], zxh[mi], z6a[s][mi]);
#pragma unroll
      for (int s = 0; s < 2; ++s)
#pragma unroll
        for (int mi = 0; mi < 2; ++mi) z6a[s][mi] = MFMA32(cwl[s], zxh[mi], z6a[s][mi]);
#pragma unroll
      for (int s = 0; s < 2; ++s)
#pragma unroll
        for (int mi = 0; mi < 2; ++mi) z6a[s][mi] = MFMA32(cwh[s], zxl[mi], z6a[s][mi]);
      __builtin_amdgcn_s_setprio(0);
#pragma unroll
      for (int s = 0; s < 2; ++s) { cwh[s] = nwh[s]; cwl[s] = nwl[s]; }
    }
  }
  __syncthreads();  // all phase-A LDS reads done
  // ---- z6 epilogue -> smem [0,32768): hi [0,16384), lo [16384,32768)
#pragma unroll
  for (int s = 0; s < 2; ++s) {
    int kcb = (w * 2 + s) * 2 + hb;
#pragma unroll
    for (int mi = 0; mi < 2; ++mi) {
      Oct o = epi_pack(z6a[s][mi], hb);
      epi_store_lds(o, smem, smem + 16384, (kcb * 2 + mi) * 64, p31);
    }
  }
  // prefetch W7 kc=0 under the barrier
  bf16x8 a7wh, a7wl, n7h, n7l;
  {
    size_t wo = ((size_t)(w * 16) * 64 + lane) * 8;
    a7wh = *(const bf16x8*)(W7h + wo);
    a7wl = *(const bf16x8*)(W7l + wo);
  }
  __syncthreads();
  // ---- L7: wave strip w, K=256, 1-deep W pipeline
  f32x16 a7[2];
  binit2(a7, b7, w * 32, hb);
#pragma unroll
  for (int kc = 0; kc < 16; ++kc) {
    if (kc < 15) {
      size_t wo = ((size_t)(w * 16 + kc + 1) * 64 + lane) * 8;
      n7h = *(const bf16x8*)(W7h + wo);
      n7l = *(const bf16x8*)(W7l + wo);
    }
    bf16x8 zxh[2], zxl[2];
#pragma unroll
    for (int mi = 0; mi < 2; ++mi) {
      const bf16_t* xp = smem + ((kc * 2 + mi) * 64 + lane) * 8;
      zxh[mi] = *(const bf16x8*)xp;
      zxl[mi] = *(const bf16x8*)(xp + 16384);
    }
    __builtin_amdgcn_s_setprio(1);
#pragma unroll
    for (int mi = 0; mi < 2; ++mi) a7[mi] = MFMA32(a7wh, zxh[mi], a7[mi]);
#pragma unroll
    for (int mi = 0; mi < 2; ++mi) a7[mi] = MFMA32(a7wl, zxh[mi], a7[mi]);
#pragma unroll
    for (int mi = 0; mi < 2; ++mi) a7[mi] = MFMA32(a7wh, zxl[mi], a7[mi]);
    __builtin_amdgcn_s_setprio(0);
    a7wh = n7h; a7wl = n7l;
  }
  // ---- L8: dot with w8
  float w8v[16];
#pragma unroll
  for (int r = 0; r < 16; ++r) w8v[r] = w8[w * 32 + 8 * (r >> 2) + 4 * hb + (r & 3)];
#pragma unroll
  for (int mi = 0; mi < 2; ++mi) {
    float s = 0.f;
#pragma unroll
    for (int r = 0; r < 16; ++r) s = fmaf(relu(a7[mi][r]), w8v[r], s);
    s += __shfl_xor(s, 32);
    if (hb == 0) sp[w][mi * 32 + p31] = s;
  }
  __syncthreads();
  if (tid < 64)
    out[b * 64 + tid] = sp[0][tid] + sp[1][tid] + sp[2][tid] + sp[3][tid] + b8v[0];
}

extern "C" void kernel_launch(void* const* d_in, const int* in_sizes, int n_in,
                              void* d_out, int out_size, void* d_ws, size_t ws_size,
                              hipStream_t stream) {
  const float* x  = (const float*)d_in[0];
  const float* W1 = (const float*)d_in[1];  const float* b1 = (const float*)d_in[2];
  const float* W2 = (const float*)d_in[3];  const float* b2 = (const float*)d_in[4];
  const float* W3 = (const float*)d_in[5];  const float* b3 = (const float*)d_in[6];
  const float* W4 = (const float*)d_in[7];  const float* b4 = (const float*)d_in[8];
  const float* W5 = (const float*)d_in[9];  const float* b5 = (const float*)d_in[10];
  const float* W6 = (const float*)d_in[11]; const float* b6 = (const float*)d_in[12];
  const float* W7 = (const float*)d_in[13]; const float* b7 = (const float*)d_in[14];
  const float* W8 = (const float*)d_in[15]; const float* b8 = (const float*)d_in[16];
  float* out = (float*)d_out;

  // Workspace overlays:
  //   h2 pair [128,136)+[136,144)  L2->kl34max,mega2
  //   h1 pair [144,152)+[152,160)  k1a->L2
  //   gpart [208,210), g/c5 [210,..), weight frags after
  const size_t MB = 1ull << 20;
  char* ws = (char*)d_ws;
  bf16_t* h2h = (bf16_t*)(ws + 128 * MB);  bf16_t* h2l = (bf16_t*)(ws + 136 * MB);
  bf16_t* h1h = (bf16_t*)(ws + 144 * MB);  bf16_t* h1l = (bf16_t*)(ws + 152 * MB);
  float* gpart = (float*)(ws + 208 * MB);
  float* g     = (float*)(ws + 210 * MB);
  float* c5    = (float*)(ws + 210 * MB + 4096);
  char* wb = ws + 210 * MB + 65536;
  bf16_t* W2h = (bf16_t*)(wb);             bf16_t* W2l = (bf16_t*)(wb + 8192);
  bf16_t* W3h = (bf16_t*)(wb + 16384);     bf16_t* W3l = (bf16_t*)(wb + 32768);
  bf16_t* W4h = (bf16_t*)(wb + 49152);     bf16_t* W4l = (bf16_t*)(wb + 311296);
  bf16_t* W5h = (bf16_t*)(wb + 573440);    bf16_t* W5l = (bf16_t*)(wb + 638976);
  bf16_t* W6h = (bf16_t*)(wb + 704512);    bf16_t* W6l = (bf16_t*)(wb + 966656);
  bf16_t* W7h = (bf16_t*)(wb + 1228800);   bf16_t* W7l = (bf16_t*)(wb + 1294336);

  hipMemsetAsync(g, 0, 1024 * sizeof(float), stream);  // max identity (relu outputs >= 0)

  PrepAll pa;
  pa.seg[0] = {W2, W2h, W2l, 64, 64, 2};
  pa.seg[1] = {W3, W3h, W3l, 64, 64, 4};
  pa.seg[2] = {W4, W4h, W4l, 128, 128, 64};
  pa.seg[3] = {W5, W5h, W5l, 1088, 64, 16};   // W5[:, :64]
  pa.seg[4] = {W6, W6h, W6l, 512, 512, 64};
  pa.seg[5] = {W7, W7h, W7l, 256, 256, 16};
  kprep<<<166, 256, 0, stream>>>(pa);

  k1a<<<256, 256, 0, stream>>>(x, W1, b1, h1h, h1l);
  gemmS<2, 64, 0><<<dim3(256, 1), 256, 0, stream>>>(
      h1h, h1l, W2h, W2l, b2, 4, h2h, h2l, nullptr, nullptr, nullptr);        // L2
  kl34max<<<256, 512, 0, stream>>>(h2h, h2l, W3h, W3l, b3, W4h, W4l, b4, gpart);  // L3+L4+max
  kgmax<<<32, 256, 0, stream>>>(gpart, g);
  kc5<<<16, 256, 0, stream>>>(W5, b5, g, c5);
  mega2<<<1024, 256, 0, stream>>>(h2h, h2l, W5h, W5l, c5, W6h, W6l, b6,
                                  W7h, W7l, b7, W8, b8, out);                 // L5..L8 fused
}

// Round 14
// 252.744 us; speedup vs baseline: 1.3575x; 1.0214x over previous
//
#include <hip/hip_runtime.h>

#define NPTS 65536

typedef __bf16 bf16_t;
typedef __bf16 bf16x8 __attribute__((ext_vector_type(8)));
typedef float f32x16 __attribute__((ext_vector_type(16)));

#define MFMA32(A, B, C) __builtin_amdgcn_mfma_f32_32x32x16_bf16(A, B, C, 0, 0, 0)

__device__ __forceinline__ float relu(float v) { return v > 0.f ? v : 0.f; }

// ======================================================================
// Layouts (128-pt blocks, 4 mi slots):
// Activation (C ch): octet idx = ((b*(C/16)+kc)*4+mi)*64 + l
//   point = b*128 + mi*32 + (l&31); channel = kc*16 + (l>>5)*8 + j
// Weight (N x K): octet idx = (st*(K/16)+kc)*64 + l; n = st*32+(l&31); k = kc*16+(l>>5)*8+j
// ======================================================================

struct PrepSeg { const float* src; bf16_t* h; bf16_t* l; int SW; int K; int nblk; };
struct PrepAll { PrepSeg seg[6]; };

__global__ __launch_bounds__(256) void kprep(PrepAll pa) {
  int blk = blockIdx.x, i = 0;
  while (blk >= pa.seg[i].nblk) { blk -= pa.seg[i].nblk; ++i; }
  const PrepSeg sg = pa.seg[i];
  int t8 = blk * 256 + threadIdx.x;
  int l = t8 & 63;
  int rest = t8 >> 6;
  int NKC = sg.K >> 4;
  int kc = rest % NKC, st = rest / NKC;
  int n = st * 32 + (l & 31);
  int k0 = kc * 16 + (l >> 5) * 8;
  const float* src = sg.src + (size_t)n * sg.SW + k0;
  bf16x8 hv, lv;
#pragma unroll
  for (int j = 0; j < 8; ++j) {
    float v = src[j];
    bf16_t h = (bf16_t)v;
    hv[j] = h; lv[j] = (bf16_t)(v - (float)h);
  }
  *(bf16x8*)(sg.h + (size_t)t8 * 8) = hv;
  *(bf16x8*)(sg.l + (size_t)t8 * 8) = lv;
}

// ============ k1a: h1 = relu(x@W1.T+b1) in activation order (R11 verbatim)
__global__ __launch_bounds__(256, 2) void k1a(
    const float* __restrict__ x, const float* __restrict__ W1, const float* __restrict__ b1,
    bf16_t* __restrict__ h1h, bf16_t* __restrict__ h1l) {
  int p = blockIdx.x * 256 + threadIdx.x;
  float x0 = x[p * 3 + 0], x1 = x[p * 3 + 1], x2 = x[p * 3 + 2];
  int b = p >> 7, mi = (p >> 5) & 3, p31 = p & 31;
#pragma unroll
  for (int kc = 0; kc < 4; ++kc)
#pragma unroll
    for (int hbw = 0; hbw < 2; ++hbw) {
      bf16x8 hv, lv;
#pragma unroll
      for (int j = 0; j < 8; ++j) {
        int c = kc * 16 + hbw * 8 + j;
        float v = relu(fmaf(W1[c * 3], x0, fmaf(W1[c * 3 + 1], x1, fmaf(W1[c * 3 + 2], x2, b1[c]))));
        bf16_t h = (bf16_t)v;
        hv[j] = h; lv[j] = (bf16_t)(v - (float)h);
      }
      size_t off = (((size_t)(b * 4 + kc) * 4 + mi) * 64 + hbw * 32 + p31) * 8;
      *(bf16x8*)(h1h + off) = hv;
      *(bf16x8*)(h1l + off) = lv;
    }
}

// ============ shared epilogue helpers
struct Oct { bf16x8 h0, l0, h1, l1; };
__device__ __forceinline__ Oct epi_pack(const f32x16& accv, int hb) {
  float a[16], rcv[8];
#pragma unroll
  for (int r = 0; r < 16; ++r) a[r] = relu(accv[r]);
#pragma unroll
  for (int j = 0; j < 8; ++j) rcv[j] = __shfl_xor(hb ? a[j] : a[8 + j], 32);
  float o0[8], o1[8];
#pragma unroll
  for (int j = 0; j < 4; ++j) {
    o0[j]     = hb ? rcv[j]     : a[j];
    o0[4 + j] = hb ? a[8 + j]   : rcv[j];
    o1[j]     = hb ? rcv[4 + j] : a[4 + j];
    o1[4 + j] = hb ? a[12 + j]  : rcv[4 + j];
  }
  Oct o;
#pragma unroll
  for (int j = 0; j < 8; ++j) {
    bf16_t x0 = (bf16_t)o0[j]; o.h0[j] = x0; o.l0[j] = (bf16_t)(o0[j] - (float)x0);
    bf16_t x1 = (bf16_t)o1[j]; o.h1[j] = x1; o.l1[j] = (bf16_t)(o1[j] - (float)x1);
  }
  return o;
}

__device__ __forceinline__ void epi_store_lds(const Oct& o, bf16_t* H, bf16_t* L, int ob, int p31) {
  *(bf16x8*)(H + (ob + p31) * 8)      = o.h0;
  *(bf16x8*)(H + (ob + 32 + p31) * 8) = o.h1;
  *(bf16x8*)(L + (ob + p31) * 8)      = o.l0;
  *(bf16x8*)(L + (ob + 32 + p31) * 8) = o.l1;
}

__device__ __forceinline__ void binit2(f32x16 acc[2], const float* bias, int base, int hb) {
#pragma unroll
  for (int r = 0; r < 16; ++r) {
    float bv = bias[base + 8 * (r >> 2) + 4 * hb + (r & 3)];
    acc[0][r] = bv; acc[1][r] = bv;
  }
}

// ============ gemmS: D = W·X^T, 3-term split 32x32x16 bf16 MFMA (L2 only; R11 verbatim)
template <int PB, int K, int MODE>
__global__ __launch_bounds__(256, 3) void gemmS(
    const bf16_t* __restrict__ Ah, const bf16_t* __restrict__ Al,
    const bf16_t* __restrict__ Wh, const bf16_t* __restrict__ Wl,
    const float* __restrict__ bias, int nko,
    bf16_t* __restrict__ Oh, bf16_t* __restrict__ Ol,
    float* __restrict__ aux, const float* __restrict__ w8, const float* __restrict__ b8) {
  constexpr int WC = 4 / PB;
  constexpr int NKC = K / 16;
  constexpr int KG = 2;
  constexpr int NG = NKC / KG;
  __shared__ bf16_t smem[2][PB][2][KG * 2048];

  int tid = threadIdx.x;
  int lane = tid & 63;
  int w = __builtin_amdgcn_readfirstlane(tid >> 6);
  int rg = w / WC, cw = w % WC;
  int hb = lane >> 5, p31 = lane & 31;
  int bx = blockIdx.x;
  int st0 = blockIdx.y * WC + cw;
  int bblk = bx * PB + rg;

  f32x16 acc[4];
#pragma unroll
  for (int r = 0; r < 16; ++r) {
    float bv = bias[st0 * 32 + 8 * (r >> 2) + 4 * hb + (r & 3)];
#pragma unroll
    for (int mi = 0; mi < 4; ++mi) acc[mi][r] = bv;
  }

  auto stage = [&](int buf, int g) {
#pragma unroll
    for (int i = 0; i < PB * 4; ++i) {
      int u = i * 256 + tid;
      int rgs = u >> 10, rem = u & 1023;
      int t = rem >> 9, inner = rem & 511;
      const bf16_t* src = (t ? Al : Ah) +
          ((size_t)(bx * PB + rgs) * NKC + g * KG) * 2048 + inner * 8;
      *(bf16x8*)&smem[buf][rgs][t][inner * 8] = *(const bf16x8*)src;
    }
  };

  bf16x8 wch[KG], wcl[KG], wnh[KG], wnl[KG];
  auto wload = [&](int g, bf16x8* h, bf16x8* l) {
#pragma unroll
    for (int kcl = 0; kcl < KG; ++kcl) {
      size_t wo = (((size_t)st0 * NKC + g * KG + kcl) * 64 + lane) * 8;
      h[kcl] = *(const bf16x8*)(Wh + wo);
      l[kcl] = *(const bf16x8*)(Wl + wo);
    }
  };

  auto compute = [&](int buf, bf16x8* h, bf16x8* l) {
#pragma unroll
    for (int kcl = 0; kcl < KG; ++kcl)
#pragma unroll
      for (int mi = 0; mi < 4; ++mi) {
        const bf16_t* xp = &smem[buf][rg][0][((kcl * 4 + mi) * 64 + lane) * 8];
        bf16x8 xh = *(const bf16x8*)xp;
        bf16x8 xl = *(const bf16x8*)(xp + KG * 2048);
        acc[mi] = MFMA32(h[kcl], xh, acc[mi]);
        acc[mi] = MFMA32(l[kcl], xh, acc[mi]);
        acc[mi] = MFMA32(h[kcl], xl, acc[mi]);
      }
  };

  stage(0, 0);
  wload(0, wch, wcl);
  for (int g = 0; g < NG; ++g) {
    __syncthreads();
    if (g + 1 < NG) {
      stage((g + 1) & 1, g + 1);
      wload(g + 1, wnh, wnl);
    }
    compute(g & 1, wch, wcl);
#pragma unroll
    for (int kcl = 0; kcl < KG; ++kcl) { wch[kcl] = wnh[kcl]; wcl[kcl] = wnl[kcl]; }
  }

  if constexpr (MODE == 0) {
#pragma unroll
    for (int mi = 0; mi < 4; ++mi) {
      Oct o = epi_pack(acc[mi], hb);
      int kco = st0 * 2 + hb;
      size_t ob = ((size_t)(bblk * nko + kco) * 4 + mi) * 64;
      *(bf16x8*)(Oh + (ob + p31) * 8)      = o.h0;
      *(bf16x8*)(Ol + (ob + p31) * 8)      = o.l0;
      *(bf16x8*)(Oh + (ob + 32 + p31) * 8) = o.h1;
      *(bf16x8*)(Ol + (ob + 32 + p31) * 8) = o.l1;
    }
  } else if constexpr (MODE == 1) {
#pragma unroll
    for (int r = 0; r < 16; ++r) {
      float m = relu(acc[0][r]);
#pragma unroll
      for (int mi = 1; mi < 4; ++mi) m = fmaxf(m, relu(acc[mi][r]));
#pragma unroll
      for (int off = 1; off < 32; off <<= 1) m = fmaxf(m, __shfl_xor(m, off));
      if (p31 == 0)
        aux[(size_t)bx * 1024 + st0 * 32 + 8 * (r >> 2) + 4 * hb + (r & 3)] = m;
    }
  } else {
    __shared__ float sp[4][128];
    float w8v[16];
#pragma unroll
    for (int r = 0; r < 16; ++r) w8v[r] = w8[st0 * 32 + 8 * (r >> 2) + 4 * hb + (r & 3)];
#pragma unroll
    for (int mi = 0; mi < 4; ++mi) {
      float s = 0.f;
#pragma unroll
      for (int r = 0; r < 16; ++r) s = fmaf(relu(acc[mi][r]), w8v[r], s);
      s += __shfl_xor(s, 32);
      if (hb == 0) sp[w][mi * 32 + p31] = s;
    }
    __syncthreads();
    if (tid < 128)
      aux[(size_t)bx * 128 + tid] = sp[0][tid] + sp[1][tid] + sp[2][tid] + sp[3][tid] + b8[0];
  }
}

// ============ kl34max v4 (measured 75.9 us in R9): FUSED L3+L4, 2 tiles/block,
// barrier-free per-wave DMA staging. LDS = 128K y3 + 32K wq = 160 KiB.
__global__ __launch_bounds__(512, 1) void kl34max(
    const bf16_t* __restrict__ h2h, const bf16_t* __restrict__ h2l,
    const bf16_t* __restrict__ W3h, const bf16_t* __restrict__ W3l,
    const float* __restrict__ b3,
    const bf16_t* __restrict__ Wh, const bf16_t* __restrict__ Wl,
    const float* __restrict__ bias, float* __restrict__ gpart) {
  __shared__ __align__(16) bf16_t sA[81920];  // y3 [0,65536); wq [65536,81920)
  bf16_t* wq = sA + 65536;
  int tid = threadIdx.x, lane = tid & 63;
  int w = __builtin_amdgcn_readfirstlane(tid >> 6);   // 0..7
  int w3 = w & 3, t = w >> 2;                         // strip-slot, tile
  int hb = lane >> 5, p31 = lane & 31;
  int bx = blockIdx.x;
  int pb = bx * 2 + t;
  int rot = (bx >> 2) & 7;
  bf16_t* sT = sA + t * 32768;
  bf16_t* wbuf = wq + w * 2048;  // per-wave 4 KB: 2 buffers x (512 el h + 512 el l)

  // ---- phase 1: y3(tile t) = relu(h2@W3.T+b3) -> LDS. h2 B-frags for mi=w3.
  {
    bf16x8 hx[4], lx[4];
#pragma unroll
    for (int kc = 0; kc < 4; ++kc) {
      size_t so = (((size_t)(pb * 4 + kc) * 4 + w3) * 64 + lane) * 8;
      hx[kc] = *(const bf16x8*)(h2h + so);
      lx[kc] = *(const bf16x8*)(h2l + so);
    }
#pragma unroll
    for (int spr = 0; spr < 2; ++spr) {
      f32x16 a3[2];
#pragma unroll
      for (int s = 0; s < 2; ++s) {
        int st = spr * 2 + s;
#pragma unroll
        for (int r = 0; r < 16; ++r)
          a3[s][r] = b3[st * 32 + 8 * (r >> 2) + 4 * hb + (r & 3)];
      }
#pragma unroll
      for (int kc = 0; kc < 4; ++kc)
#pragma unroll
        for (int s = 0; s < 2; ++s) {
          int st = spr * 2 + s;
          size_t wo = ((size_t)(st * 4 + kc) * 64 + lane) * 8;
          bf16x8 wh3 = *(const bf16x8*)(W3h + wo);
          bf16x8 wl3 = *(const bf16x8*)(W3l + wo);
          a3[s] = MFMA32(wh3, hx[kc], a3[s]);
          a3[s] = MFMA32(wl3, hx[kc], a3[s]);
          a3[s] = MFMA32(wh3, lx[kc], a3[s]);
        }
#pragma unroll
      for (int s = 0; s < 2; ++s) {
        int st = spr * 2 + s;
        Oct o = epi_pack(a3[s], hb);
        epi_store_lds(o, sT, sT + 16384, ((st * 2 + hb) * 4 + w3) * 64, p31);
      }
    }
  }
  __syncthreads();  // y3 ready — the ONLY block-wide barrier

  // ---- phase 2: barrier-free per-wave weight pipeline over 64 (j,kc) phases
  auto issueW = [&](int u) {
    int jj = u >> 3, kc = u & 7;
    int st = ((jj + rot) & 7) * 4 + w3;
    const bf16_t* gph = Wh + ((size_t)(st * 8 + kc) * 64 + lane) * 8;
    const bf16_t* gpl = Wl + ((size_t)(st * 8 + kc) * 64 + lane) * 8;
    bf16_t* lp = wbuf + (u & 1) * 1024;  // wave-uniform base; DMA writes lane*16B
    __builtin_amdgcn_global_load_lds(
        (const __attribute__((address_space(1))) void*)gph,
        (__attribute__((address_space(3))) void*)lp, 16, 0, 0);
    __builtin_amdgcn_global_load_lds(
        (const __attribute__((address_space(1))) void*)gpl,
        (__attribute__((address_space(3))) void*)(lp + 512), 16, 0, 0);
  };
  issueW(0);

  f32x16 acc[4];
#pragma unroll 1
  for (int u = 0; u < 64; ++u) {
    if (u + 1 < 64) {
      issueW(u + 1);
      asm volatile("s_waitcnt vmcnt(2)" ::: "memory");  // DMA(u) landed; DMA(u+1) in flight
    } else {
      asm volatile("s_waitcnt vmcnt(0)" ::: "memory");
    }
    __builtin_amdgcn_sched_barrier(0);  // rule #18: pin reads after the wait
    int jj = u >> 3, kc = u & 7;
    int st = ((jj + rot) & 7) * 4 + w3;
    if (kc == 0) {
#pragma unroll
      for (int r = 0; r < 16; ++r) {
        float bv = bias[st * 32 + 8 * (r >> 2) + 4 * hb + (r & 3)];
#pragma unroll
        for (int mi = 0; mi < 4; ++mi) acc[mi][r] = bv;
      }
    }
    const bf16_t* wb = wbuf + (u & 1) * 1024;
    bf16x8 cwh = *(const bf16x8*)(wb + lane * 8);
    bf16x8 cwl = *(const bf16x8*)(wb + 512 + lane * 8);
    __builtin_amdgcn_s_setprio(1);
#pragma unroll
    for (int mi = 0; mi < 4; ++mi) {
      const bf16_t* xp = sT + ((kc * 4 + mi) * 64 + lane) * 8;
      bf16x8 xh = *(const bf16x8*)xp;
      bf16x8 xl = *(const bf16x8*)(xp + 16384);
      acc[mi] = MFMA32(cwh, xh, acc[mi]);
      acc[mi] = MFMA32(cwl, xh, acc[mi]);
      acc[mi] = MFMA32(cwh, xl, acc[mi]);
    }
    __builtin_amdgcn_s_setprio(0);
    if (kc == 7) {
#pragma unroll
      for (int r = 0; r < 16; ++r) {
        float m = fmaxf(fmaxf(acc[0][r], acc[1][r]), fmaxf(acc[2][r], acc[3][r]));
        m = fmaxf(m, 0.f);  // relu folded into the max
#pragma unroll
        for (int off = 1; off < 32; off <<= 1) m = fmaxf(m, __shfl_xor(m, off));
        if (p31 == 0)
          gpart[(size_t)pb * 1024 + st * 32 + 8 * (r >> 2) + 4 * hb + (r & 3)] = m;
      }
    }
  }
}

// ============ kgmax: g[c] = max over 512 rows of gpart[512][1024]
__global__ __launch_bounds__(256) void kgmax(const float* __restrict__ gpart, float* __restrict__ g) {
  int t = blockIdx.x * 256 + threadIdx.x;  // 8192 threads
  int c = t & 1023, rg = t >> 10;
  const float* gp = gpart + (size_t)rg * 64 * 1024 + c;
  float m = 0.f;
#pragma unroll 8
  for (int r = 0; r < 64; ++r) m = fmaxf(m, gp[(size_t)r * 1024]);
  atomicMax((unsigned int*)(g + c), __float_as_uint(m));  // all values >= 0
}

// ============ kc5 v3: c5[c] = W5[c][64:1088] @ g + b5[c], COALESCED, bounds-fixed.
// 32 blocks x 4 waves = 128 waves x 4 channels = 512 = L5 output count.
__global__ __launch_bounds__(256) void kc5(
    const float* __restrict__ W5, const float* __restrict__ b5,
    const float* __restrict__ g, float* __restrict__ c5) {
  int lane = threadIdx.x & 63;
  int wv = blockIdx.x * 4 + (threadIdx.x >> 6);  // 128 waves
  float gv[16];
#pragma unroll
  for (int k = 0; k < 16; ++k) gv[k] = g[k * 64 + lane];
#pragma unroll
  for (int i = 0; i < 4; ++i) {
    int c = wv * 4 + i;  // 0..511
    const float* wrow = W5 + (size_t)c * 1088 + 64;
    float acc = 0.f;
#pragma unroll
    for (int k = 0; k < 16; ++k) acc = fmaf(wrow[k * 64 + lane], gv[k], acc);
#pragma unroll
    for (int off = 1; off < 64; off <<= 1) acc += __shfl_xor(acc, off);
    if (lane == 0) c5[c] = acc + b5[c];
  }
}

// ======================================================================
// mega2 v2 (R11 verbatim): h2 -> z5 -> z6 -> z7 -> out, 64-pt blocks.
// ======================================================================

__global__ __launch_bounds__(256, 2) void mega2(
    const bf16_t* __restrict__ h2gh, const bf16_t* __restrict__ h2gl,
    const bf16_t* __restrict__ W5h, const bf16_t* __restrict__ W5l, const float* __restrict__ c5,
    const bf16_t* __restrict__ W6h, const bf16_t* __restrict__ W6l, const float* __restrict__ b6,
    const bf16_t* __restrict__ W7h, const bf16_t* __restrict__ W7l, const float* __restrict__ b7,
    const float* __restrict__ w8, const float* __restrict__ b8v, float* __restrict__ out) {
  __shared__ __align__(16) bf16_t smem[32768];
  __shared__ float sp[4][64];
  int tid = threadIdx.x, lane = tid & 63;
  int w = __builtin_amdgcn_readfirstlane(tid >> 6);
  int hb = lane >> 5, p31 = lane & 31;
  int b = blockIdx.x;
  int B = b >> 1, half = b & 1;

  bf16x8 xh[4][2], xl[4][2];
#pragma unroll
  for (int kc = 0; kc < 4; ++kc)
#pragma unroll
    for (int mi = 0; mi < 2; ++mi) {
      size_t so = (((size_t)((B * 4 + kc) * 4 + half * 2 + mi)) * 64 + lane) * 8;
      xh[kc][mi] = *(const bf16x8*)(h2gh + so);
      xl[kc][mi] = *(const bf16x8*)(h2gl + so);
    }

  f32x16 z6a[2][2];
#pragma unroll
  for (int s = 0; s < 2; ++s)
#pragma unroll
    for (int r = 0; r < 16; ++r) {
      float bv = b6[(w * 2 + s) * 32 + 8 * (r >> 2) + 4 * hb + (r & 3)];
      z6a[s][0][r] = bv; z6a[s][1][r] = bv;
    }

  bf16x8 w5h[4], w5l[4];
  auto w5load = [&](int g) {
#pragma unroll
    for (int kc = 0; kc < 4; ++kc) {
      size_t wo = (((size_t)(g * 4 + w) * 4 + kc) * 64 + lane) * 8;
      w5h[kc] = *(const bf16x8*)(W5h + wo);
      w5l[kc] = *(const bf16x8*)(W5l + wo);
    }
  };
  w5load(0);

  bf16x8 cwh[2], cwl[2], nwh[2], nwl[2];
  auto w6load = [&](int g, int kc, bf16x8* hh, bf16x8* ll) {
#pragma unroll
    for (int s = 0; s < 2; ++s) {
      size_t wo = ((size_t)((w * 2 + s) * 32 + g * 8 + kc) * 64 + lane) * 8;
      hh[s] = *(const bf16x8*)(W6h + wo);
      ll[s] = *(const bf16x8*)(W6l + wo);
    }
  };

  for (int g5 = 0; g5 < 4; ++g5) {
    bf16_t* zbuf = smem + (g5 & 1) * 16384;
    int st5 = g5 * 4 + w;
    f32x16 a5[2];
    binit2(a5, c5, st5 * 32, hb);
    __builtin_amdgcn_s_setprio(1);
#pragma unroll
    for (int kc = 0; kc < 4; ++kc) {
#pragma unroll
      for (int mi = 0; mi < 2; ++mi) a5[mi] = MFMA32(w5h[kc], xh[kc][mi], a5[mi]);
#pragma unroll
      for (int mi = 0; mi < 2; ++mi) a5[mi] = MFMA32(w5l[kc], xh[kc][mi], a5[mi]);
#pragma unroll
      for (int mi = 0; mi < 2; ++mi) a5[mi] = MFMA32(w5h[kc], xl[kc][mi], a5[mi]);
    }
    __builtin_amdgcn_s_setprio(0);
    if (g5 < 3) w5load(g5 + 1);
#pragma unroll
    for (int mi = 0; mi < 2; ++mi) {
      Oct o = epi_pack(a5[mi], hb);
      epi_store_lds(o, zbuf, zbuf + 8192, ((w * 2 + hb) * 2 + mi) * 64, p31);
    }
    w6load(g5, 0, cwh, cwl);
    __syncthreads();
#pragma unroll
    for (int kc = 0; kc < 8; ++kc) {
      if (kc < 7) w6load(g5, kc + 1, nwh, nwl);
      bf16x8 zxh[2], zxl[2];
#pragma unroll
      for (int mi = 0; mi < 2; ++mi) {
        const bf16_t* xp = zbuf + ((kc * 2 + mi) * 64 + lane) * 8;
        zxh[mi] = *(const bf16x8*)xp;
        zxl[mi] = *(const bf16x8*)(xp + 8192);
      }
      __builtin_amdgcn_s_setprio(1);
#pragma unroll
      for (int s = 0; s < 2; ++s)
#pragma unroll
        for (int mi = 0; mi < 2; ++mi) z6a[s][mi] = MFMA32(cwh[s], zxh[mi], z6a[s][mi]);
#pragma unroll
      for (int s = 0; s < 2; ++s)
#pragma unroll
        for (int mi = 0; mi < 2; ++mi) z6a[s][mi] = MFMA32(cwl[s], zxh[mi], z6a[s][mi]);
#pragma unroll
      for (int s = 0; s < 2; ++s)
#pragma unroll
        for (int mi = 0; mi < 2; ++mi) z6a[s][mi] = MFMA32(cwh[s], zxl[mi], z6a[s][mi]);
      __builtin_amdgcn_s_setprio(0);
#pragma unroll
      for (int s = 0; s < 2; ++s) { cwh[s] = nwh[s]; cwl[s] = nwl[s]; }
    }
  }
  __syncthreads();
#pragma unroll
  for (int s = 0; s < 2; ++s) {
    int kcb = (w * 2 + s) * 2 + hb;
#pragma unroll
    for (int mi = 0; mi < 2; ++mi) {
      Oct o = epi_pack(z6a[s][mi], hb);
      epi_store_lds(o, smem, smem + 16384, (kcb * 2 + mi) * 64, p31);
    }
  }
  bf16x8 a7wh, a7wl, n7h, n7l;
  {
    size_t wo = ((size_t)(w * 16) * 64 + lane) * 8;
    a7wh = *(const bf16x8*)(W7h + wo);
    a7wl = *(const bf16x8*)(W7l + wo);
  }
  __syncthreads();
  f32x16 a7[2];
  binit2(a7, b7, w * 32, hb);
#pragma unroll
  for (int kc = 0; kc < 16; ++kc) {
    if (kc < 15) {
      size_t wo = ((size_t)(w * 16 + kc + 1) * 64 + lane) * 8;
      n7h = *(const bf16x8*)(W7h + wo);
      n7l = *(const bf16x8*)(W7l + wo);
    }
    bf16x8 zxh[2], zxl[2];
#pragma unroll
    for (int mi = 0; mi < 2; ++mi) {
      const bf16_t* xp = smem + ((kc * 2 + mi) * 64 + lane) * 8;
      zxh[mi] = *(const bf16x8*)xp;
      zxl[mi] = *(const bf16x8*)(xp + 16384);
    }
    __builtin_amdgcn_s_setprio(1);
#pragma unroll
    for (int mi = 0; mi < 2; ++mi) a7[mi] = MFMA32(a7wh, zxh[mi], a7[mi]);
#pragma unroll
    for (int mi = 0; mi < 2; ++mi) a7[mi] = MFMA32(a7wl, zxh[mi], a7[mi]);
#pragma unroll
    for (int mi = 0; mi < 2; ++mi) a7[mi] = MFMA32(a7wh, zxl[mi], a7[mi]);
    __builtin_amdgcn_s_setprio(0);
    a7wh = n7h; a7wl = n7l;
  }
  float w8v[16];
#pragma unroll
  for (int r = 0; r < 16; ++r) w8v[r] = w8[w * 32 + 8 * (r >> 2) + 4 * hb + (r & 3)];
#pragma unroll
  for (int mi = 0; mi < 2; ++mi) {
    float s = 0.f;
#pragma unroll
    for (int r = 0; r < 16; ++r) s = fmaf(relu(a7[mi][r]), w8v[r], s);
    s += __shfl_xor(s, 32);
    if (hb == 0) sp[w][mi * 32 + p31] = s;
  }
  __syncthreads();
  if (tid < 64)
    out[b * 64 + tid] = sp[0][tid] + sp[1][tid] + sp[2][tid] + sp[3][tid] + b8v[0];
}

extern "C" void kernel_launch(void* const* d_in, const int* in_sizes, int n_in,
                              void* d_out, int out_size, void* d_ws, size_t ws_size,
                              hipStream_t stream) {
  const float* x  = (const float*)d_in[0];
  const float* W1 = (const float*)d_in[1];  const float* b1 = (const float*)d_in[2];
  const float* W2 = (const float*)d_in[3];  const float* b2 = (const float*)d_in[4];
  const float* W3 = (const float*)d_in[5];  const float* b3 = (const float*)d_in[6];
  const float* W4 = (const float*)d_in[7];  const float* b4 = (const float*)d_in[8];
  const float* W5 = (const float*)d_in[9];  const float* b5 = (const float*)d_in[10];
  const float* W6 = (const float*)d_in[11]; const float* b6 = (const float*)d_in[12];
  const float* W7 = (const float*)d_in[13]; const float* b7 = (const float*)d_in[14];
  const float* W8 = (const float*)d_in[15]; const float* b8 = (const float*)d_in[16];
  float* out = (float*)d_out;

  // Workspace overlays:
  //   h2 pair [128,136)+[136,144)  L2->kl34max,mega2
  //   h1 pair [144,152)+[152,160)  k1a->L2
  //   gpart [208,210), g/c5 [210,..), weight frags after
  const size_t MB = 1ull << 20;
  char* ws = (char*)d_ws;
  bf16_t* h2h = (bf16_t*)(ws + 128 * MB);  bf16_t* h2l = (bf16_t*)(ws + 136 * MB);
  bf16_t* h1h = (bf16_t*)(ws + 144 * MB);  bf16_t* h1l = (bf16_t*)(ws + 152 * MB);
  float* gpart = (float*)(ws + 208 * MB);
  float* g     = (float*)(ws + 210 * MB);
  float* c5    = (float*)(ws + 210 * MB + 4096);
  char* wb = ws + 210 * MB + 65536;
  bf16_t* W2h = (bf16_t*)(wb);             bf16_t* W2l = (bf16_t*)(wb + 8192);
  bf16_t* W3h = (bf16_t*)(wb + 16384);     bf16_t* W3l = (bf16_t*)(wb + 32768);
  bf16_t* W4h = (bf16_t*)(wb + 49152);     bf16_t* W4l = (bf16_t*)(wb + 311296);
  bf16_t* W5h = (bf16_t*)(wb + 573440);    bf16_t* W5l = (bf16_t*)(wb + 638976);
  bf16_t* W6h = (bf16_t*)(wb + 704512);    bf16_t* W6l = (bf16_t*)(wb + 966656);
  bf16_t* W7h = (bf16_t*)(wb + 1228800);   bf16_t* W7l = (bf16_t*)(wb + 1294336);

  hipMemsetAsync(g, 0, 1024 * sizeof(float), stream);  // max identity (relu outputs >= 0)

  PrepAll pa;
  pa.seg[0] = {W2, W2h, W2l, 64, 64, 2};
  pa.seg[1] = {W3, W3h, W3l, 64, 64, 4};
  pa.seg[2] = {W4, W4h, W4l, 128, 128, 64};
  pa.seg[3] = {W5, W5h, W5l, 1088, 64, 16};   // W5[:, :64]
  pa.seg[4] = {W6, W6h, W6l, 512, 512, 64};
  pa.seg[5] = {W7, W7h, W7l, 256, 256, 16};
  kprep<<<166, 256, 0, stream>>>(pa);

  k1a<<<256, 256, 0, stream>>>(x, W1, b1, h1h, h1l);
  gemmS<2, 64, 0><<<dim3(256, 1), 256, 0, stream>>>(
      h1h, h1l, W2h, W2l, b2, 4, h2h, h2l, nullptr, nullptr, nullptr);        // L2
  kl34max<<<256, 512, 0, stream>>>(h2h, h2l, W3h, W3l, b3, W4h, W4l, b4, gpart);  // L3+L4+max
  kgmax<<<32, 256, 0, stream>>>(gpart, g);
  kc5<<<32, 256, 0, stream>>>(W5, b5, g, c5);
  mega2<<<1024, 256, 0, stream>>>(h2h, h2l, W5h, W5l, c5, W6h, W6l, b6,
                                  W7h, W7l, b7, W8, b8, out);                 // L5..L8 fused
}